// Round 1
// baseline (1343.397 us; speedup 1.0000x reference)
//
#include <hip/hip_runtime.h>

#define NN 50000
#define NE 400000
#define NG 512

typedef __bf16 bf16x8 __attribute__((ext_vector_type(8)));
typedef float f32x4 __attribute__((ext_vector_type(4)));
typedef unsigned short us8 __attribute__((ext_vector_type(8)));

__device__ __forceinline__ float frcp(float x) { return __builtin_amdgcn_rcpf(x); }
__device__ __forceinline__ float silu_f(float x) { return x * frcp(1.f + __expf(-x)); }
__device__ __forceinline__ float tanh_f(float x) { return 1.f - 2.f * frcp(__expf(2.f * x) + 1.f); }
__device__ __forceinline__ __bf16 f2bf(float f) {
    unsigned u = __builtin_bit_cast(unsigned, f);
    u += 0x7fffu + ((u >> 16) & 1u);
    unsigned short s = (unsigned short)(u >> 16);
    return __builtin_bit_cast(__bf16, s);
}

// ---------------- weight prep: W2T[l][j][k] = bf16(msg_W2[l][k][j]) ----------------
__global__ void k_wprep(const float* __restrict__ mW2, const float* __restrict__ pW2,
                        unsigned short* __restrict__ W2T, unsigned short* __restrict__ pW2T)
{
    int idx = blockIdx.x * 256 + threadIdx.x;
    if (idx >= 4 * 64 * 64) return;
    int l = idx >> 12, r = idx & 4095;
    int j = r >> 6, k = r & 63;
    int src = l * 4096 + k * 64 + j;
    W2T[idx]  = __builtin_bit_cast(unsigned short, f2bf(mW2[src]));
    pW2T[idx] = __builtin_bit_cast(unsigned short, f2bf(pW2[src]));
}

// ---------------- embed ----------------
__global__ __launch_bounds__(256) void k_embed(
    const float* __restrict__ x, const float* __restrict__ pe,
    const float* __restrict__ eW, const float* __restrict__ eb,
    const float* __restrict__ epW, const float* __restrict__ epb,
    float* __restrict__ h, float* __restrict__ ph)
{
    const int lane = threadIdx.x & 63;
    const int wid = (blockIdx.x << 2) + (threadIdx.x >> 6);
    const int nw = gridDim.x << 2;
    float wh[64], wp[24];
#pragma unroll
    for (int k = 0; k < 64; k++) wh[k] = eW[k * 64 + lane];
#pragma unroll
    for (int k = 0; k < 24; k++) wp[k] = epW[k * 64 + lane];
    const float bh = eb[lane], bp = epb[lane];

    for (int n = wid; n < NN; n += nw) {
        const int nu = __builtin_amdgcn_readfirstlane(n);
        const float* xr = x + (size_t)nu * 40;
        const float* pr = pe + (size_t)nu * 24;
        float a0 = 0, a1 = 0, a2 = 0, a3 = 0;
#pragma unroll
        for (int k = 0; k < 40; k += 4) {
            a0 += xr[k] * wh[k]; a1 += xr[k + 1] * wh[k + 1];
            a2 += xr[k + 2] * wh[k + 2]; a3 += xr[k + 3] * wh[k + 3];
        }
#pragma unroll
        for (int k = 0; k < 24; k += 4) {
            a0 += pr[k] * wh[40 + k]; a1 += pr[k + 1] * wh[41 + k];
            a2 += pr[k + 2] * wh[42 + k]; a3 += pr[k + 3] * wh[43 + k];
        }
        float p0 = 0, p1 = 0, p2 = 0, p3 = 0;
#pragma unroll
        for (int k = 0; k < 24; k += 4) {
            p0 += pr[k] * wp[k]; p1 += pr[k + 1] * wp[k + 1];
            p2 += pr[k + 2] * wp[k + 2]; p3 += pr[k + 3] * wp[k + 3];
        }
        h[(size_t)nu * 64 + lane] = a0 + a1 + a2 + a3 + bh;
        ph[(size_t)nu * 64 + lane] = p0 + p1 + p2 + p3 + bp;
    }
}

// ---------------- edge distances ----------------
__global__ void k_dist(const int* __restrict__ send, const int* __restrict__ rec,
                       const float* __restrict__ pos, float* __restrict__ dist)
{
    int e = blockIdx.x * 256 + threadIdx.x;
    if (e >= NE) return;
    int s = send[e], r = rec[e];
    float dx = pos[s * 3 + 0] - pos[r * 3 + 0];
    float dy = pos[s * 3 + 1] - pos[r * 3 + 1];
    float dz = pos[s * 3 + 2] - pos[r * 3 + 2];
    dist[e] = sqrtf(dx * dx + dy * dy + dz * dz);
}

// ---------------- per-layer node precompute (A|PA into stab, B|PB into rtab) -------
// z=0: A = h@W1[0:64] + ph@W1[64:128]            -> stab[n][0:64];  h2 = 2h
// z=1: B = h@W1[128:192] + ph@W1[192:256] + b1   -> rtab[n][0:64]
// z=2: PA = ph@pW1[0:64] -> stab[n][64:128]; PB = ph@pW1[64:128]+pb1 -> rtab[n][64:128]; ph2 = 2ph
__global__ __launch_bounds__(256) void k_nodepre(
    const float* __restrict__ h, const float* __restrict__ ph,
    const float* __restrict__ mW1, const float* __restrict__ mb1,
    const float* __restrict__ pW1g, const float* __restrict__ pb1,
    int layer,
    float* __restrict__ stab, float* __restrict__ rtab,
    float* __restrict__ h2, float* __restrict__ ph2)
{
    const int lane = threadIdx.x & 63;
    const int z = blockIdx.y;
    const int wid = (blockIdx.x << 2) + (threadIdx.x >> 6);
    const int nw = gridDim.x << 2;
    const float* W1 = mW1 + (size_t)layer * 16448;   // 257*64
    const float* PW1 = pW1g + (size_t)layer * 8256;  // 129*64

    float w[128];
    if (z == 0) {
#pragma unroll
        for (int k = 0; k < 128; k++) w[k] = W1[k * 64 + lane];
    } else if (z == 1) {
#pragma unroll
        for (int k = 0; k < 128; k++) w[k] = W1[(128 + k) * 64 + lane];
    } else {
#pragma unroll
        for (int k = 0; k < 128; k++) w[k] = PW1[k * 64 + lane];
    }
    const float bB = mb1[layer * 64 + lane];
    const float bPB = pb1[layer * 64 + lane];

    for (int n = wid; n < NN; n += nw) {
        const int nu = __builtin_amdgcn_readfirstlane(n);
        const float* hr = h + (size_t)nu * 64;
        const float* pr = ph + (size_t)nu * 64;
        if (z == 0) {
            float a0 = 0, a1 = 0, a2 = 0, a3 = 0;
#pragma unroll
            for (int k = 0; k < 64; k += 4) {
                a0 += hr[k] * w[k]; a1 += hr[k + 1] * w[k + 1];
                a2 += hr[k + 2] * w[k + 2]; a3 += hr[k + 3] * w[k + 3];
            }
#pragma unroll
            for (int k = 0; k < 64; k += 4) {
                a0 += pr[k] * w[64 + k]; a1 += pr[k + 1] * w[65 + k];
                a2 += pr[k + 2] * w[66 + k]; a3 += pr[k + 3] * w[67 + k];
            }
            stab[(size_t)nu * 128 + lane] = a0 + a1 + a2 + a3;
            h2[(size_t)nu * 64 + lane] = 2.f * hr[lane];
        } else if (z == 1) {
            float a0 = 0, a1 = 0, a2 = 0, a3 = 0;
#pragma unroll
            for (int k = 0; k < 64; k += 4) {
                a0 += hr[k] * w[k]; a1 += hr[k + 1] * w[k + 1];
                a2 += hr[k + 2] * w[k + 2]; a3 += hr[k + 3] * w[k + 3];
            }
#pragma unroll
            for (int k = 0; k < 64; k += 4) {
                a0 += pr[k] * w[64 + k]; a1 += pr[k + 1] * w[65 + k];
                a2 += pr[k + 2] * w[66 + k]; a3 += pr[k + 3] * w[67 + k];
            }
            rtab[(size_t)nu * 128 + lane] = a0 + a1 + a2 + a3 + bB;
        } else {
            float a0 = 0, a1 = 0, a2 = 0, a3 = 0;
            float b0 = 0, b1v = 0, b2 = 0, b3 = 0;
#pragma unroll
            for (int k = 0; k < 64; k += 4) {
                float v0 = pr[k], v1 = pr[k + 1], v2 = pr[k + 2], v3 = pr[k + 3];
                a0 += v0 * w[k]; a1 += v1 * w[k + 1]; a2 += v2 * w[k + 2]; a3 += v3 * w[k + 3];
                b0 += v0 * w[64 + k]; b1v += v1 * w[65 + k]; b2 += v2 * w[66 + k]; b3 += v3 * w[67 + k];
            }
            stab[(size_t)nu * 128 + 64 + lane] = a0 + a1 + a2 + a3;
            rtab[(size_t)nu * 128 + 64 + lane] = b0 + b1v + b2 + b3 + bPB;
            ph2[(size_t)nu * 64 + lane] = 2.f * pr[lane];
        }
    }
}

// ---------------- edge kernel: silu/tanh phase + MFMA 64x64 matmuls + atomics ------
__global__ __launch_bounds__(256) void k_edge(
    const int* __restrict__ send, const int* __restrict__ rec,
    const float* __restrict__ dist,
    const float* __restrict__ stab, const float* __restrict__ rtab,
    const float* __restrict__ mW1, const float* __restrict__ mb2,
    const float* __restrict__ pW1g, const float* __restrict__ pb2,
    const unsigned short* __restrict__ W2T, const unsigned short* __restrict__ pW2T,
    int layer,
    float* __restrict__ hout, float* __restrict__ pout)
{
    __shared__ __align__(16) float t1s[4][16][64];
    __shared__ __align__(16) float tps[4][16][64];
    const int lane = threadIdx.x & 63;
    const int wv = threadIdx.x >> 6;
    const int l15 = lane & 15, q = lane >> 4;

    const float w1l = mW1[(size_t)layer * 16448 + 16384 + lane];   // W1 row 256 (dist)
    const float pw1l = pW1g[(size_t)layer * 8256 + 8192 + lane];   // pW1 row 128 (dist)

    bf16x8 wb[8], pwb[8];
    {
        const unsigned short* w2 = W2T + layer * 4096;
        const unsigned short* pw2 = pW2T + layer * 4096;
#pragma unroll
        for (int jt = 0; jt < 4; jt++)
#pragma unroll
            for (int kk = 0; kk < 2; kk++) {
                int off = (jt * 16 + l15) * 64 + kk * 32 + q * 8;
                wb[jt * 2 + kk]  = __builtin_bit_cast(bf16x8, *(const us8*)(w2 + off));
                pwb[jt * 2 + kk] = __builtin_bit_cast(bf16x8, *(const us8*)(pw2 + off));
            }
    }
    float b2v[4], pb2v[4];
#pragma unroll
    for (int jt = 0; jt < 4; jt++) {
        b2v[jt] = mb2[layer * 64 + jt * 16 + l15];
        pb2v[jt] = pb2[layer * 64 + jt * 16 + l15];
    }

    const int nwave = gridDim.x << 2;
    for (int g = (blockIdx.x << 2) + wv; g < NE / 16; g += nwave) {
        const int ebase = g * 16;
        int sv = send[ebase + l15];
        int rv = rec[ebase + l15];
        float dv = dist[ebase + l15];

#pragma unroll 4
        for (int e = 0; e < 16; e++) {
            int se = __shfl(sv, e);
            int re = __shfl(rv, e);
            float de = __shfl(dv, e);
            const float* sr = stab + (size_t)se * 128;
            const float* rr_ = rtab + (size_t)re * 128;
            float Av = sr[lane], PAv = sr[64 + lane];
            float Bv = rr_[lane], PBv = rr_[64 + lane];
            t1s[wv][e][lane] = silu_f(Av + Bv + de * w1l);
            tps[wv][e][lane] = tanh_f(PAv + PBv + de * pw1l);
        }

        int rr[4];
#pragma unroll
        for (int i = 0; i < 4; i++) rr[i] = __shfl(rv, q * 4 + i);

        // ---- msg second layer ----
        {
            const float* tr = &t1s[wv][l15][0];
            f32x4 u0 = *(const f32x4*)(tr + q * 8);
            f32x4 u1 = *(const f32x4*)(tr + q * 8 + 4);
            f32x4 u2 = *(const f32x4*)(tr + 32 + q * 8);
            f32x4 u3 = *(const f32x4*)(tr + 32 + q * 8 + 4);
            bf16x8 a0, a1;
#pragma unroll
            for (int i = 0; i < 4; i++) {
                a0[i] = f2bf(u0[i]); a0[4 + i] = f2bf(u1[i]);
                a1[i] = f2bf(u2[i]); a1[4 + i] = f2bf(u3[i]);
            }
#pragma unroll
            for (int jt = 0; jt < 4; jt++) {
                f32x4 acc = {0.f, 0.f, 0.f, 0.f};
                acc = __builtin_amdgcn_mfma_f32_16x16x32_bf16(a0, wb[jt * 2 + 0], acc, 0, 0, 0);
                acc = __builtin_amdgcn_mfma_f32_16x16x32_bf16(a1, wb[jt * 2 + 1], acc, 0, 0, 0);
#pragma unroll
                for (int i = 0; i < 4; i++) {
                    float m = silu_f(acc[i] + b2v[jt]);
                    atomicAdd(&hout[(size_t)rr[i] * 64 + jt * 16 + l15], m);
                }
            }
        }
        // ---- pmsg second layer ----
        {
            const float* tr = &tps[wv][l15][0];
            f32x4 u0 = *(const f32x4*)(tr + q * 8);
            f32x4 u1 = *(const f32x4*)(tr + q * 8 + 4);
            f32x4 u2 = *(const f32x4*)(tr + 32 + q * 8);
            f32x4 u3 = *(const f32x4*)(tr + 32 + q * 8 + 4);
            bf16x8 a0, a1;
#pragma unroll
            for (int i = 0; i < 4; i++) {
                a0[i] = f2bf(u0[i]); a0[4 + i] = f2bf(u1[i]);
                a1[i] = f2bf(u2[i]); a1[4 + i] = f2bf(u3[i]);
            }
#pragma unroll
            for (int jt = 0; jt < 4; jt++) {
                f32x4 acc = {0.f, 0.f, 0.f, 0.f};
                acc = __builtin_amdgcn_mfma_f32_16x16x32_bf16(a0, pwb[jt * 2 + 0], acc, 0, 0, 0);
                acc = __builtin_amdgcn_mfma_f32_16x16x32_bf16(a1, pwb[jt * 2 + 1], acc, 0, 0, 0);
#pragma unroll
                for (int i = 0; i < 4; i++) {
                    float m = tanh_f(acc[i] + pb2v[jt]);
                    atomicAdd(&pout[(size_t)rr[i] * 64 + jt * 16 + l15], m);
                }
            }
        }
    }
}

// ---------------- final node MLP + pooling ----------------
__global__ __launch_bounds__(256) void k_prepool(
    const float* __restrict__ h, const int* __restrict__ batch,
    const float* __restrict__ W1, const float* __restrict__ b1,
    const float* __restrict__ W2, const float* __restrict__ b2,
    float* __restrict__ pooled)
{
    __shared__ __align__(16) float tl[4][64];
    const int lane = threadIdx.x & 63;
    const int wv = threadIdx.x >> 6;
    float w1[64], w2[64];
#pragma unroll
    for (int k = 0; k < 64; k++) { w1[k] = W1[k * 64 + lane]; w2[k] = W2[k * 64 + lane]; }
    const float bb1 = b1[lane], bb2 = b2[lane];
    const int wid = (blockIdx.x << 2) + wv;
    const int nw = gridDim.x << 2;
    for (int n = wid; n < NN; n += nw) {
        const int nu = __builtin_amdgcn_readfirstlane(n);
        const float* hr = h + (size_t)nu * 64;
        float a0 = 0, a1 = 0, a2 = 0, a3 = 0;
#pragma unroll
        for (int k = 0; k < 64; k += 4) {
            a0 += hr[k] * w1[k]; a1 += hr[k + 1] * w1[k + 1];
            a2 += hr[k + 2] * w1[k + 2]; a3 += hr[k + 3] * w1[k + 3];
        }
        tl[wv][lane] = silu_f(a0 + a1 + a2 + a3 + bb1);
        float c0 = 0, c1 = 0, c2 = 0, c3 = 0;
        const f32x4* tp4 = (const f32x4*)&tl[wv][0];
#pragma unroll
        for (int k4 = 0; k4 < 16; k4++) {
            f32x4 tv = tp4[k4];
            c0 += tv[0] * w2[k4 * 4]; c1 += tv[1] * w2[k4 * 4 + 1];
            c2 += tv[2] * w2[k4 * 4 + 2]; c3 += tv[3] * w2[k4 * 4 + 3];
        }
        float hp = c0 + c1 + c2 + c3 + bb2;
        int gidx = batch[nu];
        atomicAdd(&pooled[(size_t)gidx * 64 + lane], hp);
    }
}

// ---------------- readout ----------------
__global__ __launch_bounds__(256) void k_readout(
    const float* __restrict__ pooled,
    const float* __restrict__ W1, const float* __restrict__ b1,
    const float* __restrict__ W2, const float* __restrict__ b2,
    float* __restrict__ out)
{
    const int lane = threadIdx.x & 63;
    const int wv = threadIdx.x >> 6;
    const int g = (blockIdx.x << 2) + wv;
    if (g >= NG) return;
    const float* pr = pooled + (size_t)g * 64;
    float a0 = 0, a1 = 0, a2 = 0, a3 = 0;
#pragma unroll
    for (int k = 0; k < 64; k += 4) {
        a0 += pr[k] * W1[k * 64 + lane]; a1 += pr[k + 1] * W1[(k + 1) * 64 + lane];
        a2 += pr[k + 2] * W1[(k + 2) * 64 + lane]; a3 += pr[k + 3] * W1[(k + 3) * 64 + lane];
    }
    float v = silu_f(a0 + a1 + a2 + a3 + b1[lane]) * W2[lane];
#pragma unroll
    for (int off = 32; off > 0; off >>= 1) v += __shfl_down(v, off);
    if (lane == 0) out[g] = v + b2[0];
}

extern "C" void kernel_launch(void* const* d_in, const int* in_sizes, int n_in,
                              void* d_out, int out_size, void* d_ws, size_t ws_size,
                              hipStream_t stream)
{
    const float* x = (const float*)d_in[0];
    const float* pos = (const float*)d_in[1];
    const float* pe = (const float*)d_in[2];
    const int* eidx = (const int*)d_in[3];
    const int* batch = (const int*)d_in[4];
    const float* eW = (const float*)d_in[5];
    const float* eb = (const float*)d_in[6];
    const float* epW = (const float*)d_in[7];
    const float* epb = (const float*)d_in[8];
    const float* mW1 = (const float*)d_in[9];
    const float* mb1 = (const float*)d_in[10];
    const float* mW2 = (const float*)d_in[11];
    const float* mb2 = (const float*)d_in[12];
    const float* pW1 = (const float*)d_in[13];
    const float* pb1 = (const float*)d_in[14];
    const float* pW2 = (const float*)d_in[15];
    const float* pb2 = (const float*)d_in[16];
    const float* preW1 = (const float*)d_in[17];
    const float* preb1 = (const float*)d_in[18];
    const float* preW2 = (const float*)d_in[19];
    const float* preb2 = (const float*)d_in[20];
    const float* roW1 = (const float*)d_in[21];
    const float* rob1 = (const float*)d_in[22];
    const float* roW2 = (const float*)d_in[23];
    const float* rob2 = (const float*)d_in[24];

    const int* send = eidx;
    const int* rcv = eidx + NE;

    float* f = (float*)d_ws;
    size_t o = 0;
    float* hA = f + o; o += (size_t)NN * 64;
    float* hB = f + o; o += (size_t)NN * 64;
    float* phA = f + o; o += (size_t)NN * 64;
    float* phB = f + o; o += (size_t)NN * 64;
    float* stab = f + o; o += (size_t)NN * 128;
    float* rtab = f + o; o += (size_t)NN * 128;
    float* dist = f + o; o += NE;
    float* pooled = f + o; o += NG * 64;
    unsigned short* W2T = (unsigned short*)(f + o); o += 8192;   // 4*64*64 ushorts
    unsigned short* pW2T = (unsigned short*)(f + o); o += 8192;

    hipMemsetAsync(pooled, 0, NG * 64 * sizeof(float), stream);
    k_wprep<<<64, 256, 0, stream>>>(mW2, pW2, W2T, pW2T);
    k_embed<<<256, 256, 0, stream>>>(x, pe, eW, eb, epW, epb, hA, phA);
    k_dist<<<(NE + 255) / 256, 256, 0, stream>>>(send, rcv, pos, dist);

    float* hin = hA; float* pin = phA; float* hout = hB; float* pout = phB;
    for (int l = 0; l < 4; l++) {
        k_nodepre<<<dim3(256, 3), 256, 0, stream>>>(hin, pin, mW1, mb1, pW1, pb1, l,
                                                    stab, rtab, hout, pout);
        k_edge<<<2048, 256, 0, stream>>>(send, rcv, dist, stab, rtab,
                                         mW1, mb2, pW1, pb2, W2T, pW2T, l, hout, pout);
        float* t;
        t = hin; hin = hout; hout = t;
        t = pin; pin = pout; pout = t;
    }
    k_prepool<<<256, 256, 0, stream>>>(hin, batch, preW1, preb1, preW2, preb2, pooled);
    k_readout<<<128, 256, 0, stream>>>(pooled, roW1, rob1, roW2, rob2, (float*)d_out);
}

// Round 2
// 1209.555 us; speedup vs baseline: 1.1107x; 1.1107x over previous
//
#include <hip/hip_runtime.h>

#define NN 50000
#define NE 400000
#define NG 512

typedef __bf16 bf16x8 __attribute__((ext_vector_type(8)));
typedef float f32x4 __attribute__((ext_vector_type(4)));
typedef unsigned short us8 __attribute__((ext_vector_type(8)));

__device__ __forceinline__ float frcp(float x) { return __builtin_amdgcn_rcpf(x); }
__device__ __forceinline__ float silu_f(float x) { return x * frcp(1.f + __expf(-x)); }
__device__ __forceinline__ float tanh_f(float x) { return 1.f - 2.f * frcp(__expf(2.f * x) + 1.f); }
__device__ __forceinline__ __bf16 f2bf(float f) {
    unsigned u = __builtin_bit_cast(unsigned, f);
    u += 0x7fffu + ((u >> 16) & 1u);
    unsigned short s = (unsigned short)(u >> 16);
    return __builtin_bit_cast(__bf16, s);
}

// ---------------- weight prep: W2T[l][j][k] = bf16(msg_W2[l][k][j]) ----------------
__global__ void k_wprep(const float* __restrict__ mW2, const float* __restrict__ pW2,
                        unsigned short* __restrict__ W2T, unsigned short* __restrict__ pW2T)
{
    int idx = blockIdx.x * 256 + threadIdx.x;
    if (idx >= 4 * 64 * 64) return;
    int l = idx >> 12, r = idx & 4095;
    int j = r >> 6, k = r & 63;
    int src = l * 4096 + k * 64 + j;
    W2T[idx]  = __builtin_bit_cast(unsigned short, f2bf(mW2[src]));
    pW2T[idx] = __builtin_bit_cast(unsigned short, f2bf(pW2[src]));
}

// ---------------- counting sort by receiver ----------------
__global__ void k_hist(const int* __restrict__ rec, int* __restrict__ hist)
{
    int e = blockIdx.x * 256 + threadIdx.x;
    if (e < NE) atomicAdd(&hist[rec[e]], 1);
}

__global__ __launch_bounds__(1024) void k_scan(const int* __restrict__ hist, int* __restrict__ cursor)
{
    __shared__ int wsum[16];
    const int t = threadIdx.x;
    const int lane = t & 63, w = t >> 6;
    const int PER = 49;                    // 1024*49 = 50176 >= NN
    const int base = t * PER;
    int s = 0;
    for (int i = 0; i < PER; i++) { int idx = base + i; if (idx < NN) s += hist[idx]; }
    int pre = s;
#pragma unroll
    for (int d = 1; d < 64; d <<= 1) { int o = __shfl_up(pre, d); if (lane >= d) pre += o; }
    if (lane == 63) wsum[w] = pre;
    __syncthreads();
    if (w == 0) {
        int v = (lane < 16) ? wsum[lane] : 0;
        int p = v;
#pragma unroll
        for (int d = 1; d < 16; d <<= 1) { int o = __shfl_up(p, d); if (lane >= d) p += o; }
        if (lane < 16) wsum[lane] = p - v;   // exclusive
    }
    __syncthreads();
    int run = wsum[w] + (pre - s);
    for (int i = 0; i < PER; i++) {
        int idx = base + i;
        if (idx < NN) { cursor[idx] = run; run += hist[idx]; }
    }
}

__global__ void k_scatter(const int* __restrict__ send, const int* __restrict__ rec,
                          const float* __restrict__ pos, int* __restrict__ cursor,
                          int* __restrict__ ssend, int* __restrict__ srec,
                          float* __restrict__ sdist)
{
    int e = blockIdx.x * 256 + threadIdx.x;
    if (e >= NE) return;
    int s = send[e], r = rec[e];
    int p = atomicAdd(&cursor[r], 1);
    float dx = pos[s * 3 + 0] - pos[r * 3 + 0];
    float dy = pos[s * 3 + 1] - pos[r * 3 + 1];
    float dz = pos[s * 3 + 2] - pos[r * 3 + 2];
    ssend[p] = s; srec[p] = r;
    sdist[p] = sqrtf(dx * dx + dy * dy + dz * dz);
}

// ---------------- embed ----------------
__global__ __launch_bounds__(256) void k_embed(
    const float* __restrict__ x, const float* __restrict__ pe,
    const float* __restrict__ eW, const float* __restrict__ eb,
    const float* __restrict__ epW, const float* __restrict__ epb,
    float* __restrict__ h, float* __restrict__ ph)
{
    const int lane = threadIdx.x & 63;
    const int wid = (blockIdx.x << 2) + (threadIdx.x >> 6);
    const int nw = gridDim.x << 2;
    float wh[64], wp[24];
#pragma unroll
    for (int k = 0; k < 64; k++) wh[k] = eW[k * 64 + lane];
#pragma unroll
    for (int k = 0; k < 24; k++) wp[k] = epW[k * 64 + lane];
    const float bh = eb[lane], bp = epb[lane];

    for (int n = wid; n < NN; n += nw) {
        const int nu = __builtin_amdgcn_readfirstlane(n);
        const float* xr = x + (size_t)nu * 40;
        const float* pr = pe + (size_t)nu * 24;
        float a0 = 0, a1 = 0, a2 = 0, a3 = 0;
#pragma unroll
        for (int k = 0; k < 40; k += 4) {
            a0 += xr[k] * wh[k]; a1 += xr[k + 1] * wh[k + 1];
            a2 += xr[k + 2] * wh[k + 2]; a3 += xr[k + 3] * wh[k + 3];
        }
#pragma unroll
        for (int k = 0; k < 24; k += 4) {
            a0 += pr[k] * wh[40 + k]; a1 += pr[k + 1] * wh[41 + k];
            a2 += pr[k + 2] * wh[42 + k]; a3 += pr[k + 3] * wh[43 + k];
        }
        float p0 = 0, p1 = 0, p2 = 0, p3 = 0;
#pragma unroll
        for (int k = 0; k < 24; k += 4) {
            p0 += pr[k] * wp[k]; p1 += pr[k + 1] * wp[k + 1];
            p2 += pr[k + 2] * wp[k + 2]; p3 += pr[k + 3] * wp[k + 3];
        }
        h[(size_t)nu * 64 + lane] = a0 + a1 + a2 + a3 + bh;
        ph[(size_t)nu * 64 + lane] = p0 + p1 + p2 + p3 + bp;
    }
}

// ---------------- per-layer node precompute (A|PA into stab, B|PB into rtab) -------
__global__ __launch_bounds__(256) void k_nodepre(
    const float* __restrict__ h, const float* __restrict__ ph,
    const float* __restrict__ mW1, const float* __restrict__ mb1,
    const float* __restrict__ pW1g, const float* __restrict__ pb1,
    int layer,
    float* __restrict__ stab, float* __restrict__ rtab,
    float* __restrict__ h2, float* __restrict__ ph2)
{
    const int lane = threadIdx.x & 63;
    const int z = blockIdx.y;
    const int wid = (blockIdx.x << 2) + (threadIdx.x >> 6);
    const int nw = gridDim.x << 2;
    const float* W1 = mW1 + (size_t)layer * 16448;   // 257*64
    const float* PW1 = pW1g + (size_t)layer * 8256;  // 129*64

    float w[128];
    if (z == 0) {
#pragma unroll
        for (int k = 0; k < 128; k++) w[k] = W1[k * 64 + lane];
    } else if (z == 1) {
#pragma unroll
        for (int k = 0; k < 128; k++) w[k] = W1[(128 + k) * 64 + lane];
    } else {
#pragma unroll
        for (int k = 0; k < 128; k++) w[k] = PW1[k * 64 + lane];
    }
    const float bB = mb1[layer * 64 + lane];
    const float bPB = pb1[layer * 64 + lane];

    for (int n = wid; n < NN; n += nw) {
        const int nu = __builtin_amdgcn_readfirstlane(n);
        const float* hr = h + (size_t)nu * 64;
        const float* pr = ph + (size_t)nu * 64;
        if (z == 0) {
            float a0 = 0, a1 = 0, a2 = 0, a3 = 0;
#pragma unroll
            for (int k = 0; k < 64; k += 4) {
                a0 += hr[k] * w[k]; a1 += hr[k + 1] * w[k + 1];
                a2 += hr[k + 2] * w[k + 2]; a3 += hr[k + 3] * w[k + 3];
            }
#pragma unroll
            for (int k = 0; k < 64; k += 4) {
                a0 += pr[k] * w[64 + k]; a1 += pr[k + 1] * w[65 + k];
                a2 += pr[k + 2] * w[66 + k]; a3 += pr[k + 3] * w[67 + k];
            }
            stab[(size_t)nu * 128 + lane] = a0 + a1 + a2 + a3;
            h2[(size_t)nu * 64 + lane] = 2.f * hr[lane];
        } else if (z == 1) {
            float a0 = 0, a1 = 0, a2 = 0, a3 = 0;
#pragma unroll
            for (int k = 0; k < 64; k += 4) {
                a0 += hr[k] * w[k]; a1 += hr[k + 1] * w[k + 1];
                a2 += hr[k + 2] * w[k + 2]; a3 += hr[k + 3] * w[k + 3];
            }
#pragma unroll
            for (int k = 0; k < 64; k += 4) {
                a0 += pr[k] * w[64 + k]; a1 += pr[k + 1] * w[65 + k];
                a2 += pr[k + 2] * w[66 + k]; a3 += pr[k + 3] * w[67 + k];
            }
            rtab[(size_t)nu * 128 + lane] = a0 + a1 + a2 + a3 + bB;
        } else {
            float a0 = 0, a1 = 0, a2 = 0, a3 = 0;
            float b0 = 0, b1v = 0, b2 = 0, b3 = 0;
#pragma unroll
            for (int k = 0; k < 64; k += 4) {
                float v0 = pr[k], v1 = pr[k + 1], v2 = pr[k + 2], v3 = pr[k + 3];
                a0 += v0 * w[k]; a1 += v1 * w[k + 1]; a2 += v2 * w[k + 2]; a3 += v3 * w[k + 3];
                b0 += v0 * w[64 + k]; b1v += v1 * w[65 + k]; b2 += v2 * w[66 + k]; b3 += v3 * w[67 + k];
            }
            stab[(size_t)nu * 128 + 64 + lane] = a0 + a1 + a2 + a3;
            rtab[(size_t)nu * 128 + 64 + lane] = b0 + b1v + b2 + b3 + bPB;
            ph2[(size_t)nu * 64 + lane] = 2.f * pr[lane];
        }
    }
}

// ---------------- edge kernel: sorted edges, MFMA, segmented-reduce flush ----------
__global__ __launch_bounds__(256) void k_edge(
    const int* __restrict__ ssend, const int* __restrict__ srec,
    const float* __restrict__ sdist,
    const float* __restrict__ stab, const float* __restrict__ rtab,
    const float* __restrict__ mW1, const float* __restrict__ mb2,
    const float* __restrict__ pW1g, const float* __restrict__ pb2,
    const unsigned short* __restrict__ W2T, const unsigned short* __restrict__ pW2T,
    int layer,
    float* __restrict__ hout, float* __restrict__ pout)
{
    __shared__ __align__(16) float mh[4][16][64];
    __shared__ __align__(16) float mp[4][16][64];
    const int lane = threadIdx.x & 63;
    const int wv = threadIdx.x >> 6;
    const int l15 = lane & 15, q = lane >> 4;

    const int chunk = (blockIdx.x << 2) + wv;       // 64 edges per wave
    if (chunk >= NE / 64) return;

    const float w1l = mW1[(size_t)layer * 16448 + 16384 + lane];   // W1 row 256 (dist)
    const float pw1l = pW1g[(size_t)layer * 8256 + 8192 + lane];   // pW1 row 128 (dist)

    bf16x8 wb[8], pwb[8];
    {
        const unsigned short* w2 = W2T + layer * 4096;
        const unsigned short* pw2 = pW2T + layer * 4096;
#pragma unroll
        for (int jt = 0; jt < 4; jt++)
#pragma unroll
            for (int kk = 0; kk < 2; kk++) {
                int off = (jt * 16 + l15) * 64 + kk * 32 + q * 8;
                wb[jt * 2 + kk]  = __builtin_bit_cast(bf16x8, *(const us8*)(w2 + off));
                pwb[jt * 2 + kk] = __builtin_bit_cast(bf16x8, *(const us8*)(pw2 + off));
            }
    }
    float b2v[4], pb2v[4];
#pragma unroll
    for (int jt = 0; jt < 4; jt++) {
        b2v[jt] = mb2[layer * 64 + jt * 16 + l15];
        pb2v[jt] = pb2[layer * 64 + jt * 16 + l15];
    }

    float acch = 0.f, accp = 0.f;
    int cur = -1;
    int prev_re = -1;
    float Bv = 0.f, PBv = 0.f;

    for (int t = 0; t < 4; t++) {
        const int ebase = chunk * 64 + t * 16;
        int sv = ssend[ebase + l15];
        int rv = srec[ebase + l15];
        float dv = sdist[ebase + l15];

#pragma unroll 4
        for (int e = 0; e < 16; e++) {
            int se = __shfl(sv, e);
            int re = __shfl(rv, e);
            float de = __shfl(dv, e);
            const float* sr = stab + (size_t)se * 128;
            float Av = sr[lane], PAv = sr[64 + lane];
            if (re != prev_re) {
                const float* rr_ = rtab + (size_t)re * 128;
                Bv = rr_[lane]; PBv = rr_[64 + lane];
                prev_re = re;
            }
            mh[wv][e][lane] = silu_f(Av + Bv + de * w1l);
            mp[wv][e][lane] = tanh_f(PAv + PBv + de * pw1l);
        }

        // ---- msg second layer (overwrite mh rows with final messages) ----
        {
            const float* tr = &mh[wv][l15][0];
            f32x4 u0 = *(const f32x4*)(tr + q * 8);
            f32x4 u1 = *(const f32x4*)(tr + q * 8 + 4);
            f32x4 u2 = *(const f32x4*)(tr + 32 + q * 8);
            f32x4 u3 = *(const f32x4*)(tr + 32 + q * 8 + 4);
            bf16x8 a0, a1;
#pragma unroll
            for (int i = 0; i < 4; i++) {
                a0[i] = f2bf(u0[i]); a0[4 + i] = f2bf(u1[i]);
                a1[i] = f2bf(u2[i]); a1[4 + i] = f2bf(u3[i]);
            }
            f32x4 accs[4];
#pragma unroll
            for (int jt = 0; jt < 4; jt++) {
                f32x4 acc = {0.f, 0.f, 0.f, 0.f};
                acc = __builtin_amdgcn_mfma_f32_16x16x32_bf16(a0, wb[jt * 2 + 0], acc, 0, 0, 0);
                acc = __builtin_amdgcn_mfma_f32_16x16x32_bf16(a1, wb[jt * 2 + 1], acc, 0, 0, 0);
                accs[jt] = acc;
            }
#pragma unroll
            for (int jt = 0; jt < 4; jt++)
#pragma unroll
                for (int i = 0; i < 4; i++)
                    mh[wv][q * 4 + i][jt * 16 + l15] = silu_f(accs[jt][i] + b2v[jt]);
        }
        // ---- pmsg second layer ----
        {
            const float* tr = &mp[wv][l15][0];
            f32x4 u0 = *(const f32x4*)(tr + q * 8);
            f32x4 u1 = *(const f32x4*)(tr + q * 8 + 4);
            f32x4 u2 = *(const f32x4*)(tr + 32 + q * 8);
            f32x4 u3 = *(const f32x4*)(tr + 32 + q * 8 + 4);
            bf16x8 a0, a1;
#pragma unroll
            for (int i = 0; i < 4; i++) {
                a0[i] = f2bf(u0[i]); a0[4 + i] = f2bf(u1[i]);
                a1[i] = f2bf(u2[i]); a1[4 + i] = f2bf(u3[i]);
            }
            f32x4 accs[4];
#pragma unroll
            for (int jt = 0; jt < 4; jt++) {
                f32x4 acc = {0.f, 0.f, 0.f, 0.f};
                acc = __builtin_amdgcn_mfma_f32_16x16x32_bf16(a0, pwb[jt * 2 + 0], acc, 0, 0, 0);
                acc = __builtin_amdgcn_mfma_f32_16x16x32_bf16(a1, pwb[jt * 2 + 1], acc, 0, 0, 0);
                accs[jt] = acc;
            }
#pragma unroll
            for (int jt = 0; jt < 4; jt++)
#pragma unroll
                for (int i = 0; i < 4; i++)
                    mp[wv][q * 4 + i][jt * 16 + l15] = tanh_f(accs[jt][i] + pb2v[jt]);
        }

        // ---- segmented reduce over sorted receivers ----
        for (int e = 0; e < 16; e++) {
            int re = __shfl(rv, e);
            if (re != cur) {
                if (cur >= 0) {
                    atomicAdd(&hout[(size_t)cur * 64 + lane], acch);
                    atomicAdd(&pout[(size_t)cur * 64 + lane], accp);
                }
                cur = re; acch = 0.f; accp = 0.f;
            }
            acch += mh[wv][e][lane];
            accp += mp[wv][e][lane];
        }
    }
    if (cur >= 0) {
        atomicAdd(&hout[(size_t)cur * 64 + lane], acch);
        atomicAdd(&pout[(size_t)cur * 64 + lane], accp);
    }
}

// ---------------- final node MLP + pooling ----------------
__global__ __launch_bounds__(256) void k_prepool(
    const float* __restrict__ h, const int* __restrict__ batch,
    const float* __restrict__ W1, const float* __restrict__ b1,
    const float* __restrict__ W2, const float* __restrict__ b2,
    float* __restrict__ pooled)
{
    __shared__ __align__(16) float tl[4][64];
    const int lane = threadIdx.x & 63;
    const int wv = threadIdx.x >> 6;
    float w1[64], w2[64];
#pragma unroll
    for (int k = 0; k < 64; k++) { w1[k] = W1[k * 64 + lane]; w2[k] = W2[k * 64 + lane]; }
    const float bb1 = b1[lane], bb2 = b2[lane];
    const int wid = (blockIdx.x << 2) + wv;
    const int nw = gridDim.x << 2;
    for (int n = wid; n < NN; n += nw) {
        const int nu = __builtin_amdgcn_readfirstlane(n);
        const float* hr = h + (size_t)nu * 64;
        float a0 = 0, a1 = 0, a2 = 0, a3 = 0;
#pragma unroll
        for (int k = 0; k < 64; k += 4) {
            a0 += hr[k] * w1[k]; a1 += hr[k + 1] * w1[k + 1];
            a2 += hr[k + 2] * w1[k + 2]; a3 += hr[k + 3] * w1[k + 3];
        }
        tl[wv][lane] = silu_f(a0 + a1 + a2 + a3 + bb1);
        float c0 = 0, c1 = 0, c2 = 0, c3 = 0;
        const f32x4* tp4 = (const f32x4*)&tl[wv][0];
#pragma unroll
        for (int k4 = 0; k4 < 16; k4++) {
            f32x4 tv = tp4[k4];
            c0 += tv[0] * w2[k4 * 4]; c1 += tv[1] * w2[k4 * 4 + 1];
            c2 += tv[2] * w2[k4 * 4 + 2]; c3 += tv[3] * w2[k4 * 4 + 3];
        }
        float hp = c0 + c1 + c2 + c3 + bb2;
        int gidx = batch[nu];
        atomicAdd(&pooled[(size_t)gidx * 64 + lane], hp);
    }
}

// ---------------- readout ----------------
__global__ __launch_bounds__(256) void k_readout(
    const float* __restrict__ pooled,
    const float* __restrict__ W1, const float* __restrict__ b1,
    const float* __restrict__ W2, const float* __restrict__ b2,
    float* __restrict__ out)
{
    const int lane = threadIdx.x & 63;
    const int wv = threadIdx.x >> 6;
    const int g = (blockIdx.x << 2) + wv;
    if (g >= NG) return;
    const float* pr = pooled + (size_t)g * 64;
    float a0 = 0, a1 = 0, a2 = 0, a3 = 0;
#pragma unroll
    for (int k = 0; k < 64; k += 4) {
        a0 += pr[k] * W1[k * 64 + lane]; a1 += pr[k + 1] * W1[(k + 1) * 64 + lane];
        a2 += pr[k + 2] * W1[(k + 2) * 64 + lane]; a3 += pr[k + 3] * W1[(k + 3) * 64 + lane];
    }
    float v = silu_f(a0 + a1 + a2 + a3 + b1[lane]) * W2[lane];
#pragma unroll
    for (int off = 32; off > 0; off >>= 1) v += __shfl_down(v, off);
    if (lane == 0) out[g] = v + b2[0];
}

extern "C" void kernel_launch(void* const* d_in, const int* in_sizes, int n_in,
                              void* d_out, int out_size, void* d_ws, size_t ws_size,
                              hipStream_t stream)
{
    const float* x = (const float*)d_in[0];
    const float* pos = (const float*)d_in[1];
    const float* pe = (const float*)d_in[2];
    const int* eidx = (const int*)d_in[3];
    const int* batch = (const int*)d_in[4];
    const float* eW = (const float*)d_in[5];
    const float* eb = (const float*)d_in[6];
    const float* epW = (const float*)d_in[7];
    const float* epb = (const float*)d_in[8];
    const float* mW1 = (const float*)d_in[9];
    const float* mb1 = (const float*)d_in[10];
    const float* mW2 = (const float*)d_in[11];
    const float* mb2 = (const float*)d_in[12];
    const float* pW1 = (const float*)d_in[13];
    const float* pb1 = (const float*)d_in[14];
    const float* pW2 = (const float*)d_in[15];
    const float* pb2 = (const float*)d_in[16];
    const float* preW1 = (const float*)d_in[17];
    const float* preb1 = (const float*)d_in[18];
    const float* preW2 = (const float*)d_in[19];
    const float* preb2 = (const float*)d_in[20];
    const float* roW1 = (const float*)d_in[21];
    const float* rob1 = (const float*)d_in[22];
    const float* roW2 = (const float*)d_in[23];
    const float* rob2 = (const float*)d_in[24];

    const int* send = eidx;
    const int* rcv = eidx + NE;

    float* f = (float*)d_ws;
    size_t o = 0;
    float* hA = f + o; o += (size_t)NN * 64;
    float* hB = f + o; o += (size_t)NN * 64;
    float* phA = f + o; o += (size_t)NN * 64;
    float* phB = f + o; o += (size_t)NN * 64;
    float* stab = f + o; o += (size_t)NN * 128;
    float* rtab = f + o; o += (size_t)NN * 128;
    float* pooled = f + o; o += NG * 64;
    unsigned short* W2T = (unsigned short*)(f + o); o += 8192;   // 4*64*64 ushorts
    unsigned short* pW2T = (unsigned short*)(f + o); o += 8192;
    int* hist = (int*)(f + o); o += NN;
    int* cursor = (int*)(f + o); o += NN;
    int* ssend = (int*)(f + o); o += NE;
    int* srec = (int*)(f + o); o += NE;
    float* sdist = f + o; o += NE;

    hipMemsetAsync(pooled, 0, NG * 64 * sizeof(float), stream);
    hipMemsetAsync(hist, 0, NN * sizeof(int), stream);
    k_wprep<<<64, 256, 0, stream>>>(mW2, pW2, W2T, pW2T);
    k_hist<<<(NE + 255) / 256, 256, 0, stream>>>(rcv, hist);
    k_scan<<<1, 1024, 0, stream>>>(hist, cursor);
    k_scatter<<<(NE + 255) / 256, 256, 0, stream>>>(send, rcv, pos, cursor, ssend, srec, sdist);
    k_embed<<<256, 256, 0, stream>>>(x, pe, eW, eb, epW, epb, hA, phA);

    float* hin = hA; float* pin = phA; float* hout = hB; float* pout = phB;
    for (int l = 0; l < 4; l++) {
        k_nodepre<<<dim3(256, 3), 256, 0, stream>>>(hin, pin, mW1, mb1, pW1, pb1, l,
                                                    stab, rtab, hout, pout);
        k_edge<<<(NE / 64 + 3) / 4, 256, 0, stream>>>(ssend, srec, sdist, stab, rtab,
                                                      mW1, mb2, pW1, pb2, W2T, pW2T, l, hout, pout);
        float* t;
        t = hin; hin = hout; hout = t;
        t = pin; pin = pout; pout = t;
    }
    k_prepool<<<256, 256, 0, stream>>>(hin, batch, preW1, preb1, preW2, preb2, pooled);
    k_readout<<<128, 256, 0, stream>>>(pooled, roW1, rob1, roW2, rob2, (float*)d_out);
}

// Round 3
// 741.846 us; speedup vs baseline: 1.8109x; 1.6305x over previous
//
#include <hip/hip_runtime.h>

#define NN 50000
#define NE 400000
#define NG 512

typedef __bf16 bf16x8 __attribute__((ext_vector_type(8)));
typedef float f32x4 __attribute__((ext_vector_type(4)));
typedef unsigned short us8 __attribute__((ext_vector_type(8)));

__device__ __forceinline__ float frcp(float x) { return __builtin_amdgcn_rcpf(x); }
__device__ __forceinline__ float silu_f(float x) { return x * frcp(1.f + __expf(-x)); }
__device__ __forceinline__ float tanh_f(float x) { return 1.f - 2.f * frcp(__expf(2.f * x) + 1.f); }
__device__ __forceinline__ __bf16 f2bf(float f) {
    unsigned u = __builtin_bit_cast(unsigned, f);
    u += 0x7fffu + ((u >> 16) & 1u);
    unsigned short s = (unsigned short)(u >> 16);
    return __builtin_bit_cast(__bf16, s);
}
__device__ __forceinline__ unsigned short f2bfu(float f) {
    return __builtin_bit_cast(unsigned short, f2bf(f));
}
__device__ __forceinline__ float bf2f(__bf16 b) {
    unsigned short s = __builtin_bit_cast(unsigned short, b);
    unsigned u = ((unsigned)s) << 16;
    return __builtin_bit_cast(float, u);
}

// ---------------- weight prep ----------------
// Part1: W2T[l][j][k] = bf16(msg_W2[l][k][j])           (for k_edge)
// Part2: Wswz[l]: WcatT (256 rows=out-col, 128 k) bf16, 16B-chunk XOR-swizzled
// Part3: WembSwz: WembT (128 rows=out-col, 64 k) bf16, swizzled
// Part4: biascat[l][256], biasemb[128]
__global__ __launch_bounds__(256) void k_wprep(
    const float* __restrict__ mW1, const float* __restrict__ mb1,
    const float* __restrict__ mW2, const float* __restrict__ pW1,
    const float* __restrict__ pb1, const float* __restrict__ pW2,
    const float* __restrict__ eW, const float* __restrict__ eb,
    const float* __restrict__ epW, const float* __restrict__ epb,
    unsigned short* __restrict__ W2T, unsigned short* __restrict__ pW2T,
    unsigned short* __restrict__ Wswz, float* __restrict__ biascat,
    unsigned short* __restrict__ WembSwz, float* __restrict__ biasemb)
{
    int idx = blockIdx.x * 256 + threadIdx.x;
    if (idx < 16384) {
        int l = idx >> 12, r = idx & 4095;
        int j = r >> 6, k = r & 63;
        int src = l * 4096 + k * 64 + j;
        W2T[idx] = f2bfu(mW2[src]);
        pW2T[idx] = f2bfu(pW2[src]);
    }
    if (idx < 131072) {
        int l = idx >> 15, rem = idx & 32767;
        int r = rem >> 7, k = rem & 127;          // r = out col 0..255, k = 0..127
        const float* W1l = mW1 + (size_t)l * 16448;
        const float* pW1l = pW1 + (size_t)l * 8256;
        float v;
        if (r < 64)        v = W1l[k * 64 + r];                                    // A
        else if (r < 128)  v = (k >= 64) ? pW1l[(k - 64) * 64 + (r - 64)] : 0.f;   // PA
        else if (r < 192)  v = W1l[(128 + k) * 64 + (r - 128)];                    // B
        else               v = (k >= 64) ? pW1l[k * 64 + (r - 192)] : 0.f;         // PB
        int c = k >> 3, e = k & 7;
        int cs = c ^ (r & 15);
        Wswz[(size_t)l * 32768 + r * 128 + cs * 8 + e] = f2bfu(v);
    }
    if (idx < 8192) {
        int r = idx >> 6, k = idx & 63;           // r = out col 0..127, k = 0..63
        float v;
        if (r < 64) v = eW[k * 64 + r];
        else        v = (k >= 40) ? epW[(k - 40) * 64 + (r - 64)] : 0.f;
        int c = k >> 3, e = k & 7;
        int cs = c ^ (r & 7);
        WembSwz[r * 64 + cs * 8 + e] = f2bfu(v);
    }
    if (idx < 1024) {
        int l = idx >> 8, col = idx & 255;
        float b = 0.f;
        if (col >= 128 && col < 192) b = mb1[l * 64 + col - 128];
        else if (col >= 192)         b = pb1[l * 64 + col - 192];
        biascat[idx] = b;
    }
    if (idx < 128) biasemb[idx] = (idx < 64) ? eb[idx] : epb[idx - 64];
}

// ---------------- counting sort by receiver ----------------
__global__ void k_hist(const int* __restrict__ rec, int* __restrict__ hist)
{
    int e = blockIdx.x * 256 + threadIdx.x;
    if (e < NE) atomicAdd(&hist[rec[e]], 1);
}

__global__ __launch_bounds__(1024) void k_scan(const int* __restrict__ hist, int* __restrict__ cursor)
{
    __shared__ int wsum[16];
    const int t = threadIdx.x;
    const int lane = t & 63, w = t >> 6;
    const int PER = 49;
    const int base = t * PER;
    int s = 0;
    for (int i = 0; i < PER; i++) { int idx = base + i; if (idx < NN) s += hist[idx]; }
    int pre = s;
#pragma unroll
    for (int d = 1; d < 64; d <<= 1) { int o = __shfl_up(pre, d); if (lane >= d) pre += o; }
    if (lane == 63) wsum[w] = pre;
    __syncthreads();
    if (w == 0) {
        int v = (lane < 16) ? wsum[lane] : 0;
        int p = v;
#pragma unroll
        for (int d = 1; d < 16; d <<= 1) { int o = __shfl_up(p, d); if (lane >= d) p += o; }
        if (lane < 16) wsum[lane] = p - v;
    }
    __syncthreads();
    int run = wsum[w] + (pre - s);
    for (int i = 0; i < PER; i++) {
        int idx = base + i;
        if (idx < NN) { cursor[idx] = run; run += hist[idx]; }
    }
}

__global__ void k_scatter(const int* __restrict__ send, const int* __restrict__ rec,
                          const float* __restrict__ pos, int* __restrict__ cursor,
                          int* __restrict__ ssend, int* __restrict__ srec,
                          float* __restrict__ sdist)
{
    int e = blockIdx.x * 256 + threadIdx.x;
    if (e >= NE) return;
    int s = send[e], r = rec[e];
    int p = atomicAdd(&cursor[r], 1);
    float dx = pos[s * 3 + 0] - pos[r * 3 + 0];
    float dy = pos[s * 3 + 1] - pos[r * 3 + 1];
    float dz = pos[s * 3 + 2] - pos[r * 3 + 2];
    ssend[p] = s; srec[p] = r;
    sdist[p] = sqrtf(dx * dx + dy * dy + dz * dz);
}

// ---------------- embed GEMM: [h|ph] = [x|pe] @ Wemb + bias ----------------
__global__ __launch_bounds__(256) void k_embed_gemm(
    const float* __restrict__ x, const float* __restrict__ pe,
    const unsigned short* __restrict__ Wswz, const float* __restrict__ bias,
    float* __restrict__ h, float* __restrict__ ph)
{
    __shared__ __align__(16) unsigned short wlds[8192];   // 128 rows x 64 k, 16KB
    const int t = threadIdx.x;
    const int lane = t & 63, wv = t >> 6;
    const int l15 = lane & 15, q = lane >> 4;
    {
        const us8* src = (const us8*)Wswz;
        us8* dst = (us8*)wlds;
#pragma unroll
        for (int it = 0; it < 4; it++) dst[it * 256 + t] = src[it * 256 + t];
    }
    __syncthreads();

    const int NT = NN / 16;  // 3125
    for (int tile = blockIdx.x * 4 + wv; tile < NT; tile += gridDim.x * 4) {
        const int rb = tile * 16;
        const int row = rb + l15;
        f32x4 uf[4];
        const float* p0 = x + (size_t)row * 40 + q * 8;
        const float* p1 = (q == 0) ? (x + (size_t)row * 40 + 32)
                                   : (pe + (size_t)row * 24 + (q - 1) * 8);
        uf[0] = *(const f32x4*)(p0);
        uf[1] = *(const f32x4*)(p0 + 4);
        uf[2] = *(const f32x4*)(p1);
        uf[3] = *(const f32x4*)(p1 + 4);
        bf16x8 af[2];
#pragma unroll
        for (int ks = 0; ks < 2; ks++)
#pragma unroll
            for (int i = 0; i < 4; i++) {
                af[ks][i]     = f2bf(uf[ks * 2][i]);
                af[ks][4 + i] = f2bf(uf[ks * 2 + 1][i]);
            }
        f32x4 acc[8];
#pragma unroll
        for (int jt = 0; jt < 8; jt++) acc[jt] = (f32x4){0.f, 0.f, 0.f, 0.f};
#pragma unroll
        for (int jt = 0; jt < 8; jt++) {
            int r = jt * 16 + l15;
#pragma unroll
            for (int ks = 0; ks < 2; ks++) {
                int c = (ks * 4 + q) ^ (l15 & 7);
                bf16x8 bfr = *(const bf16x8*)&wlds[r * 64 + c * 8];
                acc[jt] = __builtin_amdgcn_mfma_f32_16x16x32_bf16(af[ks], bfr, acc[jt], 0, 0, 0);
            }
        }
#pragma unroll
        for (int jt = 0; jt < 8; jt++) {
            int col = jt * 16 + l15;
            float bv = bias[col];
            float* outp = (jt < 4) ? (h + (size_t)(rb + q * 4) * 64 + col)
                                   : (ph + (size_t)(rb + q * 4) * 64 + (col - 64));
#pragma unroll
            for (int i = 0; i < 4; i++)
                outp[(size_t)i * 64] = acc[jt][i] + bv;
        }
    }
}

// ---------------- node GEMM: [stab|rtab] = [h|ph] @ Wcat + bias; h2=2h; ph2=2ph ----
__global__ __launch_bounds__(256) void k_node_gemm(
    const float* __restrict__ h, const float* __restrict__ ph,
    const unsigned short* __restrict__ Wswz,   // + layer*32768
    const float* __restrict__ bias,            // + layer*256
    float* __restrict__ stab, float* __restrict__ rtab,
    float* __restrict__ h2, float* __restrict__ ph2)
{
    __shared__ __align__(16) unsigned short wlds[32768];   // 256 rows x 128 k, 64KB
    const int t = threadIdx.x;
    const int lane = t & 63, wv = t >> 6;
    const int l15 = lane & 15, q = lane >> 4;
    {
        const us8* src = (const us8*)Wswz;
        us8* dst = (us8*)wlds;
#pragma unroll
        for (int it = 0; it < 16; it++) dst[it * 256 + t] = src[it * 256 + t];
    }
    __syncthreads();

    const int NT = NN / 16;  // 3125
    for (int tile = blockIdx.x * 4 + wv; tile < NT; tile += gridDim.x * 4) {
        const int rb = tile * 16;
        const int row = rb + l15;
        const float* hr = h + (size_t)row * 64;
        const float* pr = ph + (size_t)row * 64;
        f32x4 uf[8];
#pragma unroll
        for (int ks = 0; ks < 2; ks++) {
            uf[ks * 2 + 0] = *(const f32x4*)(hr + ks * 32 + q * 8);
            uf[ks * 2 + 1] = *(const f32x4*)(hr + ks * 32 + q * 8 + 4);
            uf[4 + ks * 2 + 0] = *(const f32x4*)(pr + ks * 32 + q * 8);
            uf[4 + ks * 2 + 1] = *(const f32x4*)(pr + ks * 32 + q * 8 + 4);
        }
        // hi/lo bf16 split for precision (u = hi + lo to ~fp16+ accuracy)
        bf16x8 ahi[4], alo[4];
#pragma unroll
        for (int ks = 0; ks < 4; ks++)
#pragma unroll
            for (int i = 0; i < 4; i++) {
                float v0 = uf[ks * 2][i], v1 = uf[ks * 2 + 1][i];
                __bf16 h0 = f2bf(v0), h1 = f2bf(v1);
                ahi[ks][i] = h0; ahi[ks][4 + i] = h1;
                alo[ks][i] = f2bf(v0 - bf2f(h0));
                alo[ks][4 + i] = f2bf(v1 - bf2f(h1));
            }
        f32x4 acc[16];
#pragma unroll
        for (int jt = 0; jt < 16; jt++) acc[jt] = (f32x4){0.f, 0.f, 0.f, 0.f};
#pragma unroll
        for (int jt = 0; jt < 16; jt++) {
            int r = jt * 16 + l15;
#pragma unroll
            for (int ks = 0; ks < 4; ks++) {
                int c = (ks * 4 + q) ^ l15;
                bf16x8 bfr = *(const bf16x8*)&wlds[r * 128 + c * 8];
                acc[jt] = __builtin_amdgcn_mfma_f32_16x16x32_bf16(ahi[ks], bfr, acc[jt], 0, 0, 0);
                acc[jt] = __builtin_amdgcn_mfma_f32_16x16x32_bf16(alo[ks], bfr, acc[jt], 0, 0, 0);
            }
        }
#pragma unroll
        for (int jt = 0; jt < 16; jt++) {
            int col = jt * 16 + l15;
            float bv = bias[col];
            float* outp = (jt < 8) ? (stab + (size_t)(rb + q * 4) * 128 + col)
                                   : (rtab + (size_t)(rb + q * 4) * 128 + (col - 128));
#pragma unroll
            for (int i = 0; i < 4; i++)
                outp[(size_t)i * 128] = acc[jt][i] + bv;
        }
        // h2 = 2h, ph2 = 2ph (exact, from f32 regs)
#pragma unroll
        for (int ks = 0; ks < 2; ks++) {
            *(f32x4*)(h2 + (size_t)row * 64 + ks * 32 + q * 8)     = uf[ks * 2] + uf[ks * 2];
            *(f32x4*)(h2 + (size_t)row * 64 + ks * 32 + q * 8 + 4) = uf[ks * 2 + 1] + uf[ks * 2 + 1];
            *(f32x4*)(ph2 + (size_t)row * 64 + ks * 32 + q * 8)     = uf[4 + ks * 2] + uf[4 + ks * 2];
            *(f32x4*)(ph2 + (size_t)row * 64 + ks * 32 + q * 8 + 4) = uf[4 + ks * 2 + 1] + uf[4 + ks * 2 + 1];
        }
    }
}

// ---------------- edge kernel: sorted edges, MFMA, segmented-reduce flush ----------
__global__ __launch_bounds__(256) void k_edge(
    const int* __restrict__ ssend, const int* __restrict__ srec,
    const float* __restrict__ sdist,
    const float* __restrict__ stab, const float* __restrict__ rtab,
    const float* __restrict__ mW1, const float* __restrict__ mb2,
    const float* __restrict__ pW1g, const float* __restrict__ pb2,
    const unsigned short* __restrict__ W2T, const unsigned short* __restrict__ pW2T,
    int layer,
    float* __restrict__ hout, float* __restrict__ pout)
{
    __shared__ __align__(16) float mh[4][16][64];
    __shared__ __align__(16) float mp[4][16][64];
    const int lane = threadIdx.x & 63;
    const int wv = threadIdx.x >> 6;
    const int l15 = lane & 15, q = lane >> 4;

    const int chunk = (blockIdx.x << 2) + wv;
    if (chunk >= NE / 64) return;

    const float w1l = mW1[(size_t)layer * 16448 + 16384 + lane];
    const float pw1l = pW1g[(size_t)layer * 8256 + 8192 + lane];

    bf16x8 wb[8], pwb[8];
    {
        const unsigned short* w2 = W2T + layer * 4096;
        const unsigned short* pw2 = pW2T + layer * 4096;
#pragma unroll
        for (int jt = 0; jt < 4; jt++)
#pragma unroll
            for (int kk = 0; kk < 2; kk++) {
                int off = (jt * 16 + l15) * 64 + kk * 32 + q * 8;
                wb[jt * 2 + kk]  = __builtin_bit_cast(bf16x8, *(const us8*)(w2 + off));
                pwb[jt * 2 + kk] = __builtin_bit_cast(bf16x8, *(const us8*)(pw2 + off));
            }
    }
    float b2v[4], pb2v[4];
#pragma unroll
    for (int jt = 0; jt < 4; jt++) {
        b2v[jt] = mb2[layer * 64 + jt * 16 + l15];
        pb2v[jt] = pb2[layer * 64 + jt * 16 + l15];
    }

    float acch = 0.f, accp = 0.f;
    int cur = -1;
    int prev_re = -1;
    float Bv = 0.f, PBv = 0.f;

    for (int t = 0; t < 4; t++) {
        const int ebase = chunk * 64 + t * 16;
        int sv = ssend[ebase + l15];
        int rv = srec[ebase + l15];
        float dv = sdist[ebase + l15];

#pragma unroll 4
        for (int e = 0; e < 16; e++) {
            int se = __shfl(sv, e);
            int re = __shfl(rv, e);
            float de = __shfl(dv, e);
            const float* sr = stab + (size_t)se * 128;
            float Av = sr[lane], PAv = sr[64 + lane];
            if (re != prev_re) {
                const float* rr_ = rtab + (size_t)re * 128;
                Bv = rr_[lane]; PBv = rr_[64 + lane];
                prev_re = re;
            }
            mh[wv][e][lane] = silu_f(Av + Bv + de * w1l);
            mp[wv][e][lane] = tanh_f(PAv + PBv + de * pw1l);
        }

        {
            const float* tr = &mh[wv][l15][0];
            f32x4 u0 = *(const f32x4*)(tr + q * 8);
            f32x4 u1 = *(const f32x4*)(tr + q * 8 + 4);
            f32x4 u2 = *(const f32x4*)(tr + 32 + q * 8);
            f32x4 u3 = *(const f32x4*)(tr + 32 + q * 8 + 4);
            bf16x8 a0, a1;
#pragma unroll
            for (int i = 0; i < 4; i++) {
                a0[i] = f2bf(u0[i]); a0[4 + i] = f2bf(u1[i]);
                a1[i] = f2bf(u2[i]); a1[4 + i] = f2bf(u3[i]);
            }
            f32x4 accs[4];
#pragma unroll
            for (int jt = 0; jt < 4; jt++) {
                f32x4 acc = {0.f, 0.f, 0.f, 0.f};
                acc = __builtin_amdgcn_mfma_f32_16x16x32_bf16(a0, wb[jt * 2 + 0], acc, 0, 0, 0);
                acc = __builtin_amdgcn_mfma_f32_16x16x32_bf16(a1, wb[jt * 2 + 1], acc, 0, 0, 0);
                accs[jt] = acc;
            }
#pragma unroll
            for (int jt = 0; jt < 4; jt++)
#pragma unroll
                for (int i = 0; i < 4; i++)
                    mh[wv][q * 4 + i][jt * 16 + l15] = silu_f(accs[jt][i] + b2v[jt]);
        }
        {
            const float* tr = &mp[wv][l15][0];
            f32x4 u0 = *(const f32x4*)(tr + q * 8);
            f32x4 u1 = *(const f32x4*)(tr + q * 8 + 4);
            f32x4 u2 = *(const f32x4*)(tr + 32 + q * 8);
            f32x4 u3 = *(const f32x4*)(tr + 32 + q * 8 + 4);
            bf16x8 a0, a1;
#pragma unroll
            for (int i = 0; i < 4; i++) {
                a0[i] = f2bf(u0[i]); a0[4 + i] = f2bf(u1[i]);
                a1[i] = f2bf(u2[i]); a1[4 + i] = f2bf(u3[i]);
            }
            f32x4 accs[4];
#pragma unroll
            for (int jt = 0; jt < 4; jt++) {
                f32x4 acc = {0.f, 0.f, 0.f, 0.f};
                acc = __builtin_amdgcn_mfma_f32_16x16x32_bf16(a0, pwb[jt * 2 + 0], acc, 0, 0, 0);
                acc = __builtin_amdgcn_mfma_f32_16x16x32_bf16(a1, pwb[jt * 2 + 1], acc, 0, 0, 0);
                accs[jt] = acc;
            }
#pragma unroll
            for (int jt = 0; jt < 4; jt++)
#pragma unroll
                for (int i = 0; i < 4; i++)
                    mp[wv][q * 4 + i][jt * 16 + l15] = tanh_f(accs[jt][i] + pb2v[jt]);
        }

        for (int e = 0; e < 16; e++) {
            int re = __shfl(rv, e);
            if (re != cur) {
                if (cur >= 0) {
                    atomicAdd(&hout[(size_t)cur * 64 + lane], acch);
                    atomicAdd(&pout[(size_t)cur * 64 + lane], accp);
                }
                cur = re; acch = 0.f; accp = 0.f;
            }
            acch += mh[wv][e][lane];
            accp += mp[wv][e][lane];
        }
    }
    if (cur >= 0) {
        atomicAdd(&hout[(size_t)cur * 64 + lane], acch);
        atomicAdd(&pout[(size_t)cur * 64 + lane], accp);
    }
}

// ---------------- final node MLP + pooling ----------------
__global__ __launch_bounds__(256) void k_prepool(
    const float* __restrict__ h, const int* __restrict__ batch,
    const float* __restrict__ W1, const float* __restrict__ b1,
    const float* __restrict__ W2, const float* __restrict__ b2,
    float* __restrict__ pooled)
{
    __shared__ __align__(16) float tl[4][64];
    const int lane = threadIdx.x & 63;
    const int wv = threadIdx.x >> 6;
    float w1[64], w2[64];
#pragma unroll
    for (int k = 0; k < 64; k++) { w1[k] = W1[k * 64 + lane]; w2[k] = W2[k * 64 + lane]; }
    const float bb1 = b1[lane], bb2 = b2[lane];
    const int wid = (blockIdx.x << 2) + wv;
    const int nw = gridDim.x << 2;
    for (int n = wid; n < NN; n += nw) {
        const int nu = __builtin_amdgcn_readfirstlane(n);
        const float* hr = h + (size_t)nu * 64;
        float a0 = 0, a1 = 0, a2 = 0, a3 = 0;
#pragma unroll
        for (int k = 0; k < 64; k += 4) {
            a0 += hr[k] * w1[k]; a1 += hr[k + 1] * w1[k + 1];
            a2 += hr[k + 2] * w1[k + 2]; a3 += hr[k + 3] * w1[k + 3];
        }
        tl[wv][lane] = silu_f(a0 + a1 + a2 + a3 + bb1);
        float c0 = 0, c1 = 0, c2 = 0, c3 = 0;
        const f32x4* tp4 = (const f32x4*)&tl[wv][0];
#pragma unroll
        for (int k4 = 0; k4 < 16; k4++) {
            f32x4 tv = tp4[k4];
            c0 += tv[0] * w2[k4 * 4]; c1 += tv[1] * w2[k4 * 4 + 1];
            c2 += tv[2] * w2[k4 * 4 + 2]; c3 += tv[3] * w2[k4 * 4 + 3];
        }
        float hp = c0 + c1 + c2 + c3 + bb2;
        int gidx = batch[nu];
        atomicAdd(&pooled[(size_t)gidx * 64 + lane], hp);
    }
}

// ---------------- readout ----------------
__global__ __launch_bounds__(256) void k_readout(
    const float* __restrict__ pooled,
    const float* __restrict__ W1, const float* __restrict__ b1,
    const float* __restrict__ W2, const float* __restrict__ b2,
    float* __restrict__ out)
{
    const int lane = threadIdx.x & 63;
    const int wv = threadIdx.x >> 6;
    const int g = (blockIdx.x << 2) + wv;
    if (g >= NG) return;
    const float* pr = pooled + (size_t)g * 64;
    float a0 = 0, a1 = 0, a2 = 0, a3 = 0;
#pragma unroll
    for (int k = 0; k < 64; k += 4) {
        a0 += pr[k] * W1[k * 64 + lane]; a1 += pr[k + 1] * W1[(k + 1) * 64 + lane];
        a2 += pr[k + 2] * W1[(k + 2) * 64 + lane]; a3 += pr[k + 3] * W1[(k + 3) * 64 + lane];
    }
    float v = silu_f(a0 + a1 + a2 + a3 + b1[lane]) * W2[lane];
#pragma unroll
    for (int off = 32; off > 0; off >>= 1) v += __shfl_down(v, off);
    if (lane == 0) out[g] = v + b2[0];
}

extern "C" void kernel_launch(void* const* d_in, const int* in_sizes, int n_in,
                              void* d_out, int out_size, void* d_ws, size_t ws_size,
                              hipStream_t stream)
{
    const float* x = (const float*)d_in[0];
    const float* pos = (const float*)d_in[1];
    const float* pe = (const float*)d_in[2];
    const int* eidx = (const int*)d_in[3];
    const int* batch = (const int*)d_in[4];
    const float* eW = (const float*)d_in[5];
    const float* eb = (const float*)d_in[6];
    const float* epW = (const float*)d_in[7];
    const float* epb = (const float*)d_in[8];
    const float* mW1 = (const float*)d_in[9];
    const float* mb1 = (const float*)d_in[10];
    const float* mW2 = (const float*)d_in[11];
    const float* mb2 = (const float*)d_in[12];
    const float* pW1 = (const float*)d_in[13];
    const float* pb1 = (const float*)d_in[14];
    const float* pW2 = (const float*)d_in[15];
    const float* pb2 = (const float*)d_in[16];
    const float* preW1 = (const float*)d_in[17];
    const float* preb1 = (const float*)d_in[18];
    const float* preW2 = (const float*)d_in[19];
    const float* preb2 = (const float*)d_in[20];
    const float* roW1 = (const float*)d_in[21];
    const float* rob1 = (const float*)d_in[22];
    const float* roW2 = (const float*)d_in[23];
    const float* rob2 = (const float*)d_in[24];

    const int* send = eidx;
    const int* rcv = eidx + NE;

    float* f = (float*)d_ws;
    size_t o = 0;
    float* hA = f + o; o += (size_t)NN * 64;
    float* hB = f + o; o += (size_t)NN * 64;
    float* phA = f + o; o += (size_t)NN * 64;
    float* phB = f + o; o += (size_t)NN * 64;
    float* stab = f + o; o += (size_t)NN * 128;
    float* rtab = f + o; o += (size_t)NN * 128;
    float* pooled = f + o; o += NG * 64;
    unsigned short* W2T = (unsigned short*)(f + o); o += 8192;
    unsigned short* pW2T = (unsigned short*)(f + o); o += 8192;
    unsigned short* Wswz = (unsigned short*)(f + o); o += 65536;    // 4*32768 bf16
    unsigned short* WembSwz = (unsigned short*)(f + o); o += 4096;  // 8192 bf16
    float* biascat = f + o; o += 1024;
    float* biasemb = f + o; o += 128;
    int* hist = (int*)(f + o); o += NN;
    int* cursor = (int*)(f + o); o += NN;
    int* ssend = (int*)(f + o); o += NE;
    int* srec = (int*)(f + o); o += NE;
    float* sdist = f + o; o += NE;

    hipMemsetAsync(pooled, 0, NG * 64 * sizeof(float), stream);
    hipMemsetAsync(hist, 0, NN * sizeof(int), stream);
    k_wprep<<<512, 256, 0, stream>>>(mW1, mb1, mW2, pW1, pb1, pW2,
                                     eW, eb, epW, epb,
                                     W2T, pW2T, Wswz, biascat, WembSwz, biasemb);
    k_hist<<<(NE + 255) / 256, 256, 0, stream>>>(rcv, hist);
    k_scan<<<1, 1024, 0, stream>>>(hist, cursor);
    k_scatter<<<(NE + 255) / 256, 256, 0, stream>>>(send, rcv, pos, cursor, ssend, srec, sdist);
    k_embed_gemm<<<512, 256, 0, stream>>>(x, pe, WembSwz, biasemb, hA, phA);

    float* hin = hA; float* pin = phA; float* hout = hB; float* pout = phB;
    for (int l = 0; l < 4; l++) {
        k_node_gemm<<<512, 256, 0, stream>>>(hin, pin, Wswz + (size_t)l * 32768,
                                             biascat + l * 256, stab, rtab, hout, pout);
        k_edge<<<(NE / 64 + 3) / 4, 256, 0, stream>>>(ssend, srec, sdist, stab, rtab,
                                                      mW1, mb2, pW1, pb2, W2T, pW2T, l, hout, pout);
        float* t;
        t = hin; hin = hout; hout = t;
        t = pin; pin = pout; pout = t;
    }
    k_prepool<<<256, 256, 0, stream>>>(hin, batch, preW1, preb1, preW2, preb2, pooled);
    k_readout<<<128, 256, 0, stream>>>(pooled, roW1, rob1, roW2, rob2, (float*)d_out);
}

// Round 4
// 653.386 us; speedup vs baseline: 2.0561x; 1.1354x over previous
//
#include <hip/hip_runtime.h>

#define NN 50000
#define NE 400000
#define NG 512

typedef __bf16 bf16x8 __attribute__((ext_vector_type(8)));
typedef float f32x4 __attribute__((ext_vector_type(4)));
typedef unsigned short us8 __attribute__((ext_vector_type(8)));

__device__ __forceinline__ float frcp(float x) { return __builtin_amdgcn_rcpf(x); }
__device__ __forceinline__ float silu_f(float x) { return x * frcp(1.f + __expf(-x)); }
__device__ __forceinline__ float tanh_f(float x) { return 1.f - 2.f * frcp(__expf(2.f * x) + 1.f); }
__device__ __forceinline__ __bf16 f2bf(float f) {
    unsigned u = __builtin_bit_cast(unsigned, f);
    u += 0x7fffu + ((u >> 16) & 1u);
    unsigned short s = (unsigned short)(u >> 16);
    return __builtin_bit_cast(__bf16, s);
}
__device__ __forceinline__ unsigned short f2bfu(float f) {
    return __builtin_bit_cast(unsigned short, f2bf(f));
}
__device__ __forceinline__ float bf2f(__bf16 b) {
    unsigned short s = __builtin_bit_cast(unsigned short, b);
    unsigned u = ((unsigned)s) << 16;
    return __builtin_bit_cast(float, u);
}

// ---------------- weight prep ----------------
__global__ __launch_bounds__(256) void k_wprep(
    const float* __restrict__ mW1, const float* __restrict__ mb1,
    const float* __restrict__ mW2, const float* __restrict__ pW1,
    const float* __restrict__ pb1, const float* __restrict__ pW2,
    const float* __restrict__ eW, const float* __restrict__ eb,
    const float* __restrict__ epW, const float* __restrict__ epb,
    unsigned short* __restrict__ W2T, unsigned short* __restrict__ pW2T,
    unsigned short* __restrict__ Wswz, float* __restrict__ biascat,
    unsigned short* __restrict__ WembSwz, float* __restrict__ biasemb)
{
    int idx = blockIdx.x * 256 + threadIdx.x;
    if (idx < 16384) {
        int l = idx >> 12, r = idx & 4095;
        int j = r >> 6, k = r & 63;
        int src = l * 4096 + k * 64 + j;
        W2T[idx] = f2bfu(mW2[src]);
        pW2T[idx] = f2bfu(pW2[src]);
    }
    if (idx < 131072) {
        int l = idx >> 15, rem = idx & 32767;
        int r = rem >> 7, k = rem & 127;          // r = out col 0..255, k = 0..127
        const float* W1l = mW1 + (size_t)l * 16448;
        const float* pW1l = pW1 + (size_t)l * 8256;
        float v;
        if (r < 64)        v = W1l[k * 64 + r];                                    // A
        else if (r < 128)  v = (k >= 64) ? pW1l[(k - 64) * 64 + (r - 64)] : 0.f;   // PA
        else if (r < 192)  v = W1l[(128 + k) * 64 + (r - 128)];                    // B
        else               v = (k >= 64) ? pW1l[k * 64 + (r - 192)] : 0.f;         // PB
        int c = k >> 3, e = k & 7;
        int cs = c ^ (r & 15);
        Wswz[(size_t)l * 32768 + r * 128 + cs * 8 + e] = f2bfu(v);
    }
    if (idx < 8192) {
        int r = idx >> 6, k = idx & 63;           // r = out col 0..127, k = 0..63
        float v;
        if (r < 64) v = eW[k * 64 + r];
        else        v = (k >= 40) ? epW[(k - 40) * 64 + (r - 64)] : 0.f;
        int c = k >> 3, e = k & 7;
        int cs = c ^ (r & 7);
        WembSwz[r * 64 + cs * 8 + e] = f2bfu(v);
    }
    if (idx < 1024) {
        int l = idx >> 8, col = idx & 255;
        float b = 0.f;
        if (col >= 128 && col < 192) b = mb1[l * 64 + col - 128];
        else if (col >= 192)         b = pb1[l * 64 + col - 192];
        biascat[idx] = b;
    }
    if (idx < 128) biasemb[idx] = (idx < 64) ? eb[idx] : epb[idx - 64];
}

// ---------------- counting sort by receiver ----------------
__global__ void k_hist(const int* __restrict__ rec, int* __restrict__ hist)
{
    int e = blockIdx.x * 256 + threadIdx.x;
    if (e < NE) atomicAdd(&hist[rec[e]], 1);
}

__global__ __launch_bounds__(1024) void k_scan(const int* __restrict__ hist, int* __restrict__ cursor)
{
    __shared__ int wsum[16];
    const int t = threadIdx.x;
    const int lane = t & 63, w = t >> 6;
    const int PER = 49;
    const int base = t * PER;
    int s = 0;
    for (int i = 0; i < PER; i++) { int idx = base + i; if (idx < NN) s += hist[idx]; }
    int pre = s;
#pragma unroll
    for (int d = 1; d < 64; d <<= 1) { int o = __shfl_up(pre, d); if (lane >= d) pre += o; }
    if (lane == 63) wsum[w] = pre;
    __syncthreads();
    if (w == 0) {
        int v = (lane < 16) ? wsum[lane] : 0;
        int p = v;
#pragma unroll
        for (int d = 1; d < 16; d <<= 1) { int o = __shfl_up(p, d); if (lane >= d) p += o; }
        if (lane < 16) wsum[lane] = p - v;
    }
    __syncthreads();
    int run = wsum[w] + (pre - s);
    for (int i = 0; i < PER; i++) {
        int idx = base + i;
        if (idx < NN) { cursor[idx] = run; run += hist[idx]; }
    }
}

__global__ void k_scatter(const int* __restrict__ send, const int* __restrict__ rec,
                          const float* __restrict__ pos, int* __restrict__ cursor,
                          int* __restrict__ ssend, int* __restrict__ srec,
                          float* __restrict__ sdist)
{
    int e = blockIdx.x * 256 + threadIdx.x;
    if (e >= NE) return;
    int s = send[e], r = rec[e];
    int p = atomicAdd(&cursor[r], 1);
    float dx = pos[s * 3 + 0] - pos[r * 3 + 0];
    float dy = pos[s * 3 + 1] - pos[r * 3 + 1];
    float dz = pos[s * 3 + 2] - pos[r * 3 + 2];
    ssend[p] = s; srec[p] = r;
    sdist[p] = sqrtf(dx * dx + dy * dy + dz * dz);
}

// ---------------- embed GEMM: [h|ph] = [x|pe] @ Wemb + bias ----------------
__global__ __launch_bounds__(256) void k_embed_gemm(
    const float* __restrict__ x, const float* __restrict__ pe,
    const unsigned short* __restrict__ Wswz, const float* __restrict__ bias,
    float* __restrict__ h, float* __restrict__ ph)
{
    __shared__ __align__(16) unsigned short wlds[8192];   // 128 rows x 64 k, 16KB
    const int t = threadIdx.x;
    const int lane = t & 63, wv = t >> 6;
    const int l15 = lane & 15, q = lane >> 4;
    {
        const us8* src = (const us8*)Wswz;
        us8* dst = (us8*)wlds;
#pragma unroll
        for (int it = 0; it < 4; it++) dst[it * 256 + t] = src[it * 256 + t];
    }
    __syncthreads();

    const int NT = NN / 16;  // 3125
    for (int tile = blockIdx.x * 4 + wv; tile < NT; tile += gridDim.x * 4) {
        const int rb = tile * 16;
        const int row = rb + l15;
        f32x4 uf[4];
        const float* p0 = x + (size_t)row * 40 + q * 8;
        const float* p1 = (q == 0) ? (x + (size_t)row * 40 + 32)
                                   : (pe + (size_t)row * 24 + (q - 1) * 8);
        uf[0] = *(const f32x4*)(p0);
        uf[1] = *(const f32x4*)(p0 + 4);
        uf[2] = *(const f32x4*)(p1);
        uf[3] = *(const f32x4*)(p1 + 4);
        bf16x8 af[2];
#pragma unroll
        for (int ks = 0; ks < 2; ks++)
#pragma unroll
            for (int i = 0; i < 4; i++) {
                af[ks][i]     = f2bf(uf[ks * 2][i]);
                af[ks][4 + i] = f2bf(uf[ks * 2 + 1][i]);
            }
        f32x4 acc[8];
#pragma unroll
        for (int jt = 0; jt < 8; jt++) acc[jt] = (f32x4){0.f, 0.f, 0.f, 0.f};
#pragma unroll
        for (int jt = 0; jt < 8; jt++) {
            int r = jt * 16 + l15;
#pragma unroll
            for (int ks = 0; ks < 2; ks++) {
                int c = (ks * 4 + q) ^ (l15 & 7);
                bf16x8 bfr = *(const bf16x8*)&wlds[r * 64 + c * 8];
                acc[jt] = __builtin_amdgcn_mfma_f32_16x16x32_bf16(af[ks], bfr, acc[jt], 0, 0, 0);
            }
        }
#pragma unroll
        for (int jt = 0; jt < 8; jt++) {
            int col = jt * 16 + l15;
            float bv = bias[col];
            float* outp = (jt < 4) ? (h + (size_t)(rb + q * 4) * 64 + col)
                                   : (ph + (size_t)(rb + q * 4) * 64 + (col - 64));
#pragma unroll
            for (int i = 0; i < 4; i++)
                outp[(size_t)i * 64] = acc[jt][i] + bv;
        }
    }
}

// ---------------- node GEMM: [stab|rtab] = [h|ph] @ Wcat + bias; h2=2h; ph2=2ph ----
__global__ __launch_bounds__(256) void k_node_gemm(
    const float* __restrict__ h, const float* __restrict__ ph,
    const unsigned short* __restrict__ Wswz,   // + layer*32768
    const float* __restrict__ bias,            // + layer*256
    float* __restrict__ stab, float* __restrict__ rtab,
    float* __restrict__ h2, float* __restrict__ ph2)
{
    __shared__ __align__(16) unsigned short wlds[32768];   // 256 rows x 128 k, 64KB
    const int t = threadIdx.x;
    const int lane = t & 63, wv = t >> 6;
    const int l15 = lane & 15, q = lane >> 4;
    {
        const us8* src = (const us8*)Wswz;
        us8* dst = (us8*)wlds;
#pragma unroll
        for (int it = 0; it < 16; it++) dst[it * 256 + t] = src[it * 256 + t];
    }
    __syncthreads();

    const int NT = NN / 16;  // 3125
    for (int tile = blockIdx.x * 4 + wv; tile < NT; tile += gridDim.x * 4) {
        const int rb = tile * 16;
        const int row = rb + l15;
        const float* hr = h + (size_t)row * 64;
        const float* pr = ph + (size_t)row * 64;
        f32x4 uf[8];
#pragma unroll
        for (int ks = 0; ks < 2; ks++) {
            uf[ks * 2 + 0] = *(const f32x4*)(hr + ks * 32 + q * 8);
            uf[ks * 2 + 1] = *(const f32x4*)(hr + ks * 32 + q * 8 + 4);
            uf[4 + ks * 2 + 0] = *(const f32x4*)(pr + ks * 32 + q * 8);
            uf[4 + ks * 2 + 1] = *(const f32x4*)(pr + ks * 32 + q * 8 + 4);
        }
        // hi/lo bf16 split for precision
        bf16x8 ahi[4], alo[4];
#pragma unroll
        for (int ks = 0; ks < 4; ks++)
#pragma unroll
            for (int i = 0; i < 4; i++) {
                float v0 = uf[ks * 2][i], v1 = uf[ks * 2 + 1][i];
                __bf16 h0 = f2bf(v0), h1 = f2bf(v1);
                ahi[ks][i] = h0; ahi[ks][4 + i] = h1;
                alo[ks][i] = f2bf(v0 - bf2f(h0));
                alo[ks][4 + i] = f2bf(v1 - bf2f(h1));
            }
        f32x4 acc[16];
#pragma unroll
        for (int jt = 0; jt < 16; jt++) acc[jt] = (f32x4){0.f, 0.f, 0.f, 0.f};
#pragma unroll
        for (int jt = 0; jt < 16; jt++) {
            int r = jt * 16 + l15;
#pragma unroll
            for (int ks = 0; ks < 4; ks++) {
                int c = (ks * 4 + q) ^ l15;
                bf16x8 bfr = *(const bf16x8*)&wlds[r * 128 + c * 8];
                acc[jt] = __builtin_amdgcn_mfma_f32_16x16x32_bf16(ahi[ks], bfr, acc[jt], 0, 0, 0);
                acc[jt] = __builtin_amdgcn_mfma_f32_16x16x32_bf16(alo[ks], bfr, acc[jt], 0, 0, 0);
            }
        }
#pragma unroll
        for (int jt = 0; jt < 16; jt++) {
            int col = jt * 16 + l15;
            float bv = bias[col];
            float* outp = (jt < 8) ? (stab + (size_t)(rb + q * 4) * 128 + col)
                                   : (rtab + (size_t)(rb + q * 4) * 128 + (col - 128));
#pragma unroll
            for (int i = 0; i < 4; i++)
                outp[(size_t)i * 128] = acc[jt][i] + bv;
        }
#pragma unroll
        for (int ks = 0; ks < 2; ks++) {
            *(f32x4*)(h2 + (size_t)row * 64 + ks * 32 + q * 8)     = uf[ks * 2] + uf[ks * 2];
            *(f32x4*)(h2 + (size_t)row * 64 + ks * 32 + q * 8 + 4) = uf[ks * 2 + 1] + uf[ks * 2 + 1];
            *(f32x4*)(ph2 + (size_t)row * 64 + ks * 32 + q * 8)     = uf[4 + ks * 2] + uf[4 + ks * 2];
            *(f32x4*)(ph2 + (size_t)row * 64 + ks * 32 + q * 8 + 4) = uf[4 + ks * 2 + 1] + uf[4 + ks * 2 + 1];
        }
    }
}

// ---------------- edge kernel: direct-fragment gather + MFMA + segmented reduce ----
// Lane (q,l15) owns edge l15 of each 16-edge group, k-columns q*8..q*8+7.
// A-fragment built directly in registers (no phase-1 LDS, no serial edge loop).
__global__ __launch_bounds__(256) void k_edge(
    const int* __restrict__ ssend, const int* __restrict__ srec,
    const float* __restrict__ sdist,
    const float* __restrict__ stab, const float* __restrict__ rtab,
    const float* __restrict__ mW1, const float* __restrict__ mb2,
    const float* __restrict__ pW1g, const float* __restrict__ pb2,
    const unsigned short* __restrict__ W2T, const unsigned short* __restrict__ pW2T,
    int layer,
    float* __restrict__ hout, float* __restrict__ pout)
{
    __shared__ __align__(16) float mbuf[4][16][68];   // padded: reduce/epilogue ~2-way
    const int lane = threadIdx.x & 63;
    const int wv = threadIdx.x >> 6;
    const int l15 = lane & 15, q = lane >> 4;

    const int chunk = (blockIdx.x << 2) + wv;
    if (chunk >= NE / 64) return;

    // dist-row coefficients for this lane's k-columns
    const float* w1p = mW1 + (size_t)layer * 16448 + 16384;
    const float* pw1p = pW1g + (size_t)layer * 8256 + 8192;
    f32x4 w1c[4], pw1c[4];
#pragma unroll
    for (int s = 0; s < 2; s++) {
        w1c[s * 2 + 0] = *(const f32x4*)(w1p + s * 32 + q * 8);
        w1c[s * 2 + 1] = *(const f32x4*)(w1p + s * 32 + q * 8 + 4);
        pw1c[s * 2 + 0] = *(const f32x4*)(pw1p + s * 32 + q * 8);
        pw1c[s * 2 + 1] = *(const f32x4*)(pw1p + s * 32 + q * 8 + 4);
    }

    bf16x8 wb[8], pwb[8];
    {
        const unsigned short* w2 = W2T + layer * 4096;
        const unsigned short* pw2 = pW2T + layer * 4096;
#pragma unroll
        for (int jt = 0; jt < 4; jt++)
#pragma unroll
            for (int kk = 0; kk < 2; kk++) {
                int off = (jt * 16 + l15) * 64 + kk * 32 + q * 8;
                wb[jt * 2 + kk]  = __builtin_bit_cast(bf16x8, *(const us8*)(w2 + off));
                pwb[jt * 2 + kk] = __builtin_bit_cast(bf16x8, *(const us8*)(pw2 + off));
            }
    }
    float b2v[4], pb2v[4];
#pragma unroll
    for (int jt = 0; jt < 4; jt++) {
        b2v[jt] = mb2[layer * 64 + jt * 16 + l15];
        pb2v[jt] = pb2[layer * 64 + jt * 16 + l15];
    }

    float acch = 0.f, accp = 0.f;
    int curh = -1, curp = -1;

    for (int t = 0; t < 4; t++) {
        const int ebase = chunk * 64 + t * 16;
        const int se = ssend[ebase + l15];
        const int re = srec[ebase + l15];
        const float de = sdist[ebase + l15];

        const float* sr = stab + (size_t)se * 128;
        const float* rr = rtab + (size_t)re * 128;

        // ---- gather + activation directly into MFMA A-fragments ----
        f32x4 A[4], B[4], PA[4], PB[4];
#pragma unroll
        for (int s = 0; s < 2; s++) {
            A[s * 2 + 0] = *(const f32x4*)(sr + s * 32 + q * 8);
            A[s * 2 + 1] = *(const f32x4*)(sr + s * 32 + q * 8 + 4);
            B[s * 2 + 0] = *(const f32x4*)(rr + s * 32 + q * 8);
            B[s * 2 + 1] = *(const f32x4*)(rr + s * 32 + q * 8 + 4);
            PA[s * 2 + 0] = *(const f32x4*)(sr + 64 + s * 32 + q * 8);
            PA[s * 2 + 1] = *(const f32x4*)(sr + 64 + s * 32 + q * 8 + 4);
            PB[s * 2 + 0] = *(const f32x4*)(rr + 64 + s * 32 + q * 8);
            PB[s * 2 + 1] = *(const f32x4*)(rr + 64 + s * 32 + q * 8 + 4);
        }
        bf16x8 ah[2], ap[2];
#pragma unroll
        for (int s = 0; s < 2; s++)
#pragma unroll
            for (int i = 0; i < 4; i++) {
                ah[s][i]     = f2bf(silu_f(A[s * 2][i] + B[s * 2][i] + de * w1c[s * 2][i]));
                ah[s][4 + i] = f2bf(silu_f(A[s * 2 + 1][i] + B[s * 2 + 1][i] + de * w1c[s * 2 + 1][i]));
                ap[s][i]     = f2bf(tanh_f(PA[s * 2][i] + PB[s * 2][i] + de * pw1c[s * 2][i]));
                ap[s][4 + i] = f2bf(tanh_f(PA[s * 2 + 1][i] + PB[s * 2 + 1][i] + de * pw1c[s * 2 + 1][i]));
            }

        // ---- msg second matmul + epilogue to LDS ----
#pragma unroll
        for (int jt = 0; jt < 4; jt++) {
            f32x4 acc = {0.f, 0.f, 0.f, 0.f};
            acc = __builtin_amdgcn_mfma_f32_16x16x32_bf16(ah[0], wb[jt * 2 + 0], acc, 0, 0, 0);
            acc = __builtin_amdgcn_mfma_f32_16x16x32_bf16(ah[1], wb[jt * 2 + 1], acc, 0, 0, 0);
#pragma unroll
            for (int i = 0; i < 4; i++)
                mbuf[wv][q * 4 + i][jt * 16 + l15] = silu_f(acc[i] + b2v[jt]);
        }
        // ---- segmented reduce (h) ----
        for (int e = 0; e < 16; e++) {
            int ree = __shfl(re, e);
            if (ree != curh) {
                if (curh >= 0) atomicAdd(&hout[(size_t)curh * 64 + lane], acch);
                curh = ree; acch = 0.f;
            }
            acch += mbuf[wv][e][lane];
        }

        // ---- pmsg second matmul + epilogue to LDS (reuse buffer) ----
#pragma unroll
        for (int jt = 0; jt < 4; jt++) {
            f32x4 acc = {0.f, 0.f, 0.f, 0.f};
            acc = __builtin_amdgcn_mfma_f32_16x16x32_bf16(ap[0], pwb[jt * 2 + 0], acc, 0, 0, 0);
            acc = __builtin_amdgcn_mfma_f32_16x16x32_bf16(ap[1], pwb[jt * 2 + 1], acc, 0, 0, 0);
#pragma unroll
            for (int i = 0; i < 4; i++)
                mbuf[wv][q * 4 + i][jt * 16 + l15] = tanh_f(acc[i] + pb2v[jt]);
        }
        // ---- segmented reduce (p) ----
        for (int e = 0; e < 16; e++) {
            int ree = __shfl(re, e);
            if (ree != curp) {
                if (curp >= 0) atomicAdd(&pout[(size_t)curp * 64 + lane], accp);
                curp = ree; accp = 0.f;
            }
            accp += mbuf[wv][e][lane];
        }
    }
    if (curh >= 0) atomicAdd(&hout[(size_t)curh * 64 + lane], acch);
    if (curp >= 0) atomicAdd(&pout[(size_t)curp * 64 + lane], accp);
}

// ---------------- final node MLP + pooling ----------------
__global__ __launch_bounds__(256) void k_prepool(
    const float* __restrict__ h, const int* __restrict__ batch,
    const float* __restrict__ W1, const float* __restrict__ b1,
    const float* __restrict__ W2, const float* __restrict__ b2,
    float* __restrict__ pooled)
{
    __shared__ __align__(16) float tl[4][64];
    const int lane = threadIdx.x & 63;
    const int wv = threadIdx.x >> 6;
    float w1[64], w2[64];
#pragma unroll
    for (int k = 0; k < 64; k++) { w1[k] = W1[k * 64 + lane]; w2[k] = W2[k * 64 + lane]; }
    const float bb1 = b1[lane], bb2 = b2[lane];
    const int wid = (blockIdx.x << 2) + wv;
    const int nw = gridDim.x << 2;
    for (int n = wid; n < NN; n += nw) {
        const int nu = __builtin_amdgcn_readfirstlane(n);
        const float* hr = h + (size_t)nu * 64;
        float a0 = 0, a1 = 0, a2 = 0, a3 = 0;
#pragma unroll
        for (int k = 0; k < 64; k += 4) {
            a0 += hr[k] * w1[k]; a1 += hr[k + 1] * w1[k + 1];
            a2 += hr[k + 2] * w1[k + 2]; a3 += hr[k + 3] * w1[k + 3];
        }
        tl[wv][lane] = silu_f(a0 + a1 + a2 + a3 + bb1);
        float c0 = 0, c1 = 0, c2 = 0, c3 = 0;
        const f32x4* tp4 = (const f32x4*)&tl[wv][0];
#pragma unroll
        for (int k4 = 0; k4 < 16; k4++) {
            f32x4 tv = tp4[k4];
            c0 += tv[0] * w2[k4 * 4]; c1 += tv[1] * w2[k4 * 4 + 1];
            c2 += tv[2] * w2[k4 * 4 + 2]; c3 += tv[3] * w2[k4 * 4 + 3];
        }
        float hp = c0 + c1 + c2 + c3 + bb2;
        int gidx = batch[nu];
        atomicAdd(&pooled[(size_t)gidx * 64 + lane], hp);
    }
}

// ---------------- readout ----------------
__global__ __launch_bounds__(256) void k_readout(
    const float* __restrict__ pooled,
    const float* __restrict__ W1, const float* __restrict__ b1,
    const float* __restrict__ W2, const float* __restrict__ b2,
    float* __restrict__ out)
{
    const int lane = threadIdx.x & 63;
    const int wv = threadIdx.x >> 6;
    const int g = (blockIdx.x << 2) + wv;
    if (g >= NG) return;
    const float* pr = pooled + (size_t)g * 64;
    float a0 = 0, a1 = 0, a2 = 0, a3 = 0;
#pragma unroll
    for (int k = 0; k < 64; k += 4) {
        a0 += pr[k] * W1[k * 64 + lane]; a1 += pr[k + 1] * W1[(k + 1) * 64 + lane];
        a2 += pr[k + 2] * W1[(k + 2) * 64 + lane]; a3 += pr[k + 3] * W1[(k + 3) * 64 + lane];
    }
    float v = silu_f(a0 + a1 + a2 + a3 + b1[lane]) * W2[lane];
#pragma unroll
    for (int off = 32; off > 0; off >>= 1) v += __shfl_down(v, off);
    if (lane == 0) out[g] = v + b2[0];
}

extern "C" void kernel_launch(void* const* d_in, const int* in_sizes, int n_in,
                              void* d_out, int out_size, void* d_ws, size_t ws_size,
                              hipStream_t stream)
{
    const float* x = (const float*)d_in[0];
    const float* pos = (const float*)d_in[1];
    const float* pe = (const float*)d_in[2];
    const int* eidx = (const int*)d_in[3];
    const int* batch = (const int*)d_in[4];
    const float* eW = (const float*)d_in[5];
    const float* eb = (const float*)d_in[6];
    const float* epW = (const float*)d_in[7];
    const float* epb = (const float*)d_in[8];
    const float* mW1 = (const float*)d_in[9];
    const float* mb1 = (const float*)d_in[10];
    const float* mW2 = (const float*)d_in[11];
    const float* mb2 = (const float*)d_in[12];
    const float* pW1 = (const float*)d_in[13];
    const float* pb1 = (const float*)d_in[14];
    const float* pW2 = (const float*)d_in[15];
    const float* pb2 = (const float*)d_in[16];
    const float* preW1 = (const float*)d_in[17];
    const float* preb1 = (const float*)d_in[18];
    const float* preW2 = (const float*)d_in[19];
    const float* preb2 = (const float*)d_in[20];
    const float* roW1 = (const float*)d_in[21];
    const float* rob1 = (const float*)d_in[22];
    const float* roW2 = (const float*)d_in[23];
    const float* rob2 = (const float*)d_in[24];

    const int* send = eidx;
    const int* rcv = eidx + NE;

    float* f = (float*)d_ws;
    size_t o = 0;
    float* hA = f + o; o += (size_t)NN * 64;
    float* hB = f + o; o += (size_t)NN * 64;
    float* phA = f + o; o += (size_t)NN * 64;
    float* phB = f + o; o += (size_t)NN * 64;
    float* stab = f + o; o += (size_t)NN * 128;
    float* rtab = f + o; o += (size_t)NN * 128;
    float* pooled = f + o; o += NG * 64;
    unsigned short* W2T = (unsigned short*)(f + o); o += 8192;
    unsigned short* pW2T = (unsigned short*)(f + o); o += 8192;
    unsigned short* Wswz = (unsigned short*)(f + o); o += 65536;    // 4*32768 bf16
    unsigned short* WembSwz = (unsigned short*)(f + o); o += 4096;  // 8192 bf16
    float* biascat = f + o; o += 1024;
    float* biasemb = f + o; o += 128;
    int* hist = (int*)(f + o); o += NN;
    int* cursor = (int*)(f + o); o += NN;
    int* ssend = (int*)(f + o); o += NE;
    int* srec = (int*)(f + o); o += NE;
    float* sdist = f + o; o += NE;

    hipMemsetAsync(pooled, 0, NG * 64 * sizeof(float), stream);
    hipMemsetAsync(hist, 0, NN * sizeof(int), stream);
    k_wprep<<<512, 256, 0, stream>>>(mW1, mb1, mW2, pW1, pb1, pW2,
                                     eW, eb, epW, epb,
                                     W2T, pW2T, Wswz, biascat, WembSwz, biasemb);
    k_hist<<<(NE + 255) / 256, 256, 0, stream>>>(rcv, hist);
    k_scan<<<1, 1024, 0, stream>>>(hist, cursor);
    k_scatter<<<(NE + 255) / 256, 256, 0, stream>>>(send, rcv, pos, cursor, ssend, srec, sdist);
    k_embed_gemm<<<512, 256, 0, stream>>>(x, pe, WembSwz, biasemb, hA, phA);

    float* hin = hA; float* pin = phA; float* hout = hB; float* pout = phB;
    for (int l = 0; l < 4; l++) {
        k_node_gemm<<<512, 256, 0, stream>>>(hin, pin, Wswz + (size_t)l * 32768,
                                             biascat + l * 256, stab, rtab, hout, pout);
        k_edge<<<(NE / 64 + 3) / 4, 256, 0, stream>>>(ssend, srec, sdist, stab, rtab,
                                                      mW1, mb2, pW1, pb2, W2T, pW2T, l, hout, pout);
        float* t;
        t = hin; hin = hout; hout = t;
        t = pin; pin = pout; pout = t;
    }
    k_prepool<<<256, 256, 0, stream>>>(hin, batch, preW1, preb1, preW2, preb2, pooled);
    k_readout<<<128, 256, 0, stream>>>(pooled, roW1, rob1, roW2, rob2, (float*)d_out);
}

// Round 5
// 624.082 us; speedup vs baseline: 2.1526x; 1.0470x over previous
//
#include <hip/hip_runtime.h>

#define NN 50000
#define NE 400000
#define NG 512

typedef __bf16 bf16x8 __attribute__((ext_vector_type(8)));
typedef float f32x4 __attribute__((ext_vector_type(4)));
typedef unsigned short us8 __attribute__((ext_vector_type(8)));

__device__ __forceinline__ float frcp(float x) { return __builtin_amdgcn_rcpf(x); }
__device__ __forceinline__ float silu_f(float x) { return x * frcp(1.f + __expf(-x)); }
__device__ __forceinline__ float tanh_f(float x) { return 1.f - 2.f * frcp(__expf(2.f * x) + 1.f); }
__device__ __forceinline__ __bf16 f2bf(float f) {
    unsigned u = __builtin_bit_cast(unsigned, f);
    u += 0x7fffu + ((u >> 16) & 1u);
    unsigned short s = (unsigned short)(u >> 16);
    return __builtin_bit_cast(__bf16, s);
}
__device__ __forceinline__ unsigned short f2bfu(float f) {
    return __builtin_bit_cast(unsigned short, f2bf(f));
}
__device__ __forceinline__ float bf2f(__bf16 b) {
    unsigned short s = __builtin_bit_cast(unsigned short, b);
    unsigned u = ((unsigned)s) << 16;
    return __builtin_bit_cast(float, u);
}

// ---------------- weight prep ----------------
__global__ __launch_bounds__(256) void k_wprep(
    const float* __restrict__ mW1, const float* __restrict__ mb1,
    const float* __restrict__ mW2, const float* __restrict__ pW1,
    const float* __restrict__ pb1, const float* __restrict__ pW2,
    const float* __restrict__ eW, const float* __restrict__ eb,
    const float* __restrict__ epW, const float* __restrict__ epb,
    unsigned short* __restrict__ W2T, unsigned short* __restrict__ pW2T,
    unsigned short* __restrict__ Wswz, float* __restrict__ biascat,
    unsigned short* __restrict__ WembSwz, float* __restrict__ biasemb)
{
    int idx = blockIdx.x * 256 + threadIdx.x;
    if (idx < 16384) {
        int l = idx >> 12, r = idx & 4095;
        int j = r >> 6, k = r & 63;
        int src = l * 4096 + k * 64 + j;
        W2T[idx] = f2bfu(mW2[src]);
        pW2T[idx] = f2bfu(pW2[src]);
    }
    if (idx < 131072) {
        int l = idx >> 15, rem = idx & 32767;
        int r = rem >> 7, k = rem & 127;          // r = out col 0..255, k = 0..127
        const float* W1l = mW1 + (size_t)l * 16448;
        const float* pW1l = pW1 + (size_t)l * 8256;
        float v;
        if (r < 64)        v = W1l[k * 64 + r];                                    // A
        else if (r < 128)  v = (k >= 64) ? pW1l[(k - 64) * 64 + (r - 64)] : 0.f;   // PA
        else if (r < 192)  v = W1l[(128 + k) * 64 + (r - 128)];                    // B
        else               v = (k >= 64) ? pW1l[k * 64 + (r - 192)] : 0.f;         // PB
        int c = k >> 3, e = k & 7;
        int cs = c ^ (r & 15);
        Wswz[(size_t)l * 32768 + r * 128 + cs * 8 + e] = f2bfu(v);
    }
    if (idx < 8192) {
        int r = idx >> 6, k = idx & 63;           // r = out col 0..127, k = 0..63
        float v;
        if (r < 64) v = eW[k * 64 + r];
        else        v = (k >= 40) ? epW[(k - 40) * 64 + (r - 64)] : 0.f;
        int c = k >> 3, e = k & 7;
        int cs = c ^ (r & 7);
        WembSwz[r * 64 + cs * 8 + e] = f2bfu(v);
    }
    if (idx < 1024) {
        int l = idx >> 8, col = idx & 255;
        float b = 0.f;
        if (col >= 128 && col < 192) b = mb1[l * 64 + col - 128];
        else if (col >= 192)         b = pb1[l * 64 + col - 192];
        biascat[idx] = b;
    }
    if (idx < 128) biasemb[idx] = (idx < 64) ? eb[idx] : epb[idx - 64];
}

// ---------------- counting sort by receiver ----------------
__global__ void k_hist(const int* __restrict__ rec, int* __restrict__ hist)
{
    int e = blockIdx.x * 256 + threadIdx.x;
    if (e < NE) atomicAdd(&hist[rec[e]], 1);
}

__global__ __launch_bounds__(1024) void k_scan(const int* __restrict__ hist, int* __restrict__ cursor)
{
    __shared__ int wsum[16];
    const int t = threadIdx.x;
    const int lane = t & 63, w = t >> 6;
    const int PER = 49;
    const int base = t * PER;
    int s = 0;
    for (int i = 0; i < PER; i++) { int idx = base + i; if (idx < NN) s += hist[idx]; }
    int pre = s;
#pragma unroll
    for (int d = 1; d < 64; d <<= 1) { int o = __shfl_up(pre, d); if (lane >= d) pre += o; }
    if (lane == 63) wsum[w] = pre;
    __syncthreads();
    if (w == 0) {
        int v = (lane < 16) ? wsum[lane] : 0;
        int p = v;
#pragma unroll
        for (int d = 1; d < 16; d <<= 1) { int o = __shfl_up(p, d); if (lane >= d) p += o; }
        if (lane < 16) wsum[lane] = p - v;
    }
    __syncthreads();
    int run = wsum[w] + (pre - s);
    for (int i = 0; i < PER; i++) {
        int idx = base + i;
        if (idx < NN) { cursor[idx] = run; run += hist[idx]; }
    }
}

__global__ void k_scatter(const int* __restrict__ send, const int* __restrict__ rec,
                          const float* __restrict__ pos, int* __restrict__ cursor,
                          int* __restrict__ ssend, int* __restrict__ srec,
                          float* __restrict__ sdist)
{
    int e = blockIdx.x * 256 + threadIdx.x;
    if (e >= NE) return;
    int s = send[e], r = rec[e];
    int p = atomicAdd(&cursor[r], 1);
    float dx = pos[s * 3 + 0] - pos[r * 3 + 0];
    float dy = pos[s * 3 + 1] - pos[r * 3 + 1];
    float dz = pos[s * 3 + 2] - pos[r * 3 + 2];
    ssend[p] = s; srec[p] = r;
    sdist[p] = sqrtf(dx * dx + dy * dy + dz * dz);
}

// ---------------- embed GEMM: [h|ph] = [x|pe] @ Wemb + bias ----------------
__global__ __launch_bounds__(256) void k_embed_gemm(
    const float* __restrict__ x, const float* __restrict__ pe,
    const unsigned short* __restrict__ Wswz, const float* __restrict__ bias,
    float* __restrict__ h, float* __restrict__ ph)
{
    __shared__ __align__(16) unsigned short wlds[8192];   // 128 rows x 64 k, 16KB
    const int t = threadIdx.x;
    const int lane = t & 63, wv = t >> 6;
    const int l15 = lane & 15, q = lane >> 4;
    {
        const us8* src = (const us8*)Wswz;
        us8* dst = (us8*)wlds;
#pragma unroll
        for (int it = 0; it < 4; it++) dst[it * 256 + t] = src[it * 256 + t];
    }
    __syncthreads();

    const int NT = NN / 16;  // 3125
    for (int tile = blockIdx.x * 4 + wv; tile < NT; tile += gridDim.x * 4) {
        const int rb = tile * 16;
        const int row = rb + l15;
        f32x4 uf[4];
        const float* p0 = x + (size_t)row * 40 + q * 8;
        const float* p1 = (q == 0) ? (x + (size_t)row * 40 + 32)
                                   : (pe + (size_t)row * 24 + (q - 1) * 8);
        uf[0] = *(const f32x4*)(p0);
        uf[1] = *(const f32x4*)(p0 + 4);
        uf[2] = *(const f32x4*)(p1);
        uf[3] = *(const f32x4*)(p1 + 4);
        bf16x8 af[2];
#pragma unroll
        for (int ks = 0; ks < 2; ks++)
#pragma unroll
            for (int i = 0; i < 4; i++) {
                af[ks][i]     = f2bf(uf[ks * 2][i]);
                af[ks][4 + i] = f2bf(uf[ks * 2 + 1][i]);
            }
        f32x4 acc[8];
#pragma unroll
        for (int jt = 0; jt < 8; jt++) acc[jt] = (f32x4){0.f, 0.f, 0.f, 0.f};
#pragma unroll
        for (int jt = 0; jt < 8; jt++) {
            int r = jt * 16 + l15;
#pragma unroll
            for (int ks = 0; ks < 2; ks++) {
                int c = (ks * 4 + q) ^ (l15 & 7);
                bf16x8 bfr = *(const bf16x8*)&wlds[r * 64 + c * 8];
                acc[jt] = __builtin_amdgcn_mfma_f32_16x16x32_bf16(af[ks], bfr, acc[jt], 0, 0, 0);
            }
        }
#pragma unroll
        for (int jt = 0; jt < 8; jt++) {
            int col = jt * 16 + l15;
            float bv = bias[col];
            float* outp = (jt < 4) ? (h + (size_t)(rb + q * 4) * 64 + col)
                                   : (ph + (size_t)(rb + q * 4) * 64 + (col - 64));
#pragma unroll
            for (int i = 0; i < 4; i++)
                outp[(size_t)i * 64] = acc[jt][i] + bv;
        }
    }
}

// ---------------- node GEMM: [stab|rtab] = [h|ph] @ Wcat + bias; h2=2h; ph2=2ph ----
__global__ __launch_bounds__(256) void k_node_gemm(
    const float* __restrict__ h, const float* __restrict__ ph,
    const unsigned short* __restrict__ Wswz,   // + layer*32768
    const float* __restrict__ bias,            // + layer*256
    float* __restrict__ stab, float* __restrict__ rtab,
    float* __restrict__ h2, float* __restrict__ ph2)
{
    __shared__ __align__(16) unsigned short wlds[32768];   // 256 rows x 128 k, 64KB
    const int t = threadIdx.x;
    const int lane = t & 63, wv = t >> 6;
    const int l15 = lane & 15, q = lane >> 4;
    {
        const us8* src = (const us8*)Wswz;
        us8* dst = (us8*)wlds;
#pragma unroll
        for (int it = 0; it < 16; it++) dst[it * 256 + t] = src[it * 256 + t];
    }
    __syncthreads();

    const int NT = NN / 16;  // 3125
    for (int tile = blockIdx.x * 4 + wv; tile < NT; tile += gridDim.x * 4) {
        const int rb = tile * 16;
        const int row = rb + l15;
        const float* hr = h + (size_t)row * 64;
        const float* pr = ph + (size_t)row * 64;
        f32x4 uf[8];
#pragma unroll
        for (int ks = 0; ks < 2; ks++) {
            uf[ks * 2 + 0] = *(const f32x4*)(hr + ks * 32 + q * 8);
            uf[ks * 2 + 1] = *(const f32x4*)(hr + ks * 32 + q * 8 + 4);
            uf[4 + ks * 2 + 0] = *(const f32x4*)(pr + ks * 32 + q * 8);
            uf[4 + ks * 2 + 1] = *(const f32x4*)(pr + ks * 32 + q * 8 + 4);
        }
        // hi/lo bf16 split for precision
        bf16x8 ahi[4], alo[4];
#pragma unroll
        for (int ks = 0; ks < 4; ks++)
#pragma unroll
            for (int i = 0; i < 4; i++) {
                float v0 = uf[ks * 2][i], v1 = uf[ks * 2 + 1][i];
                __bf16 h0 = f2bf(v0), h1 = f2bf(v1);
                ahi[ks][i] = h0; ahi[ks][4 + i] = h1;
                alo[ks][i] = f2bf(v0 - bf2f(h0));
                alo[ks][4 + i] = f2bf(v1 - bf2f(h1));
            }
        f32x4 acc[16];
#pragma unroll
        for (int jt = 0; jt < 16; jt++) acc[jt] = (f32x4){0.f, 0.f, 0.f, 0.f};
#pragma unroll
        for (int jt = 0; jt < 16; jt++) {
            int r = jt * 16 + l15;
#pragma unroll
            for (int ks = 0; ks < 4; ks++) {
                int c = (ks * 4 + q) ^ l15;
                bf16x8 bfr = *(const bf16x8*)&wlds[r * 128 + c * 8];
                acc[jt] = __builtin_amdgcn_mfma_f32_16x16x32_bf16(ahi[ks], bfr, acc[jt], 0, 0, 0);
                acc[jt] = __builtin_amdgcn_mfma_f32_16x16x32_bf16(alo[ks], bfr, acc[jt], 0, 0, 0);
            }
        }
#pragma unroll
        for (int jt = 0; jt < 16; jt++) {
            int col = jt * 16 + l15;
            float bv = bias[col];
            float* outp = (jt < 8) ? (stab + (size_t)(rb + q * 4) * 128 + col)
                                   : (rtab + (size_t)(rb + q * 4) * 128 + (col - 128));
#pragma unroll
            for (int i = 0; i < 4; i++)
                outp[(size_t)i * 128] = acc[jt][i] + bv;
        }
#pragma unroll
        for (int ks = 0; ks < 2; ks++) {
            *(f32x4*)(h2 + (size_t)row * 64 + ks * 32 + q * 8)     = uf[ks * 2] + uf[ks * 2];
            *(f32x4*)(h2 + (size_t)row * 64 + ks * 32 + q * 8 + 4) = uf[ks * 2 + 1] + uf[ks * 2 + 1];
            *(f32x4*)(ph2 + (size_t)row * 64 + ks * 32 + q * 8)     = uf[4 + ks * 2] + uf[4 + ks * 2];
            *(f32x4*)(ph2 + (size_t)row * 64 + ks * 32 + q * 8 + 4) = uf[4 + ks * 2 + 1] + uf[4 + ks * 2 + 1];
        }
    }
}

// ---------------- edge kernel: direct-fragment gather + MFMA + fast fused reduce ---
// Lane (q,l15) owns edge l15 of each 16-edge group, k-columns q*8..q*8+7.
// Reduce: batch-load all 32 column values to regs, precompute receiver broadcasts,
// then one fused serial scan (pure VALU, wave-uniform branches).
__global__ __launch_bounds__(256) void k_edge(
    const int* __restrict__ ssend, const int* __restrict__ srec,
    const float* __restrict__ sdist,
    const float* __restrict__ stab, const float* __restrict__ rtab,
    const float* __restrict__ mW1, const float* __restrict__ mb2,
    const float* __restrict__ pW1g, const float* __restrict__ pb2,
    const unsigned short* __restrict__ W2T, const unsigned short* __restrict__ pW2T,
    int layer,
    float* __restrict__ hout, float* __restrict__ pout)
{
    __shared__ __align__(16) float mh[4][16][68];
    __shared__ __align__(16) float mp[4][16][68];
    const int lane = threadIdx.x & 63;
    const int wv = threadIdx.x >> 6;
    const int l15 = lane & 15, q = lane >> 4;

    const int chunk = (blockIdx.x << 2) + wv;
    if (chunk >= NE / 64) return;

    // dist-row coefficients for this lane's k-columns
    const float* w1p = mW1 + (size_t)layer * 16448 + 16384;
    const float* pw1p = pW1g + (size_t)layer * 8256 + 8192;
    f32x4 w1c[4], pw1c[4];
#pragma unroll
    for (int s = 0; s < 2; s++) {
        w1c[s * 2 + 0] = *(const f32x4*)(w1p + s * 32 + q * 8);
        w1c[s * 2 + 1] = *(const f32x4*)(w1p + s * 32 + q * 8 + 4);
        pw1c[s * 2 + 0] = *(const f32x4*)(pw1p + s * 32 + q * 8);
        pw1c[s * 2 + 1] = *(const f32x4*)(pw1p + s * 32 + q * 8 + 4);
    }

    bf16x8 wb[8], pwb[8];
    {
        const unsigned short* w2 = W2T + layer * 4096;
        const unsigned short* pw2 = pW2T + layer * 4096;
#pragma unroll
        for (int jt = 0; jt < 4; jt++)
#pragma unroll
            for (int kk = 0; kk < 2; kk++) {
                int off = (jt * 16 + l15) * 64 + kk * 32 + q * 8;
                wb[jt * 2 + kk]  = __builtin_bit_cast(bf16x8, *(const us8*)(w2 + off));
                pwb[jt * 2 + kk] = __builtin_bit_cast(bf16x8, *(const us8*)(pw2 + off));
            }
    }
    float b2v[4], pb2v[4];
#pragma unroll
    for (int jt = 0; jt < 4; jt++) {
        b2v[jt] = mb2[layer * 64 + jt * 16 + l15];
        pb2v[jt] = pb2[layer * 64 + jt * 16 + l15];
    }

    float acch = 0.f, accp = 0.f;
    int cur = -1;

    for (int t = 0; t < 4; t++) {
        const int ebase = chunk * 64 + t * 16;
        const int se = ssend[ebase + l15];
        const int re = srec[ebase + l15];
        const float de = sdist[ebase + l15];

        const float* sr = stab + (size_t)se * 128;
        const float* rr = rtab + (size_t)re * 128;

        // receiver of every edge in this group (independent broadcasts, off the chain)
        int rv[16];
#pragma unroll
        for (int e = 0; e < 16; e++) rv[e] = __shfl(re, e);

        // ---- gather + activation directly into MFMA A-fragments ----
        f32x4 A[4], B[4], PA[4], PB[4];
#pragma unroll
        for (int s = 0; s < 2; s++) {
            A[s * 2 + 0] = *(const f32x4*)(sr + s * 32 + q * 8);
            A[s * 2 + 1] = *(const f32x4*)(sr + s * 32 + q * 8 + 4);
            B[s * 2 + 0] = *(const f32x4*)(rr + s * 32 + q * 8);
            B[s * 2 + 1] = *(const f32x4*)(rr + s * 32 + q * 8 + 4);
            PA[s * 2 + 0] = *(const f32x4*)(sr + 64 + s * 32 + q * 8);
            PA[s * 2 + 1] = *(const f32x4*)(sr + 64 + s * 32 + q * 8 + 4);
            PB[s * 2 + 0] = *(const f32x4*)(rr + 64 + s * 32 + q * 8);
            PB[s * 2 + 1] = *(const f32x4*)(rr + 64 + s * 32 + q * 8 + 4);
        }
        bf16x8 ah[2], ap[2];
#pragma unroll
        for (int s = 0; s < 2; s++)
#pragma unroll
            for (int i = 0; i < 4; i++) {
                ah[s][i]     = f2bf(silu_f(A[s * 2][i] + B[s * 2][i] + de * w1c[s * 2][i]));
                ah[s][4 + i] = f2bf(silu_f(A[s * 2 + 1][i] + B[s * 2 + 1][i] + de * w1c[s * 2 + 1][i]));
                ap[s][i]     = f2bf(tanh_f(PA[s * 2][i] + PB[s * 2][i] + de * pw1c[s * 2][i]));
                ap[s][4 + i] = f2bf(tanh_f(PA[s * 2 + 1][i] + PB[s * 2 + 1][i] + de * pw1c[s * 2 + 1][i]));
            }

        // ---- both second matmuls + epilogues to LDS (independent, good ILP) ----
#pragma unroll
        for (int jt = 0; jt < 4; jt++) {
            f32x4 acc = {0.f, 0.f, 0.f, 0.f};
            acc = __builtin_amdgcn_mfma_f32_16x16x32_bf16(ah[0], wb[jt * 2 + 0], acc, 0, 0, 0);
            acc = __builtin_amdgcn_mfma_f32_16x16x32_bf16(ah[1], wb[jt * 2 + 1], acc, 0, 0, 0);
#pragma unroll
            for (int i = 0; i < 4; i++)
                mh[wv][q * 4 + i][jt * 16 + l15] = silu_f(acc[i] + b2v[jt]);
        }
#pragma unroll
        for (int jt = 0; jt < 4; jt++) {
            f32x4 acc = {0.f, 0.f, 0.f, 0.f};
            acc = __builtin_amdgcn_mfma_f32_16x16x32_bf16(ap[0], pwb[jt * 2 + 0], acc, 0, 0, 0);
            acc = __builtin_amdgcn_mfma_f32_16x16x32_bf16(ap[1], pwb[jt * 2 + 1], acc, 0, 0, 0);
#pragma unroll
            for (int i = 0; i < 4; i++)
                mp[wv][q * 4 + i][jt * 16 + l15] = tanh_f(acc[i] + pb2v[jt]);
        }

        // ---- batch column loads into registers (parallel ds_reads, one wait) ----
        float vh[16], vp[16];
#pragma unroll
        for (int e = 0; e < 16; e++) {
            vh[e] = mh[wv][e][lane];
            vp[e] = mp[wv][e][lane];
        }

        // ---- fused serial scan: pure VALU, wave-uniform branches ----
#pragma unroll
        for (int e = 0; e < 16; e++) {
            if (rv[e] != cur) {
                if (cur >= 0) {
                    atomicAdd(&hout[(size_t)cur * 64 + lane], acch);
                    atomicAdd(&pout[(size_t)cur * 64 + lane], accp);
                }
                cur = rv[e]; acch = 0.f; accp = 0.f;
            }
            acch += vh[e];
            accp += vp[e];
        }
    }
    if (cur >= 0) {
        atomicAdd(&hout[(size_t)cur * 64 + lane], acch);
        atomicAdd(&pout[(size_t)cur * 64 + lane], accp);
    }
}

// ---------------- final node MLP + pooling ----------------
__global__ __launch_bounds__(256) void k_prepool(
    const float* __restrict__ h, const int* __restrict__ batch,
    const float* __restrict__ W1, const float* __restrict__ b1,
    const float* __restrict__ W2, const float* __restrict__ b2,
    float* __restrict__ pooled)
{
    __shared__ __align__(16) float tl[4][64];
    const int lane = threadIdx.x & 63;
    const int wv = threadIdx.x >> 6;
    float w1[64], w2[64];
#pragma unroll
    for (int k = 0; k < 64; k++) { w1[k] = W1[k * 64 + lane]; w2[k] = W2[k * 64 + lane]; }
    const float bb1 = b1[lane], bb2 = b2[lane];
    const int wid = (blockIdx.x << 2) + wv;
    const int nw = gridDim.x << 2;
    for (int n = wid; n < NN; n += nw) {
        const int nu = __builtin_amdgcn_readfirstlane(n);
        const float* hr = h + (size_t)nu * 64;
        float a0 = 0, a1 = 0, a2 = 0, a3 = 0;
#pragma unroll
        for (int k = 0; k < 64; k += 4) {
            a0 += hr[k] * w1[k]; a1 += hr[k + 1] * w1[k + 1];
            a2 += hr[k + 2] * w1[k + 2]; a3 += hr[k + 3] * w1[k + 3];
        }
        tl[wv][lane] = silu_f(a0 + a1 + a2 + a3 + bb1);
        float c0 = 0, c1 = 0, c2 = 0, c3 = 0;
        const f32x4* tp4 = (const f32x4*)&tl[wv][0];
#pragma unroll
        for (int k4 = 0; k4 < 16; k4++) {
            f32x4 tv = tp4[k4];
            c0 += tv[0] * w2[k4 * 4]; c1 += tv[1] * w2[k4 * 4 + 1];
            c2 += tv[2] * w2[k4 * 4 + 2]; c3 += tv[3] * w2[k4 * 4 + 3];
        }
        float hp = c0 + c1 + c2 + c3 + bb2;
        int gidx = batch[nu];
        atomicAdd(&pooled[(size_t)gidx * 64 + lane], hp);
    }
}

// ---------------- readout ----------------
__global__ __launch_bounds__(256) void k_readout(
    const float* __restrict__ pooled,
    const float* __restrict__ W1, const float* __restrict__ b1,
    const float* __restrict__ W2, const float* __restrict__ b2,
    float* __restrict__ out)
{
    const int lane = threadIdx.x & 63;
    const int wv = threadIdx.x >> 6;
    const int g = (blockIdx.x << 2) + wv;
    if (g >= NG) return;
    const float* pr = pooled + (size_t)g * 64;
    float a0 = 0, a1 = 0, a2 = 0, a3 = 0;
#pragma unroll
    for (int k = 0; k < 64; k += 4) {
        a0 += pr[k] * W1[k * 64 + lane]; a1 += pr[k + 1] * W1[(k + 1) * 64 + lane];
        a2 += pr[k + 2] * W1[(k + 2) * 64 + lane]; a3 += pr[k + 3] * W1[(k + 3) * 64 + lane];
    }
    float v = silu_f(a0 + a1 + a2 + a3 + b1[lane]) * W2[lane];
#pragma unroll
    for (int off = 32; off > 0; off >>= 1) v += __shfl_down(v, off);
    if (lane == 0) out[g] = v + b2[0];
}

extern "C" void kernel_launch(void* const* d_in, const int* in_sizes, int n_in,
                              void* d_out, int out_size, void* d_ws, size_t ws_size,
                              hipStream_t stream)
{
    const float* x = (const float*)d_in[0];
    const float* pos = (const float*)d_in[1];
    const float* pe = (const float*)d_in[2];
    const int* eidx = (const int*)d_in[3];
    const int* batch = (const int*)d_in[4];
    const float* eW = (const float*)d_in[5];
    const float* eb = (const float*)d_in[6];
    const float* epW = (const float*)d_in[7];
    const float* epb = (const float*)d_in[8];
    const float* mW1 = (const float*)d_in[9];
    const float* mb1 = (const float*)d_in[10];
    const float* mW2 = (const float*)d_in[11];
    const float* mb2 = (const float*)d_in[12];
    const float* pW1 = (const float*)d_in[13];
    const float* pb1 = (const float*)d_in[14];
    const float* pW2 = (const float*)d_in[15];
    const float* pb2 = (const float*)d_in[16];
    const float* preW1 = (const float*)d_in[17];
    const float* preb1 = (const float*)d_in[18];
    const float* preW2 = (const float*)d_in[19];
    const float* preb2 = (const float*)d_in[20];
    const float* roW1 = (const float*)d_in[21];
    const float* rob1 = (const float*)d_in[22];
    const float* roW2 = (const float*)d_in[23];
    const float* rob2 = (const float*)d_in[24];

    const int* send = eidx;
    const int* rcv = eidx + NE;

    float* f = (float*)d_ws;
    size_t o = 0;
    float* hA = f + o; o += (size_t)NN * 64;
    float* hB = f + o; o += (size_t)NN * 64;
    float* phA = f + o; o += (size_t)NN * 64;
    float* phB = f + o; o += (size_t)NN * 64;
    float* stab = f + o; o += (size_t)NN * 128;
    float* rtab = f + o; o += (size_t)NN * 128;
    float* pooled = f + o; o += NG * 64;
    unsigned short* W2T = (unsigned short*)(f + o); o += 8192;
    unsigned short* pW2T = (unsigned short*)(f + o); o += 8192;
    unsigned short* Wswz = (unsigned short*)(f + o); o += 65536;    // 4*32768 bf16
    unsigned short* WembSwz = (unsigned short*)(f + o); o += 4096;  // 8192 bf16
    float* biascat = f + o; o += 1024;
    float* biasemb = f + o; o += 128;
    int* hist = (int*)(f + o); o += NN;
    int* cursor = (int*)(f + o); o += NN;
    int* ssend = (int*)(f + o); o += NE;
    int* srec = (int*)(f + o); o += NE;
    float* sdist = f + o; o += NE;

    hipMemsetAsync(pooled, 0, NG * 64 * sizeof(float), stream);
    hipMemsetAsync(hist, 0, NN * sizeof(int), stream);
    k_wprep<<<512, 256, 0, stream>>>(mW1, mb1, mW2, pW1, pb1, pW2,
                                     eW, eb, epW, epb,
                                     W2T, pW2T, Wswz, biascat, WembSwz, biasemb);
    k_hist<<<(NE + 255) / 256, 256, 0, stream>>>(rcv, hist);
    k_scan<<<1, 1024, 0, stream>>>(hist, cursor);
    k_scatter<<<(NE + 255) / 256, 256, 0, stream>>>(send, rcv, pos, cursor, ssend, srec, sdist);
    k_embed_gemm<<<512, 256, 0, stream>>>(x, pe, WembSwz, biasemb, hA, phA);

    float* hin = hA; float* pin = phA; float* hout = hB; float* pout = phB;
    for (int l = 0; l < 4; l++) {
        k_node_gemm<<<512, 256, 0, stream>>>(hin, pin, Wswz + (size_t)l * 32768,
                                             biascat + l * 256, stab, rtab, hout, pout);
        k_edge<<<(NE / 64 + 3) / 4, 256, 0, stream>>>(ssend, srec, sdist, stab, rtab,
                                                      mW1, mb2, pW1, pb2, W2T, pW2T, l, hout, pout);
        float* t;
        t = hin; hin = hout; hout = t;
        t = pin; pin = pout; pout = t;
    }
    k_prepool<<<256, 256, 0, stream>>>(hin, batch, preW1, preb1, preW2, preb2, pooled);
    k_readout<<<128, 256, 0, stream>>>(pooled, roW1, rob1, roW2, rob2, (float*)d_out);
}

// Round 6
// 506.607 us; speedup vs baseline: 2.6518x; 1.2319x over previous
//
#include <hip/hip_runtime.h>

#define NN 50000
#define NE 400000
#define NG 512

typedef __bf16 bf16x8 __attribute__((ext_vector_type(8)));
typedef float f32x4 __attribute__((ext_vector_type(4)));
typedef unsigned short us8 __attribute__((ext_vector_type(8)));

__device__ __forceinline__ float frcp(float x) { return __builtin_amdgcn_rcpf(x); }
__device__ __forceinline__ float silu_f(float x) { return x * frcp(1.f + __expf(-x)); }
__device__ __forceinline__ float tanh_f(float x) { return 1.f - 2.f * frcp(__expf(2.f * x) + 1.f); }
__device__ __forceinline__ __bf16 f2bf(float f) {
    unsigned u = __builtin_bit_cast(unsigned, f);
    u += 0x7fffu + ((u >> 16) & 1u);
    unsigned short s = (unsigned short)(u >> 16);
    return __builtin_bit_cast(__bf16, s);
}
__device__ __forceinline__ unsigned short f2bfu(float f) {
    return __builtin_bit_cast(unsigned short, f2bf(f));
}
__device__ __forceinline__ float bf2f(__bf16 b) {
    unsigned short s = __builtin_bit_cast(unsigned short, b);
    unsigned u = ((unsigned)s) << 16;
    return __builtin_bit_cast(float, u);
}

// ---------------- weight prep ----------------
__global__ __launch_bounds__(256) void k_wprep(
    const float* __restrict__ mW1, const float* __restrict__ mb1,
    const float* __restrict__ mW2, const float* __restrict__ pW1,
    const float* __restrict__ pb1, const float* __restrict__ pW2,
    const float* __restrict__ eW, const float* __restrict__ eb,
    const float* __restrict__ epW, const float* __restrict__ epb,
    unsigned short* __restrict__ W2T, unsigned short* __restrict__ pW2T,
    unsigned short* __restrict__ Wswz, float* __restrict__ biascat,
    unsigned short* __restrict__ WembSwz, float* __restrict__ biasemb)
{
    int idx = blockIdx.x * 256 + threadIdx.x;
    if (idx < 16384) {
        int l = idx >> 12, r = idx & 4095;
        int j = r >> 6, k = r & 63;
        int src = l * 4096 + k * 64 + j;
        W2T[idx] = f2bfu(mW2[src]);
        pW2T[idx] = f2bfu(pW2[src]);
    }
    if (idx < 131072) {
        int l = idx >> 15, rem = idx & 32767;
        int r = rem >> 7, k = rem & 127;          // r = out col 0..255, k = 0..127
        const float* W1l = mW1 + (size_t)l * 16448;
        const float* pW1l = pW1 + (size_t)l * 8256;
        float v;
        if (r < 64)        v = W1l[k * 64 + r];                                    // A
        else if (r < 128)  v = (k >= 64) ? pW1l[(k - 64) * 64 + (r - 64)] : 0.f;   // PA
        else if (r < 192)  v = W1l[(128 + k) * 64 + (r - 128)];                    // B
        else               v = (k >= 64) ? pW1l[k * 64 + (r - 192)] : 0.f;         // PB
        int c = k >> 3, e = k & 7;
        int cs = c ^ (r & 15);
        Wswz[(size_t)l * 32768 + r * 128 + cs * 8 + e] = f2bfu(v);
    }
    if (idx < 8192) {
        int r = idx >> 6, k = idx & 63;           // r = out col 0..127, k = 0..63
        float v;
        if (r < 64) v = eW[k * 64 + r];
        else        v = (k >= 40) ? epW[(k - 40) * 64 + (r - 64)] : 0.f;
        int c = k >> 3, e = k & 7;
        int cs = c ^ (r & 7);
        WembSwz[r * 64 + cs * 8 + e] = f2bfu(v);
    }
    if (idx < 1024) {
        int l = idx >> 8, col = idx & 255;
        float b = 0.f;
        if (col >= 128 && col < 192) b = mb1[l * 64 + col - 128];
        else if (col >= 192)         b = pb1[l * 64 + col - 192];
        biascat[idx] = b;
    }
    if (idx < 128) biasemb[idx] = (idx < 64) ? eb[idx] : epb[idx - 64];
}

// ---------------- counting sort by receiver (parallel scan) ----------------
__global__ void k_hist(const int* __restrict__ rec, int* __restrict__ hist)
{
    int e = blockIdx.x * 256 + threadIdx.x;
    if (e < NE) atomicAdd(&hist[rec[e]], 1);
}

// 98 blocks x 512: intra-block exclusive scan of hist -> cursor, block total -> bsum
__global__ __launch_bounds__(512) void k_scan1(const int* __restrict__ hist,
                                               int* __restrict__ cursor,
                                               int* __restrict__ bsum)
{
    __shared__ int ws[8];
    const int g = blockIdx.x * 512 + threadIdx.x;
    const int lane = threadIdx.x & 63, w = threadIdx.x >> 6;
    int v = (g < NN) ? hist[g] : 0;
    int inc = v;
#pragma unroll
    for (int d = 1; d < 64; d <<= 1) { int o = __shfl_up(inc, d); if (lane >= d) inc += o; }
    if (lane == 63) ws[w] = inc;
    __syncthreads();
    if (threadIdx.x < 8) {
        int x = ws[threadIdx.x];
        int p = x;
#pragma unroll
        for (int d = 1; d < 8; d <<= 1) { int o = __shfl_up(p, d); if ((int)threadIdx.x >= d) p += o; }
        ws[threadIdx.x] = p - x;      // exclusive wave offsets
    }
    __syncthreads();
    if (g < NN) cursor[g] = ws[w] + inc - v;
    if (threadIdx.x == 511) bsum[blockIdx.x] = ws[7] + inc;
}

// 1 block x 128: exclusive scan of the 98 block totals in place
__global__ __launch_bounds__(128) void k_scan2(int* __restrict__ bsum)
{
    __shared__ int t0;
    const int i = threadIdx.x;
    const int lane = i & 63, w = i >> 6;
    int v = (i < 98) ? bsum[i] : 0;
    int inc = v;
#pragma unroll
    for (int d = 1; d < 64; d <<= 1) { int o = __shfl_up(inc, d); if (lane >= d) inc += o; }
    if (w == 0 && lane == 63) t0 = inc;
    __syncthreads();
    int ex = inc - v + (w ? t0 : 0);
    if (i < 98) bsum[i] = ex;
}

__global__ void k_scatter(const int* __restrict__ send, const int* __restrict__ rec,
                          const float* __restrict__ pos, int* __restrict__ cursor,
                          const int* __restrict__ boff,
                          int* __restrict__ ssend, int* __restrict__ srec,
                          float* __restrict__ sdist)
{
    int e = blockIdx.x * 256 + threadIdx.x;
    if (e >= NE) return;
    int s = send[e], r = rec[e];
    int p = atomicAdd(&cursor[r], 1) + boff[r >> 9];
    float dx = pos[s * 3 + 0] - pos[r * 3 + 0];
    float dy = pos[s * 3 + 1] - pos[r * 3 + 1];
    float dz = pos[s * 3 + 2] - pos[r * 3 + 2];
    ssend[p] = s; srec[p] = r;
    sdist[p] = sqrtf(dx * dx + dy * dy + dz * dz);
}

// ---------------- embed GEMM: [h|ph] = [x|pe] @ Wemb + bias ----------------
__global__ __launch_bounds__(256) void k_embed_gemm(
    const float* __restrict__ x, const float* __restrict__ pe,
    const unsigned short* __restrict__ Wswz, const float* __restrict__ bias,
    float* __restrict__ h, float* __restrict__ ph)
{
    __shared__ __align__(16) unsigned short wlds[8192];   // 128 rows x 64 k, 16KB
    const int t = threadIdx.x;
    const int lane = t & 63, wv = t >> 6;
    const int l15 = lane & 15, q = lane >> 4;
    {
        const us8* src = (const us8*)Wswz;
        us8* dst = (us8*)wlds;
#pragma unroll
        for (int it = 0; it < 4; it++) dst[it * 256 + t] = src[it * 256 + t];
    }
    __syncthreads();

    const int NT = NN / 16;  // 3125
    for (int tile = blockIdx.x * 4 + wv; tile < NT; tile += gridDim.x * 4) {
        const int rb = tile * 16;
        const int row = rb + l15;
        f32x4 uf[4];
        const float* p0 = x + (size_t)row * 40 + q * 8;
        const float* p1 = (q == 0) ? (x + (size_t)row * 40 + 32)
                                   : (pe + (size_t)row * 24 + (q - 1) * 8);
        uf[0] = *(const f32x4*)(p0);
        uf[1] = *(const f32x4*)(p0 + 4);
        uf[2] = *(const f32x4*)(p1);
        uf[3] = *(const f32x4*)(p1 + 4);
        bf16x8 af[2];
#pragma unroll
        for (int ks = 0; ks < 2; ks++)
#pragma unroll
            for (int i = 0; i < 4; i++) {
                af[ks][i]     = f2bf(uf[ks * 2][i]);
                af[ks][4 + i] = f2bf(uf[ks * 2 + 1][i]);
            }
        f32x4 acc[8];
#pragma unroll
        for (int jt = 0; jt < 8; jt++) acc[jt] = (f32x4){0.f, 0.f, 0.f, 0.f};
#pragma unroll
        for (int jt = 0; jt < 8; jt++) {
            int r = jt * 16 + l15;
#pragma unroll
            for (int ks = 0; ks < 2; ks++) {
                int c = (ks * 4 + q) ^ (l15 & 7);
                bf16x8 bfr = *(const bf16x8*)&wlds[r * 64 + c * 8];
                acc[jt] = __builtin_amdgcn_mfma_f32_16x16x32_bf16(af[ks], bfr, acc[jt], 0, 0, 0);
            }
        }
#pragma unroll
        for (int jt = 0; jt < 8; jt++) {
            int col = jt * 16 + l15;
            float bv = bias[col];
            float* outp = (jt < 4) ? (h + (size_t)(rb + q * 4) * 64 + col)
                                   : (ph + (size_t)(rb + q * 4) * 64 + (col - 64));
#pragma unroll
            for (int i = 0; i < 4; i++)
                outp[(size_t)i * 64] = acc[jt][i] + bv;
        }
    }
}

// ---------------- node GEMM: [stab|rtab] = [h|ph] @ Wcat + bias; h2=2h; ph2=2ph ----
__global__ __launch_bounds__(256) void k_node_gemm(
    const float* __restrict__ h, const float* __restrict__ ph,
    const unsigned short* __restrict__ Wswz,   // + layer*32768
    const float* __restrict__ bias,            // + layer*256
    float* __restrict__ stab, float* __restrict__ rtab,
    float* __restrict__ h2, float* __restrict__ ph2)
{
    __shared__ __align__(16) unsigned short wlds[32768];   // 256 rows x 128 k, 64KB
    const int t = threadIdx.x;
    const int lane = t & 63, wv = t >> 6;
    const int l15 = lane & 15, q = lane >> 4;
    {
        const us8* src = (const us8*)Wswz;
        us8* dst = (us8*)wlds;
#pragma unroll
        for (int it = 0; it < 16; it++) dst[it * 256 + t] = src[it * 256 + t];
    }
    __syncthreads();

    const int NT = NN / 16;  // 3125
    for (int tile = blockIdx.x * 4 + wv; tile < NT; tile += gridDim.x * 4) {
        const int rb = tile * 16;
        const int row = rb + l15;
        const float* hr = h + (size_t)row * 64;
        const float* pr = ph + (size_t)row * 64;
        f32x4 uf[8];
#pragma unroll
        for (int ks = 0; ks < 2; ks++) {
            uf[ks * 2 + 0] = *(const f32x4*)(hr + ks * 32 + q * 8);
            uf[ks * 2 + 1] = *(const f32x4*)(hr + ks * 32 + q * 8 + 4);
            uf[4 + ks * 2 + 0] = *(const f32x4*)(pr + ks * 32 + q * 8);
            uf[4 + ks * 2 + 1] = *(const f32x4*)(pr + ks * 32 + q * 8 + 4);
        }
        // hi/lo bf16 split for precision
        bf16x8 ahi[4], alo[4];
#pragma unroll
        for (int ks = 0; ks < 4; ks++)
#pragma unroll
            for (int i = 0; i < 4; i++) {
                float v0 = uf[ks * 2][i], v1 = uf[ks * 2 + 1][i];
                __bf16 h0 = f2bf(v0), h1 = f2bf(v1);
                ahi[ks][i] = h0; ahi[ks][4 + i] = h1;
                alo[ks][i] = f2bf(v0 - bf2f(h0));
                alo[ks][4 + i] = f2bf(v1 - bf2f(h1));
            }
        f32x4 acc[16];
#pragma unroll
        for (int jt = 0; jt < 16; jt++) acc[jt] = (f32x4){0.f, 0.f, 0.f, 0.f};
#pragma unroll
        for (int jt = 0; jt < 16; jt++) {
            int r = jt * 16 + l15;
#pragma unroll
            for (int ks = 0; ks < 4; ks++) {
                int c = (ks * 4 + q) ^ l15;
                bf16x8 bfr = *(const bf16x8*)&wlds[r * 128 + c * 8];
                acc[jt] = __builtin_amdgcn_mfma_f32_16x16x32_bf16(ahi[ks], bfr, acc[jt], 0, 0, 0);
                acc[jt] = __builtin_amdgcn_mfma_f32_16x16x32_bf16(alo[ks], bfr, acc[jt], 0, 0, 0);
            }
        }
#pragma unroll
        for (int jt = 0; jt < 16; jt++) {
            int col = jt * 16 + l15;
            float bv = bias[col];
            float* outp = (jt < 8) ? (stab + (size_t)(rb + q * 4) * 128 + col)
                                   : (rtab + (size_t)(rb + q * 4) * 128 + (col - 128));
#pragma unroll
            for (int i = 0; i < 4; i++)
                outp[(size_t)i * 128] = acc[jt][i] + bv;
        }
#pragma unroll
        for (int ks = 0; ks < 2; ks++) {
            *(f32x4*)(h2 + (size_t)row * 64 + ks * 32 + q * 8)     = uf[ks * 2] + uf[ks * 2];
            *(f32x4*)(h2 + (size_t)row * 64 + ks * 32 + q * 8 + 4) = uf[ks * 2 + 1] + uf[ks * 2 + 1];
            *(f32x4*)(ph2 + (size_t)row * 64 + ks * 32 + q * 8)     = uf[4 + ks * 2] + uf[4 + ks * 2];
            *(f32x4*)(ph2 + (size_t)row * 64 + ks * 32 + q * 8 + 4) = uf[4 + ks * 2 + 1] + uf[4 + ks * 2 + 1];
        }
    }
}

// ---------------- edge kernel: path-split + software-pipelined gathers ------------
// PATH 0 = h (silu, stab/rtab cols 0:64), PATH 1 = pe (tanh, cols 64:128).
// Lane (q,l15) owns edge l15 of each 16-edge group, k-cols {s*32+q*8..+7}.
template<int PATH>
__global__ __launch_bounds__(256, 3) void k_edge(
    const int* __restrict__ ssend, const int* __restrict__ srec,
    const float* __restrict__ sdist,
    const float* __restrict__ stab, const float* __restrict__ rtab,
    const float* __restrict__ mW1, const float* __restrict__ mb2,
    const float* __restrict__ pW1g, const float* __restrict__ pb2,
    const unsigned short* __restrict__ W2T, const unsigned short* __restrict__ pW2T,
    int layer,
    float* __restrict__ hout, float* __restrict__ pout)
{
    __shared__ __align__(16) float mbuf[4][16][68];
    const int lane = threadIdx.x & 63;
    const int wv = threadIdx.x >> 6;
    const int l15 = lane & 15, q = lane >> 4;

    const int chunk = (blockIdx.x << 2) + wv;
    if (chunk >= NE / 64) return;

    const float* stb = stab + (PATH ? 64 : 0);
    const float* rtb = rtab + (PATH ? 64 : 0);
    float* outp = PATH ? pout : hout;

    const float* wrow = PATH ? (pW1g + (size_t)layer * 8256 + 8192)
                             : (mW1 + (size_t)layer * 16448 + 16384);
    f32x4 w1c[4];
#pragma unroll
    for (int s = 0; s < 2; s++) {
        w1c[s * 2 + 0] = *(const f32x4*)(wrow + s * 32 + q * 8);
        w1c[s * 2 + 1] = *(const f32x4*)(wrow + s * 32 + q * 8 + 4);
    }
    bf16x8 wb[8];
    {
        const unsigned short* w2 = (PATH ? pW2T : W2T) + layer * 4096;
#pragma unroll
        for (int jt = 0; jt < 4; jt++)
#pragma unroll
            for (int kk = 0; kk < 2; kk++) {
                int off = (jt * 16 + l15) * 64 + kk * 32 + q * 8;
                wb[jt * 2 + kk] = __builtin_bit_cast(bf16x8, *(const us8*)(w2 + off));
            }
    }
    const float* b2p = PATH ? pb2 : mb2;
    float b2v[4];
#pragma unroll
    for (int jt = 0; jt < 4; jt++) b2v[jt] = b2p[layer * 64 + jt * 16 + l15];

    const int ebase = chunk * 64;
    // all 4 groups' indices up front (kills the index->gather chain)
    int seA[4], reA[4]; float deA[4];
#pragma unroll
    for (int t = 0; t < 4; t++) {
        seA[t] = ssend[ebase + t * 16 + l15];
        reA[t] = srec[ebase + t * 16 + l15];
        deA[t] = sdist[ebase + t * 16 + l15];
    }

    // group 0 gathers
    f32x4 A[4], B[4];
    {
        const float* sr = stb + (size_t)seA[0] * 128;
        const float* rr = rtb + (size_t)reA[0] * 128;
#pragma unroll
        for (int s = 0; s < 2; s++) {
            A[s * 2 + 0] = *(const f32x4*)(sr + s * 32 + q * 8);
            A[s * 2 + 1] = *(const f32x4*)(sr + s * 32 + q * 8 + 4);
            B[s * 2 + 0] = *(const f32x4*)(rr + s * 32 + q * 8);
            B[s * 2 + 1] = *(const f32x4*)(rr + s * 32 + q * 8 + 4);
        }
    }

    float acc1 = 0.f;
    int cur = -1;

#pragma unroll
    for (int t = 0; t < 4; t++) {
        // prefetch next group's gathers: latency hides under this group's compute
        f32x4 An[4], Bn[4];
        if (t < 3) {
            const float* sr = stb + (size_t)seA[t + 1] * 128;
            const float* rr = rtb + (size_t)reA[t + 1] * 128;
#pragma unroll
            for (int s = 0; s < 2; s++) {
                An[s * 2 + 0] = *(const f32x4*)(sr + s * 32 + q * 8);
                An[s * 2 + 1] = *(const f32x4*)(sr + s * 32 + q * 8 + 4);
                Bn[s * 2 + 0] = *(const f32x4*)(rr + s * 32 + q * 8);
                Bn[s * 2 + 1] = *(const f32x4*)(rr + s * 32 + q * 8 + 4);
            }
        }

        const float de = deA[t];
        bf16x8 ah[2];
#pragma unroll
        for (int s = 0; s < 2; s++)
#pragma unroll
            for (int i = 0; i < 4; i++) {
                float v0 = A[s * 2][i] + B[s * 2][i] + de * w1c[s * 2][i];
                float v1 = A[s * 2 + 1][i] + B[s * 2 + 1][i] + de * w1c[s * 2 + 1][i];
                ah[s][i]     = f2bf(PATH ? tanh_f(v0) : silu_f(v0));
                ah[s][4 + i] = f2bf(PATH ? tanh_f(v1) : silu_f(v1));
            }
#pragma unroll
        for (int jt = 0; jt < 4; jt++) {
            f32x4 acc = {0.f, 0.f, 0.f, 0.f};
            acc = __builtin_amdgcn_mfma_f32_16x16x32_bf16(ah[0], wb[jt * 2 + 0], acc, 0, 0, 0);
            acc = __builtin_amdgcn_mfma_f32_16x16x32_bf16(ah[1], wb[jt * 2 + 1], acc, 0, 0, 0);
#pragma unroll
            for (int i = 0; i < 4; i++) {
                float m = acc[i] + b2v[jt];
                mbuf[wv][q * 4 + i][jt * 16 + l15] = PATH ? tanh_f(m) : silu_f(m);
            }
        }

        // batch column loads (parallel ds_reads), then pure-VALU scan
        float vh[16];
#pragma unroll
        for (int e = 0; e < 16; e++) vh[e] = mbuf[wv][e][lane];
#pragma unroll
        for (int e = 0; e < 16; e++) {
            int ree = __shfl(reA[t], e);
            if (ree != cur) {
                if (cur >= 0) atomicAdd(&outp[(size_t)cur * 64 + lane], acc1);
                cur = ree; acc1 = 0.f;
            }
            acc1 += vh[e];
        }

        if (t < 3) {
#pragma unroll
            for (int s = 0; s < 4; s++) { A[s] = An[s]; B[s] = Bn[s]; }
        }
    }
    if (cur >= 0) atomicAdd(&outp[(size_t)cur * 64 + lane], acc1);
}

// ---------------- final node MLP + pooling ----------------
__global__ __launch_bounds__(256) void k_prepool(
    const float* __restrict__ h, const int* __restrict__ batch,
    const float* __restrict__ W1, const float* __restrict__ b1,
    const float* __restrict__ W2, const float* __restrict__ b2,
    float* __restrict__ pooled)
{
    __shared__ __align__(16) float tl[4][64];
    const int lane = threadIdx.x & 63;
    const int wv = threadIdx.x >> 6;
    float w1[64], w2[64];
#pragma unroll
    for (int k = 0; k < 64; k++) { w1[k] = W1[k * 64 + lane]; w2[k] = W2[k * 64 + lane]; }
    const float bb1 = b1[lane], bb2 = b2[lane];
    const int wid = (blockIdx.x << 2) + wv;
    const int nw = gridDim.x << 2;
    for (int n = wid; n < NN; n += nw) {
        const int nu = __builtin_amdgcn_readfirstlane(n);
        const float* hr = h + (size_t)nu * 64;
        float a0 = 0, a1 = 0, a2 = 0, a3 = 0;
#pragma unroll
        for (int k = 0; k < 64; k += 4) {
            a0 += hr[k] * w1[k]; a1 += hr[k + 1] * w1[k + 1];
            a2 += hr[k + 2] * w1[k + 2]; a3 += hr[k + 3] * w1[k + 3];
        }
        tl[wv][lane] = silu_f(a0 + a1 + a2 + a3 + bb1);
        float c0 = 0, c1 = 0, c2 = 0, c3 = 0;
        const f32x4* tp4 = (const f32x4*)&tl[wv][0];
#pragma unroll
        for (int k4 = 0; k4 < 16; k4++) {
            f32x4 tv = tp4[k4];
            c0 += tv[0] * w2[k4 * 4]; c1 += tv[1] * w2[k4 * 4 + 1];
            c2 += tv[2] * w2[k4 * 4 + 2]; c3 += tv[3] * w2[k4 * 4 + 3];
        }
        float hp = c0 + c1 + c2 + c3 + bb2;
        int gidx = batch[nu];
        atomicAdd(&pooled[(size_t)gidx * 64 + lane], hp);
    }
}

// ---------------- readout ----------------
__global__ __launch_bounds__(256) void k_readout(
    const float* __restrict__ pooled,
    const float* __restrict__ W1, const float* __restrict__ b1,
    const float* __restrict__ W2, const float* __restrict__ b2,
    float* __restrict__ out)
{
    const int lane = threadIdx.x & 63;
    const int wv = threadIdx.x >> 6;
    const int g = (blockIdx.x << 2) + wv;
    if (g >= NG) return;
    const float* pr = pooled + (size_t)g * 64;
    float a0 = 0, a1 = 0, a2 = 0, a3 = 0;
#pragma unroll
    for (int k = 0; k < 64; k += 4) {
        a0 += pr[k] * W1[k * 64 + lane]; a1 += pr[k + 1] * W1[(k + 1) * 64 + lane];
        a2 += pr[k + 2] * W1[(k + 2) * 64 + lane]; a3 += pr[k + 3] * W1[(k + 3) * 64 + lane];
    }
    float v = silu_f(a0 + a1 + a2 + a3 + b1[lane]) * W2[lane];
#pragma unroll
    for (int off = 32; off > 0; off >>= 1) v += __shfl_down(v, off);
    if (lane == 0) out[g] = v + b2[0];
}

extern "C" void kernel_launch(void* const* d_in, const int* in_sizes, int n_in,
                              void* d_out, int out_size, void* d_ws, size_t ws_size,
                              hipStream_t stream)
{
    const float* x = (const float*)d_in[0];
    const float* pos = (const float*)d_in[1];
    const float* pe = (const float*)d_in[2];
    const int* eidx = (const int*)d_in[3];
    const int* batch = (const int*)d_in[4];
    const float* eW = (const float*)d_in[5];
    const float* eb = (const float*)d_in[6];
    const float* epW = (const float*)d_in[7];
    const float* epb = (const float*)d_in[8];
    const float* mW1 = (const float*)d_in[9];
    const float* mb1 = (const float*)d_in[10];
    const float* mW2 = (const float*)d_in[11];
    const float* mb2 = (const float*)d_in[12];
    const float* pW1 = (const float*)d_in[13];
    const float* pb1 = (const float*)d_in[14];
    const float* pW2 = (const float*)d_in[15];
    const float* pb2 = (const float*)d_in[16];
    const float* preW1 = (const float*)d_in[17];
    const float* preb1 = (const float*)d_in[18];
    const float* preW2 = (const float*)d_in[19];
    const float* preb2 = (const float*)d_in[20];
    const float* roW1 = (const float*)d_in[21];
    const float* rob1 = (const float*)d_in[22];
    const float* roW2 = (const float*)d_in[23];
    const float* rob2 = (const float*)d_in[24];

    const int* send = eidx;
    const int* rcv = eidx + NE;

    float* f = (float*)d_ws;
    size_t o = 0;
    float* hA = f + o; o += (size_t)NN * 64;
    float* hB = f + o; o += (size_t)NN * 64;
    float* phA = f + o; o += (size_t)NN * 64;
    float* phB = f + o; o += (size_t)NN * 64;
    float* stab = f + o; o += (size_t)NN * 128;
    float* rtab = f + o; o += (size_t)NN * 128;
    float* pooled = f + o; o += NG * 64;
    unsigned short* W2T = (unsigned short*)(f + o); o += 8192;
    unsigned short* pW2T = (unsigned short*)(f + o); o += 8192;
    unsigned short* Wswz = (unsigned short*)(f + o); o += 65536;    // 4*32768 bf16
    unsigned short* WembSwz = (unsigned short*)(f + o); o += 4096;  // 8192 bf16
    float* biascat = f + o; o += 1024;
    float* biasemb = f + o; o += 128;
    int* hist = (int*)(f + o); o += NN;
    int* cursor = (int*)(f + o); o += NN;
    int* bsum = (int*)(f + o); o += 128;
    int* ssend = (int*)(f + o); o += NE;
    int* srec = (int*)(f + o); o += NE;
    float* sdist = f + o; o += NE;

    hipMemsetAsync(pooled, 0, NG * 64 * sizeof(float), stream);
    hipMemsetAsync(hist, 0, NN * sizeof(int), stream);
    k_wprep<<<512, 256, 0, stream>>>(mW1, mb1, mW2, pW1, pb1, pW2,
                                     eW, eb, epW, epb,
                                     W2T, pW2T, Wswz, biascat, WembSwz, biasemb);
    k_hist<<<(NE + 255) / 256, 256, 0, stream>>>(rcv, hist);
    k_scan1<<<98, 512, 0, stream>>>(hist, cursor, bsum);
    k_scan2<<<1, 128, 0, stream>>>(bsum);
    k_scatter<<<(NE + 255) / 256, 256, 0, stream>>>(send, rcv, pos, cursor, bsum,
                                                    ssend, srec, sdist);
    k_embed_gemm<<<512, 256, 0, stream>>>(x, pe, WembSwz, biasemb, hA, phA);

    const int EB = (NE / 64 + 3) / 4;   // 1563 blocks per path
    float* hin = hA; float* pin = phA; float* hout = hB; float* pout = phB;
    for (int l = 0; l < 4; l++) {
        k_node_gemm<<<512, 256, 0, stream>>>(hin, pin, Wswz + (size_t)l * 32768,
                                             biascat + l * 256, stab, rtab, hout, pout);
        k_edge<0><<<EB, 256, 0, stream>>>(ssend, srec, sdist, stab, rtab,
                                          mW1, mb2, pW1, pb2, W2T, pW2T, l, hout, pout);
        k_edge<1><<<EB, 256, 0, stream>>>(ssend, srec, sdist, stab, rtab,
                                          mW1, mb2, pW1, pb2, W2T, pW2T, l, hout, pout);
        float* t;
        t = hin; hin = hout; hout = t;
        t = pin; pin = pout; pout = t;
    }
    k_prepool<<<256, 256, 0, stream>>>(hin, batch, preW1, preb1, preW2, preb2, pooled);
    k_readout<<<128, 256, 0, stream>>>(pooled, roW1, rob1, roW2, rob2, (float*)d_out);
}

// Round 7
// 473.036 us; speedup vs baseline: 2.8399x; 1.0710x over previous
//
#include <hip/hip_runtime.h>

#define NN 50000
#define NE 400000
#define NG 512

typedef __bf16 bf16x8 __attribute__((ext_vector_type(8)));
typedef float f32x4 __attribute__((ext_vector_type(4)));
typedef unsigned short us8 __attribute__((ext_vector_type(8)));
typedef _Float16 half8 __attribute__((ext_vector_type(8)));

__device__ __forceinline__ float frcp(float x) { return __builtin_amdgcn_rcpf(x); }
__device__ __forceinline__ float silu_f(float x) { return x * frcp(1.f + __expf(-x)); }
__device__ __forceinline__ float tanh_f(float x) { return 1.f - 2.f * frcp(__expf(2.f * x) + 1.f); }
__device__ __forceinline__ __bf16 f2bf(float f) {
    unsigned u = __builtin_bit_cast(unsigned, f);
    u += 0x7fffu + ((u >> 16) & 1u);
    unsigned short s = (unsigned short)(u >> 16);
    return __builtin_bit_cast(__bf16, s);
}
__device__ __forceinline__ unsigned short f2bfu(float f) {
    return __builtin_bit_cast(unsigned short, f2bf(f));
}
__device__ __forceinline__ float bf2f(__bf16 b) {
    unsigned short s = __builtin_bit_cast(unsigned short, b);
    unsigned u = ((unsigned)s) << 16;
    return __builtin_bit_cast(float, u);
}

// ---------------- weight prep ----------------
__global__ __launch_bounds__(256) void k_wprep(
    const float* __restrict__ mW1, const float* __restrict__ mb1,
    const float* __restrict__ mW2, const float* __restrict__ pW1,
    const float* __restrict__ pb1, const float* __restrict__ pW2,
    const float* __restrict__ eW, const float* __restrict__ eb,
    const float* __restrict__ epW, const float* __restrict__ epb,
    const float* __restrict__ preW1, const float* __restrict__ preW2,
    unsigned short* __restrict__ W2T, unsigned short* __restrict__ pW2T,
    unsigned short* __restrict__ Wswz, float* __restrict__ biascat,
    unsigned short* __restrict__ WembSwz, float* __restrict__ biasemb,
    unsigned short* __restrict__ preW1T, unsigned short* __restrict__ preW2T)
{
    int idx = blockIdx.x * 256 + threadIdx.x;
    if (idx < 16384) {
        int l = idx >> 12, r = idx & 4095;
        int j = r >> 6, k = r & 63;
        int src = l * 4096 + k * 64 + j;
        W2T[idx] = f2bfu(mW2[src]);
        pW2T[idx] = f2bfu(pW2[src]);
    }
    if (idx < 131072) {
        int l = idx >> 15, rem = idx & 32767;
        int r = rem >> 7, k = rem & 127;          // r = out col 0..255, k = 0..127
        const float* W1l = mW1 + (size_t)l * 16448;
        const float* pW1l = pW1 + (size_t)l * 8256;
        float v;
        if (r < 64)        v = W1l[k * 64 + r];                                    // A
        else if (r < 128)  v = (k >= 64) ? pW1l[(k - 64) * 64 + (r - 64)] : 0.f;   // PA
        else if (r < 192)  v = W1l[(128 + k) * 64 + (r - 128)];                    // B
        else               v = (k >= 64) ? pW1l[k * 64 + (r - 192)] : 0.f;         // PB
        int c = k >> 3, e = k & 7;
        int cs = c ^ (r & 15);
        Wswz[(size_t)l * 32768 + r * 128 + cs * 8 + e] = f2bfu(v);
    }
    if (idx < 8192) {
        int r = idx >> 6, k = idx & 63;           // r = out col 0..127, k = 0..63
        float v;
        if (r < 64) v = eW[k * 64 + r];
        else        v = (k >= 40) ? epW[(k - 40) * 64 + (r - 64)] : 0.f;
        int c = k >> 3, e = k & 7;
        int cs = c ^ (r & 7);
        WembSwz[r * 64 + cs * 8 + e] = f2bfu(v);
    }
    if (idx < 4096) {
        int j = idx >> 6, k = idx & 63;           // [j][k] transposed
        preW1T[idx] = f2bfu(preW1[k * 64 + j]);
        preW2T[idx] = f2bfu(preW2[k * 64 + j]);
    }
    if (idx < 1024) {
        int l = idx >> 8, col = idx & 255;
        float b = 0.f;
        if (col >= 128 && col < 192) b = mb1[l * 64 + col - 128];
        else if (col >= 192)         b = pb1[l * 64 + col - 192];
        biascat[idx] = b;
    }
    if (idx < 128) biasemb[idx] = (idx < 64) ? eb[idx] : epb[idx - 64];
}

// ---------------- counting sort by receiver (parallel scan) ----------------
__global__ void k_hist(const int* __restrict__ rec, int* __restrict__ hist)
{
    int e = blockIdx.x * 256 + threadIdx.x;
    if (e < NE) atomicAdd(&hist[rec[e]], 1);
}

__global__ __launch_bounds__(512) void k_scan1(const int* __restrict__ hist,
                                               int* __restrict__ cursor,
                                               int* __restrict__ bsum)
{
    __shared__ int ws[8];
    const int g = blockIdx.x * 512 + threadIdx.x;
    const int lane = threadIdx.x & 63, w = threadIdx.x >> 6;
    int v = (g < NN) ? hist[g] : 0;
    int inc = v;
#pragma unroll
    for (int d = 1; d < 64; d <<= 1) { int o = __shfl_up(inc, d); if (lane >= d) inc += o; }
    if (lane == 63) ws[w] = inc;
    __syncthreads();
    if (threadIdx.x < 8) {
        int x = ws[threadIdx.x];
        int p = x;
#pragma unroll
        for (int d = 1; d < 8; d <<= 1) { int o = __shfl_up(p, d); if ((int)threadIdx.x >= d) p += o; }
        ws[threadIdx.x] = p - x;
    }
    __syncthreads();
    if (g < NN) cursor[g] = ws[w] + inc - v;
    if (threadIdx.x == 511) bsum[blockIdx.x] = ws[7] + inc;
}

__global__ __launch_bounds__(128) void k_scan2(int* __restrict__ bsum)
{
    __shared__ int t0;
    const int i = threadIdx.x;
    const int lane = i & 63, w = i >> 6;
    int v = (i < 98) ? bsum[i] : 0;
    int inc = v;
#pragma unroll
    for (int d = 1; d < 64; d <<= 1) { int o = __shfl_up(inc, d); if (lane >= d) inc += o; }
    if (w == 0 && lane == 63) t0 = inc;
    __syncthreads();
    int ex = inc - v + (w ? t0 : 0);
    if (i < 98) bsum[i] = ex;
}

__global__ void k_scatter(const int* __restrict__ send, const int* __restrict__ rec,
                          const float* __restrict__ pos, int* __restrict__ cursor,
                          const int* __restrict__ boff,
                          int* __restrict__ ssend, int* __restrict__ srec,
                          float* __restrict__ sdist)
{
    int e = blockIdx.x * 256 + threadIdx.x;
    if (e >= NE) return;
    int s = send[e], r = rec[e];
    int p = atomicAdd(&cursor[r], 1) + boff[r >> 9];
    float dx = pos[s * 3 + 0] - pos[r * 3 + 0];
    float dy = pos[s * 3 + 1] - pos[r * 3 + 1];
    float dz = pos[s * 3 + 2] - pos[r * 3 + 2];
    ssend[p] = s; srec[p] = r;
    sdist[p] = sqrtf(dx * dx + dy * dy + dz * dz);
}

// ---------------- embed GEMM: [h|ph] = [x|pe] @ Wemb + bias ----------------
__global__ __launch_bounds__(256) void k_embed_gemm(
    const float* __restrict__ x, const float* __restrict__ pe,
    const unsigned short* __restrict__ Wswz, const float* __restrict__ bias,
    float* __restrict__ h, float* __restrict__ ph)
{
    __shared__ __align__(16) unsigned short wlds[8192];
    const int t = threadIdx.x;
    const int lane = t & 63, wv = t >> 6;
    const int l15 = lane & 15, q = lane >> 4;
    {
        const us8* src = (const us8*)Wswz;
        us8* dst = (us8*)wlds;
#pragma unroll
        for (int it = 0; it < 4; it++) dst[it * 256 + t] = src[it * 256 + t];
    }
    __syncthreads();

    const int NT = NN / 16;
    for (int tile = blockIdx.x * 4 + wv; tile < NT; tile += gridDim.x * 4) {
        const int rb = tile * 16;
        const int row = rb + l15;
        f32x4 uf[4];
        const float* p0 = x + (size_t)row * 40 + q * 8;
        const float* p1 = (q == 0) ? (x + (size_t)row * 40 + 32)
                                   : (pe + (size_t)row * 24 + (q - 1) * 8);
        uf[0] = *(const f32x4*)(p0);
        uf[1] = *(const f32x4*)(p0 + 4);
        uf[2] = *(const f32x4*)(p1);
        uf[3] = *(const f32x4*)(p1 + 4);
        bf16x8 af[2];
#pragma unroll
        for (int ks = 0; ks < 2; ks++)
#pragma unroll
            for (int i = 0; i < 4; i++) {
                af[ks][i]     = f2bf(uf[ks * 2][i]);
                af[ks][4 + i] = f2bf(uf[ks * 2 + 1][i]);
            }
        f32x4 acc[8];
#pragma unroll
        for (int jt = 0; jt < 8; jt++) acc[jt] = (f32x4){0.f, 0.f, 0.f, 0.f};
#pragma unroll
        for (int jt = 0; jt < 8; jt++) {
            int r = jt * 16 + l15;
#pragma unroll
            for (int ks = 0; ks < 2; ks++) {
                int c = (ks * 4 + q) ^ (l15 & 7);
                bf16x8 bfr = *(const bf16x8*)&wlds[r * 64 + c * 8];
                acc[jt] = __builtin_amdgcn_mfma_f32_16x16x32_bf16(af[ks], bfr, acc[jt], 0, 0, 0);
            }
        }
#pragma unroll
        for (int jt = 0; jt < 8; jt++) {
            int col = jt * 16 + l15;
            float bv = bias[col];
            float* outp = (jt < 4) ? (h + (size_t)(rb + q * 4) * 64 + col)
                                   : (ph + (size_t)(rb + q * 4) * 64 + (col - 64));
#pragma unroll
            for (int i = 0; i < 4; i++)
                outp[(size_t)i * 64] = acc[jt][i] + bv;
        }
    }
}

// ---------------- node GEMM: [stab|rtab](f16) = [h|ph] @ Wcat + bias; h2; ph2 ------
__global__ __launch_bounds__(256) void k_node_gemm(
    const float* __restrict__ h, const float* __restrict__ ph,
    const unsigned short* __restrict__ Wswz,
    const float* __restrict__ bias,
    _Float16* __restrict__ stab, _Float16* __restrict__ rtab,
    float* __restrict__ h2, float* __restrict__ ph2)
{
    __shared__ __align__(16) unsigned short wlds[32768];
    const int t = threadIdx.x;
    const int lane = t & 63, wv = t >> 6;
    const int l15 = lane & 15, q = lane >> 4;
    {
        const us8* src = (const us8*)Wswz;
        us8* dst = (us8*)wlds;
#pragma unroll
        for (int it = 0; it < 16; it++) dst[it * 256 + t] = src[it * 256 + t];
    }
    __syncthreads();

    const int NT = NN / 16;
    for (int tile = blockIdx.x * 4 + wv; tile < NT; tile += gridDim.x * 4) {
        const int rb = tile * 16;
        const int row = rb + l15;
        const float* hr = h + (size_t)row * 64;
        const float* pr = ph + (size_t)row * 64;
        f32x4 uf[8];
#pragma unroll
        for (int ks = 0; ks < 2; ks++) {
            uf[ks * 2 + 0] = *(const f32x4*)(hr + ks * 32 + q * 8);
            uf[ks * 2 + 1] = *(const f32x4*)(hr + ks * 32 + q * 8 + 4);
            uf[4 + ks * 2 + 0] = *(const f32x4*)(pr + ks * 32 + q * 8);
            uf[4 + ks * 2 + 1] = *(const f32x4*)(pr + ks * 32 + q * 8 + 4);
        }
        bf16x8 ahi[4], alo[4];
#pragma unroll
        for (int ks = 0; ks < 4; ks++)
#pragma unroll
            for (int i = 0; i < 4; i++) {
                float v0 = uf[ks * 2][i], v1 = uf[ks * 2 + 1][i];
                __bf16 h0 = f2bf(v0), h1 = f2bf(v1);
                ahi[ks][i] = h0; ahi[ks][4 + i] = h1;
                alo[ks][i] = f2bf(v0 - bf2f(h0));
                alo[ks][4 + i] = f2bf(v1 - bf2f(h1));
            }
        f32x4 acc[16];
#pragma unroll
        for (int jt = 0; jt < 16; jt++) acc[jt] = (f32x4){0.f, 0.f, 0.f, 0.f};
#pragma unroll
        for (int jt = 0; jt < 16; jt++) {
            int r = jt * 16 + l15;
#pragma unroll
            for (int ks = 0; ks < 4; ks++) {
                int c = (ks * 4 + q) ^ l15;
                bf16x8 bfr = *(const bf16x8*)&wlds[r * 128 + c * 8];
                acc[jt] = __builtin_amdgcn_mfma_f32_16x16x32_bf16(ahi[ks], bfr, acc[jt], 0, 0, 0);
                acc[jt] = __builtin_amdgcn_mfma_f32_16x16x32_bf16(alo[ks], bfr, acc[jt], 0, 0, 0);
            }
        }
#pragma unroll
        for (int jt = 0; jt < 16; jt++) {
            int col = jt * 16 + l15;
            float bv = bias[col];
            _Float16* outp = (jt < 8) ? (stab + (size_t)(rb + q * 4) * 128 + col)
                                      : (rtab + (size_t)(rb + q * 4) * 128 + (col - 128));
#pragma unroll
            for (int i = 0; i < 4; i++)
                outp[(size_t)i * 128] = (_Float16)(acc[jt][i] + bv);
        }
#pragma unroll
        for (int ks = 0; ks < 2; ks++) {
            *(f32x4*)(h2 + (size_t)row * 64 + ks * 32 + q * 8)     = uf[ks * 2] + uf[ks * 2];
            *(f32x4*)(h2 + (size_t)row * 64 + ks * 32 + q * 8 + 4) = uf[ks * 2 + 1] + uf[ks * 2 + 1];
            *(f32x4*)(ph2 + (size_t)row * 64 + ks * 32 + q * 8)     = uf[4 + ks * 2] + uf[4 + ks * 2];
            *(f32x4*)(ph2 + (size_t)row * 64 + ks * 32 + q * 8 + 4) = uf[4 + ks * 2 + 1] + uf[4 + ks * 2 + 1];
        }
    }
}

// ---------------- edge kernel: f16 gathers, path-split, pipelined -----------------
template<int PATH>
__global__ __launch_bounds__(256, 3) void k_edge(
    const int* __restrict__ ssend, const int* __restrict__ srec,
    const float* __restrict__ sdist,
    const _Float16* __restrict__ stab, const _Float16* __restrict__ rtab,
    const float* __restrict__ mW1, const float* __restrict__ mb2,
    const float* __restrict__ pW1g, const float* __restrict__ pb2,
    const unsigned short* __restrict__ W2T, const unsigned short* __restrict__ pW2T,
    int layer,
    float* __restrict__ hout, float* __restrict__ pout)
{
    __shared__ __align__(16) float mbuf[4][16][68];
    const int lane = threadIdx.x & 63;
    const int wv = threadIdx.x >> 6;
    const int l15 = lane & 15, q = lane >> 4;

    const int chunk = (blockIdx.x << 2) + wv;
    if (chunk >= NE / 64) return;

    const _Float16* stb = stab + (PATH ? 64 : 0);
    const _Float16* rtb = rtab + (PATH ? 64 : 0);
    float* outp = PATH ? pout : hout;

    const float* wrow = PATH ? (pW1g + (size_t)layer * 8256 + 8192)
                             : (mW1 + (size_t)layer * 16448 + 16384);
    f32x4 w1c[4];
#pragma unroll
    for (int s = 0; s < 2; s++) {
        w1c[s * 2 + 0] = *(const f32x4*)(wrow + s * 32 + q * 8);
        w1c[s * 2 + 1] = *(const f32x4*)(wrow + s * 32 + q * 8 + 4);
    }
    bf16x8 wb[8];
    {
        const unsigned short* w2 = (PATH ? pW2T : W2T) + layer * 4096;
#pragma unroll
        for (int jt = 0; jt < 4; jt++)
#pragma unroll
            for (int kk = 0; kk < 2; kk++) {
                int off = (jt * 16 + l15) * 64 + kk * 32 + q * 8;
                wb[jt * 2 + kk] = __builtin_bit_cast(bf16x8, *(const us8*)(w2 + off));
            }
    }
    const float* b2p = PATH ? pb2 : mb2;
    float b2v[4];
#pragma unroll
    for (int jt = 0; jt < 4; jt++) b2v[jt] = b2p[layer * 64 + jt * 16 + l15];

    const int ebase = chunk * 64;
    int seA[4], reA[4]; float deA[4];
#pragma unroll
    for (int t = 0; t < 4; t++) {
        seA[t] = ssend[ebase + t * 16 + l15];
        reA[t] = srec[ebase + t * 16 + l15];
        deA[t] = sdist[ebase + t * 16 + l15];
    }

    half8 A[2], B[2];
    {
        const _Float16* sr = stb + (size_t)seA[0] * 128;
        const _Float16* rr = rtb + (size_t)reA[0] * 128;
#pragma unroll
        for (int s = 0; s < 2; s++) {
            A[s] = *(const half8*)(sr + s * 32 + q * 8);
            B[s] = *(const half8*)(rr + s * 32 + q * 8);
        }
    }

    float acc1 = 0.f;
    int cur = -1;

#pragma unroll
    for (int t = 0; t < 4; t++) {
        half8 An[2], Bn[2];
        if (t < 3) {
            const _Float16* sr = stb + (size_t)seA[t + 1] * 128;
            const _Float16* rr = rtb + (size_t)reA[t + 1] * 128;
#pragma unroll
            for (int s = 0; s < 2; s++) {
                An[s] = *(const half8*)(sr + s * 32 + q * 8);
                Bn[s] = *(const half8*)(rr + s * 32 + q * 8);
            }
        }

        const float de = deA[t];
        bf16x8 ah[2];
#pragma unroll
        for (int s = 0; s < 2; s++)
#pragma unroll
            for (int i = 0; i < 4; i++) {
                float v0 = (float)A[s][i]     + (float)B[s][i]     + de * w1c[s * 2][i];
                float v1 = (float)A[s][4 + i] + (float)B[s][4 + i] + de * w1c[s * 2 + 1][i];
                ah[s][i]     = f2bf(PATH ? tanh_f(v0) : silu_f(v0));
                ah[s][4 + i] = f2bf(PATH ? tanh_f(v1) : silu_f(v1));
            }
#pragma unroll
        for (int jt = 0; jt < 4; jt++) {
            f32x4 acc = {0.f, 0.f, 0.f, 0.f};
            acc = __builtin_amdgcn_mfma_f32_16x16x32_bf16(ah[0], wb[jt * 2 + 0], acc, 0, 0, 0);
            acc = __builtin_amdgcn_mfma_f32_16x16x32_bf16(ah[1], wb[jt * 2 + 1], acc, 0, 0, 0);
#pragma unroll
            for (int i = 0; i < 4; i++) {
                float m = acc[i] + b2v[jt];
                mbuf[wv][q * 4 + i][jt * 16 + l15] = PATH ? tanh_f(m) : silu_f(m);
            }
        }

        float vh[16];
#pragma unroll
        for (int e = 0; e < 16; e++) vh[e] = mbuf[wv][e][lane];
#pragma unroll
        for (int e = 0; e < 16; e++) {
            int ree = __shfl(reA[t], e);
            if (ree != cur) {
                if (cur >= 0) atomicAdd(&outp[(size_t)cur * 64 + lane], acc1);
                cur = ree; acc1 = 0.f;
            }
            acc1 += vh[e];
        }

        if (t < 3) {
#pragma unroll
            for (int s = 0; s < 2; s++) { A[s] = An[s]; B[s] = Bn[s]; }
        }
    }
    if (cur >= 0) atomicAdd(&outp[(size_t)cur * 64 + lane], acc1);
}

// ---------------- final node MLP + pooling (MFMA) ----------------
__global__ __launch_bounds__(256) void k_prepool(
    const float* __restrict__ h, const int* __restrict__ batch,
    const unsigned short* __restrict__ preW1T, const float* __restrict__ b1,
    const unsigned short* __restrict__ preW2T, const float* __restrict__ b2,
    float* __restrict__ pooled)
{
    __shared__ __align__(16) float tl[4][16][68];
    const int lane = threadIdx.x & 63;
    const int wv = threadIdx.x >> 6;
    const int l15 = lane & 15, q = lane >> 4;

    bf16x8 wb1[8], wb2[8];
#pragma unroll
    for (int jt = 0; jt < 4; jt++)
#pragma unroll
        for (int kk = 0; kk < 2; kk++) {
            int off = (jt * 16 + l15) * 64 + kk * 32 + q * 8;
            wb1[jt * 2 + kk] = __builtin_bit_cast(bf16x8, *(const us8*)(preW1T + off));
            wb2[jt * 2 + kk] = __builtin_bit_cast(bf16x8, *(const us8*)(preW2T + off));
        }
    float b1v[4], b2v[4];
#pragma unroll
    for (int jt = 0; jt < 4; jt++) {
        b1v[jt] = b1[jt * 16 + l15];
        b2v[jt] = b2[jt * 16 + l15];
    }

    const int NT = NN / 16;
    for (int tile = blockIdx.x * 4 + wv; tile < NT; tile += gridDim.x * 4) {
        const int rb = tile * 16;
        const int row = rb + l15;
        const float* hr = h + (size_t)row * 64;
        f32x4 uf[4];
#pragma unroll
        for (int ks = 0; ks < 2; ks++) {
            uf[ks * 2 + 0] = *(const f32x4*)(hr + ks * 32 + q * 8);
            uf[ks * 2 + 1] = *(const f32x4*)(hr + ks * 32 + q * 8 + 4);
        }
        bf16x8 ahi[2], alo[2];
#pragma unroll
        for (int ks = 0; ks < 2; ks++)
#pragma unroll
            for (int i = 0; i < 4; i++) {
                float v0 = uf[ks * 2][i], v1 = uf[ks * 2 + 1][i];
                __bf16 h0 = f2bf(v0), h1 = f2bf(v1);
                ahi[ks][i] = h0; ahi[ks][4 + i] = h1;
                alo[ks][i] = f2bf(v0 - bf2f(h0));
                alo[ks][4 + i] = f2bf(v1 - bf2f(h1));
            }
        // t = silu(h @ W1 + b1), C layout -> LDS
#pragma unroll
        for (int jt = 0; jt < 4; jt++) {
            f32x4 acc = {0.f, 0.f, 0.f, 0.f};
#pragma unroll
            for (int ks = 0; ks < 2; ks++) {
                acc = __builtin_amdgcn_mfma_f32_16x16x32_bf16(ahi[ks], wb1[jt * 2 + ks], acc, 0, 0, 0);
                acc = __builtin_amdgcn_mfma_f32_16x16x32_bf16(alo[ks], wb1[jt * 2 + ks], acc, 0, 0, 0);
            }
#pragma unroll
            for (int i = 0; i < 4; i++)
                tl[wv][q * 4 + i][jt * 16 + l15] = silu_f(acc[i] + b1v[jt]);
        }
        // read back in A layout, hi/lo split
        const float* tr = &tl[wv][l15][0];
        f32x4 u0 = *(const f32x4*)(tr + q * 8);
        f32x4 u1 = *(const f32x4*)(tr + q * 8 + 4);
        f32x4 u2 = *(const f32x4*)(tr + 32 + q * 8);
        f32x4 u3 = *(const f32x4*)(tr + 32 + q * 8 + 4);
        bf16x8 thi[2], tlo[2];
#pragma unroll
        for (int i = 0; i < 4; i++) {
            __bf16 c0 = f2bf(u0[i]), c1 = f2bf(u1[i]), c2 = f2bf(u2[i]), c3 = f2bf(u3[i]);
            thi[0][i] = c0; thi[0][4 + i] = c1; thi[1][i] = c2; thi[1][4 + i] = c3;
            tlo[0][i] = f2bf(u0[i] - bf2f(c0)); tlo[0][4 + i] = f2bf(u1[i] - bf2f(c1));
            tlo[1][i] = f2bf(u2[i] - bf2f(c2)); tlo[1][4 + i] = f2bf(u3[i] - bf2f(c3));
        }
        int gid[4];
#pragma unroll
        for (int i = 0; i < 4; i++) gid[i] = batch[rb + q * 4 + i];
#pragma unroll
        for (int jt = 0; jt < 4; jt++) {
            f32x4 acc = {0.f, 0.f, 0.f, 0.f};
#pragma unroll
            for (int ks = 0; ks < 2; ks++) {
                acc = __builtin_amdgcn_mfma_f32_16x16x32_bf16(thi[ks], wb2[jt * 2 + ks], acc, 0, 0, 0);
                acc = __builtin_amdgcn_mfma_f32_16x16x32_bf16(tlo[ks], wb2[jt * 2 + ks], acc, 0, 0, 0);
            }
#pragma unroll
            for (int i = 0; i < 4; i++)
                atomicAdd(&pooled[(size_t)gid[i] * 64 + jt * 16 + l15], acc[i] + b2v[jt]);
        }
    }
}

// ---------------- readout ----------------
__global__ __launch_bounds__(256) void k_readout(
    const float* __restrict__ pooled,
    const float* __restrict__ W1, const float* __restrict__ b1,
    const float* __restrict__ W2, const float* __restrict__ b2,
    float* __restrict__ out)
{
    const int lane = threadIdx.x & 63;
    const int wv = threadIdx.x >> 6;
    const int g = (blockIdx.x << 2) + wv;
    if (g >= NG) return;
    const float* pr = pooled + (size_t)g * 64;
    float a0 = 0, a1 = 0, a2 = 0, a3 = 0;
#pragma unroll
    for (int k = 0; k < 64; k += 4) {
        a0 += pr[k] * W1[k * 64 + lane]; a1 += pr[k + 1] * W1[(k + 1) * 64 + lane];
        a2 += pr[k + 2] * W1[(k + 2) * 64 + lane]; a3 += pr[k + 3] * W1[(k + 3) * 64 + lane];
    }
    float v = silu_f(a0 + a1 + a2 + a3 + b1[lane]) * W2[lane];
#pragma unroll
    for (int off = 32; off > 0; off >>= 1) v += __shfl_down(v, off);
    if (lane == 0) out[g] = v + b2[0];
}

extern "C" void kernel_launch(void* const* d_in, const int* in_sizes, int n_in,
                              void* d_out, int out_size, void* d_ws, size_t ws_size,
                              hipStream_t stream)
{
    const float* x = (const float*)d_in[0];
    const float* pos = (const float*)d_in[1];
    const float* pe = (const float*)d_in[2];
    const int* eidx = (const int*)d_in[3];
    const int* batch = (const int*)d_in[4];
    const float* eW = (const float*)d_in[5];
    const float* eb = (const float*)d_in[6];
    const float* epW = (const float*)d_in[7];
    const float* epb = (const float*)d_in[8];
    const float* mW1 = (const float*)d_in[9];
    const float* mb1 = (const float*)d_in[10];
    const float* mW2 = (const float*)d_in[11];
    const float* mb2 = (const float*)d_in[12];
    const float* pW1 = (const float*)d_in[13];
    const float* pb1 = (const float*)d_in[14];
    const float* pW2 = (const float*)d_in[15];
    const float* pb2 = (const float*)d_in[16];
    const float* preW1 = (const float*)d_in[17];
    const float* preb1 = (const float*)d_in[18];
    const float* preW2 = (const float*)d_in[19];
    const float* preb2 = (const float*)d_in[20];
    const float* roW1 = (const float*)d_in[21];
    const float* rob1 = (const float*)d_in[22];
    const float* roW2 = (const float*)d_in[23];
    const float* rob2 = (const float*)d_in[24];

    const int* send = eidx;
    const int* rcv = eidx + NE;

    float* f = (float*)d_ws;
    size_t o = 0;
    float* hA = f + o; o += (size_t)NN * 64;
    float* hB = f + o; o += (size_t)NN * 64;
    float* phA = f + o; o += (size_t)NN * 64;
    float* phB = f + o; o += (size_t)NN * 64;
    _Float16* stab = (_Float16*)(f + o); o += (size_t)NN * 64;   // NN x 128 f16
    _Float16* rtab = (_Float16*)(f + o); o += (size_t)NN * 64;
    float* pooled = f + o; o += NG * 64;
    unsigned short* W2T = (unsigned short*)(f + o); o += 8192;
    unsigned short* pW2T = (unsigned short*)(f + o); o += 8192;
    unsigned short* Wswz = (unsigned short*)(f + o); o += 65536;
    unsigned short* WembSwz = (unsigned short*)(f + o); o += 4096;
    unsigned short* preW1T = (unsigned short*)(f + o); o += 2048;
    unsigned short* preW2T = (unsigned short*)(f + o); o += 2048;
    float* biascat = f + o; o += 1024;
    float* biasemb = f + o; o += 128;
    int* hist = (int*)(f + o); o += NN;
    int* cursor = (int*)(f + o); o += NN;
    int* bsum = (int*)(f + o); o += 128;
    int* ssend = (int*)(f + o); o += NE;
    int* srec = (int*)(f + o); o += NE;
    float* sdist = f + o; o += NE;

    hipMemsetAsync(pooled, 0, NG * 64 * sizeof(float), stream);
    hipMemsetAsync(hist, 0, NN * sizeof(int), stream);
    k_wprep<<<512, 256, 0, stream>>>(mW1, mb1, mW2, pW1, pb1, pW2,
                                     eW, eb, epW, epb, preW1, preW2,
                                     W2T, pW2T, Wswz, biascat, WembSwz, biasemb,
                                     preW1T, preW2T);
    k_hist<<<(NE + 255) / 256, 256, 0, stream>>>(rcv, hist);
    k_scan1<<<98, 512, 0, stream>>>(hist, cursor, bsum);
    k_scan2<<<1, 128, 0, stream>>>(bsum);
    k_scatter<<<(NE + 255) / 256, 256, 0, stream>>>(send, rcv, pos, cursor, bsum,
                                                    ssend, srec, sdist);
    k_embed_gemm<<<512, 256, 0, stream>>>(x, pe, WembSwz, biasemb, hA, phA);

    const int EB = (NE / 64 + 3) / 4;
    float* hin = hA; float* pin = phA; float* hout = hB; float* pout = phB;
    for (int l = 0; l < 4; l++) {
        k_node_gemm<<<512, 256, 0, stream>>>(hin, pin, Wswz + (size_t)l * 32768,
                                             biascat + l * 256, stab, rtab, hout, pout);
        k_edge<0><<<EB, 256, 0, stream>>>(ssend, srec, sdist, stab, rtab,
                                          mW1, mb2, pW1, pb2, W2T, pW2T, l, hout, pout);
        k_edge<1><<<EB, 256, 0, stream>>>(ssend, srec, sdist, stab, rtab,
                                          mW1, mb2, pW1, pb2, W2T, pW2T, l, hout, pout);
        float* t;
        t = hin; hin = hout; hout = t;
        t = pin; pin = pout; pout = t;
    }
    k_prepool<<<512, 256, 0, stream>>>(hin, batch, preW1T, preb1, preW2T, preb2, pooled);
    k_readout<<<128, 256, 0, stream>>>(pooled, roW1, rob1, roW2, rob2, (float*)d_out);
}

// Round 8
// 421.204 us; speedup vs baseline: 3.1894x; 1.1231x over previous
//
#include <hip/hip_runtime.h>

#define NN 50000
#define NE 400000
#define NG 512

typedef __bf16 bf16x8 __attribute__((ext_vector_type(8)));
typedef float f32x4 __attribute__((ext_vector_type(4)));
typedef unsigned short us8 __attribute__((ext_vector_type(8)));
typedef _Float16 half8 __attribute__((ext_vector_type(8)));

__device__ __forceinline__ float frcp(float x) { return __builtin_amdgcn_rcpf(x); }
__device__ __forceinline__ float silu_f(float x) { return x * frcp(1.f + __expf(-x)); }
__device__ __forceinline__ float tanh_f(float x) { return 1.f - 2.f * frcp(__expf(2.f * x) + 1.f); }
__device__ __forceinline__ __bf16 f2bf(float f) {
    unsigned u = __builtin_bit_cast(unsigned, f);
    u += 0x7fffu + ((u >> 16) & 1u);
    unsigned short s = (unsigned short)(u >> 16);
    return __builtin_bit_cast(__bf16, s);
}
__device__ __forceinline__ unsigned short f2bfu(float f) {
    return __builtin_bit_cast(unsigned short, f2bf(f));
}
__device__ __forceinline__ float bf2f(__bf16 b) {
    unsigned short s = __builtin_bit_cast(unsigned short, b);
    unsigned u = ((unsigned)s) << 16;
    return __builtin_bit_cast(float, u);
}

// ---------------- weight prep ----------------
__global__ __launch_bounds__(256) void k_wprep(
    const float* __restrict__ mW1, const float* __restrict__ mb1,
    const float* __restrict__ mW2, const float* __restrict__ pW1,
    const float* __restrict__ pb1, const float* __restrict__ pW2,
    const float* __restrict__ eW, const float* __restrict__ eb,
    const float* __restrict__ epW, const float* __restrict__ epb,
    const float* __restrict__ preW1, const float* __restrict__ preW2,
    unsigned short* __restrict__ W2T, unsigned short* __restrict__ pW2T,
    unsigned short* __restrict__ Wswz, float* __restrict__ biascat,
    unsigned short* __restrict__ WembSwz, float* __restrict__ biasemb,
    unsigned short* __restrict__ preW1T, unsigned short* __restrict__ preW2T)
{
    int idx = blockIdx.x * 256 + threadIdx.x;
    if (idx < 16384) {
        int l = idx >> 12, r = idx & 4095;
        int j = r >> 6, k = r & 63;
        int src = l * 4096 + k * 64 + j;
        W2T[idx] = f2bfu(mW2[src]);
        pW2T[idx] = f2bfu(pW2[src]);
    }
    if (idx < 131072) {
        int l = idx >> 15, rem = idx & 32767;
        int r = rem >> 7, k = rem & 127;          // r = out col 0..255, k = 0..127
        const float* W1l = mW1 + (size_t)l * 16448;
        const float* pW1l = pW1 + (size_t)l * 8256;
        float v;
        if (r < 64)        v = W1l[k * 64 + r];                                    // A
        else if (r < 128)  v = (k >= 64) ? pW1l[(k - 64) * 64 + (r - 64)] : 0.f;   // PA
        else if (r < 192)  v = W1l[(128 + k) * 64 + (r - 128)];                    // B
        else               v = (k >= 64) ? pW1l[k * 64 + (r - 192)] : 0.f;         // PB
        int c = k >> 3, e = k & 7;
        int cs = c ^ (r & 15);
        Wswz[(size_t)l * 32768 + r * 128 + cs * 8 + e] = f2bfu(v);
    }
    if (idx < 8192) {
        int r = idx >> 6, k = idx & 63;
        float v;
        if (r < 64) v = eW[k * 64 + r];
        else        v = (k >= 40) ? epW[(k - 40) * 64 + (r - 64)] : 0.f;
        int c = k >> 3, e = k & 7;
        int cs = c ^ (r & 7);
        WembSwz[r * 64 + cs * 8 + e] = f2bfu(v);
    }
    if (idx < 4096) {
        int j = idx >> 6, k = idx & 63;
        preW1T[idx] = f2bfu(preW1[k * 64 + j]);
        preW2T[idx] = f2bfu(preW2[k * 64 + j]);
    }
    if (idx < 1024) {
        int l = idx >> 8, col = idx & 255;
        float b = 0.f;
        if (col >= 128 && col < 192) b = mb1[l * 64 + col - 128];
        else if (col >= 192)         b = pb1[l * 64 + col - 192];
        biascat[idx] = b;
    }
    if (idx < 128) biasemb[idx] = (idx < 64) ? eb[idx] : epb[idx - 64];
}

// ---------------- counting sort by receiver (parallel scan) ----------------
__global__ void k_hist(const int* __restrict__ rec, int* __restrict__ hist)
{
    int e = blockIdx.x * 256 + threadIdx.x;
    if (e < NE) atomicAdd(&hist[rec[e]], 1);
}

__global__ __launch_bounds__(512) void k_scan1(const int* __restrict__ hist,
                                               int* __restrict__ cursor,
                                               int* __restrict__ bsum)
{
    __shared__ int ws[8];
    const int g = blockIdx.x * 512 + threadIdx.x;
    const int lane = threadIdx.x & 63, w = threadIdx.x >> 6;
    int v = (g < NN) ? hist[g] : 0;
    int inc = v;
#pragma unroll
    for (int d = 1; d < 64; d <<= 1) { int o = __shfl_up(inc, d); if (lane >= d) inc += o; }
    if (lane == 63) ws[w] = inc;
    __syncthreads();
    if (threadIdx.x < 8) {
        int x = ws[threadIdx.x];
        int p = x;
#pragma unroll
        for (int d = 1; d < 8; d <<= 1) { int o = __shfl_up(p, d); if ((int)threadIdx.x >= d) p += o; }
        ws[threadIdx.x] = p - x;
    }
    __syncthreads();
    if (g < NN) cursor[g] = ws[w] + inc - v;
    if (threadIdx.x == 511) bsum[blockIdx.x] = ws[7] + inc;
}

__global__ __launch_bounds__(128) void k_scan2(int* __restrict__ bsum)
{
    __shared__ int t0;
    const int i = threadIdx.x;
    const int lane = i & 63, w = i >> 6;
    int v = (i < 98) ? bsum[i] : 0;
    int inc = v;
#pragma unroll
    for (int d = 1; d < 64; d <<= 1) { int o = __shfl_up(inc, d); if (lane >= d) inc += o; }
    if (w == 0 && lane == 63) t0 = inc;
    __syncthreads();
    int ex = inc - v + (w ? t0 : 0);
    if (i < 98) bsum[i] = ex;
}

__global__ void k_scatter(const int* __restrict__ send, const int* __restrict__ rec,
                          const float* __restrict__ pos, int* __restrict__ cursor,
                          const int* __restrict__ boff,
                          int* __restrict__ ssend, int* __restrict__ srec,
                          float* __restrict__ sdist)
{
    int e = blockIdx.x * 256 + threadIdx.x;
    if (e >= NE) return;
    int s = send[e], r = rec[e];
    int p = atomicAdd(&cursor[r], 1) + boff[r >> 9];
    float dx = pos[s * 3 + 0] - pos[r * 3 + 0];
    float dy = pos[s * 3 + 1] - pos[r * 3 + 1];
    float dz = pos[s * 3 + 2] - pos[r * 3 + 2];
    ssend[p] = s; srec[p] = r;
    sdist[p] = sqrtf(dx * dx + dy * dy + dz * dz);
}

// ---------------- embed GEMM: [h|ph] = [x|pe] @ Wemb + bias ----------------
__global__ __launch_bounds__(256) void k_embed_gemm(
    const float* __restrict__ x, const float* __restrict__ pe,
    const unsigned short* __restrict__ Wswz, const float* __restrict__ bias,
    float* __restrict__ h, float* __restrict__ ph)
{
    __shared__ __align__(16) unsigned short wlds[8192];
    const int t = threadIdx.x;
    const int lane = t & 63, wv = t >> 6;
    const int l15 = lane & 15, q = lane >> 4;
    {
        const us8* src = (const us8*)Wswz;
        us8* dst = (us8*)wlds;
#pragma unroll
        for (int it = 0; it < 4; it++) dst[it * 256 + t] = src[it * 256 + t];
    }
    __syncthreads();

    const int NT = NN / 16;
    for (int tile = blockIdx.x * 4 + wv; tile < NT; tile += gridDim.x * 4) {
        const int rb = tile * 16;
        const int row = rb + l15;
        f32x4 uf[4];
        const float* p0 = x + (size_t)row * 40 + q * 8;
        const float* p1 = (q == 0) ? (x + (size_t)row * 40 + 32)
                                   : (pe + (size_t)row * 24 + (q - 1) * 8);
        uf[0] = *(const f32x4*)(p0);
        uf[1] = *(const f32x4*)(p0 + 4);
        uf[2] = *(const f32x4*)(p1);
        uf[3] = *(const f32x4*)(p1 + 4);
        bf16x8 af[2];
#pragma unroll
        for (int ks = 0; ks < 2; ks++)
#pragma unroll
            for (int i = 0; i < 4; i++) {
                af[ks][i]     = f2bf(uf[ks * 2][i]);
                af[ks][4 + i] = f2bf(uf[ks * 2 + 1][i]);
            }
        f32x4 acc[8];
#pragma unroll
        for (int jt = 0; jt < 8; jt++) acc[jt] = (f32x4){0.f, 0.f, 0.f, 0.f};
#pragma unroll
        for (int jt = 0; jt < 8; jt++) {
            int r = jt * 16 + l15;
#pragma unroll
            for (int ks = 0; ks < 2; ks++) {
                int c = (ks * 4 + q) ^ (l15 & 7);
                bf16x8 bfr = *(const bf16x8*)&wlds[r * 64 + c * 8];
                acc[jt] = __builtin_amdgcn_mfma_f32_16x16x32_bf16(af[ks], bfr, acc[jt], 0, 0, 0);
            }
        }
#pragma unroll
        for (int jt = 0; jt < 8; jt++) {
            int col = jt * 16 + l15;
            float bv = bias[col];
            float* outp = (jt < 4) ? (h + (size_t)(rb + q * 4) * 64 + col)
                                   : (ph + (size_t)(rb + q * 4) * 64 + (col - 64));
#pragma unroll
            for (int i = 0; i < 4; i++)
                outp[(size_t)i * 64] = acc[jt][i] + bv;
        }
    }
}

// ---------------- node GEMM: [stab|rtab](f16) = [h|ph] @ Wcat + bias; h2; ph2 ------
__global__ __launch_bounds__(256) void k_node_gemm(
    const float* __restrict__ h, const float* __restrict__ ph,
    const unsigned short* __restrict__ Wswz,
    const float* __restrict__ bias,
    _Float16* __restrict__ stab, _Float16* __restrict__ rtab,
    float* __restrict__ h2, float* __restrict__ ph2)
{
    __shared__ __align__(16) unsigned short wlds[32768];
    const int t = threadIdx.x;
    const int lane = t & 63, wv = t >> 6;
    const int l15 = lane & 15, q = lane >> 4;
    {
        const us8* src = (const us8*)Wswz;
        us8* dst = (us8*)wlds;
#pragma unroll
        for (int it = 0; it < 16; it++) dst[it * 256 + t] = src[it * 256 + t];
    }
    __syncthreads();

    const int NT = NN / 16;
    for (int tile = blockIdx.x * 4 + wv; tile < NT; tile += gridDim.x * 4) {
        const int rb = tile * 16;
        const int row = rb + l15;
        const float* hr = h + (size_t)row * 64;
        const float* pr = ph + (size_t)row * 64;
        f32x4 uf[8];
#pragma unroll
        for (int ks = 0; ks < 2; ks++) {
            uf[ks * 2 + 0] = *(const f32x4*)(hr + ks * 32 + q * 8);
            uf[ks * 2 + 1] = *(const f32x4*)(hr + ks * 32 + q * 8 + 4);
            uf[4 + ks * 2 + 0] = *(const f32x4*)(pr + ks * 32 + q * 8);
            uf[4 + ks * 2 + 1] = *(const f32x4*)(pr + ks * 32 + q * 8 + 4);
        }
        bf16x8 ahi[4], alo[4];
#pragma unroll
        for (int ks = 0; ks < 4; ks++)
#pragma unroll
            for (int i = 0; i < 4; i++) {
                float v0 = uf[ks * 2][i], v1 = uf[ks * 2 + 1][i];
                __bf16 h0 = f2bf(v0), h1 = f2bf(v1);
                ahi[ks][i] = h0; ahi[ks][4 + i] = h1;
                alo[ks][i] = f2bf(v0 - bf2f(h0));
                alo[ks][4 + i] = f2bf(v1 - bf2f(h1));
            }
        f32x4 acc[16];
#pragma unroll
        for (int jt = 0; jt < 16; jt++) acc[jt] = (f32x4){0.f, 0.f, 0.f, 0.f};
#pragma unroll
        for (int jt = 0; jt < 16; jt++) {
            int r = jt * 16 + l15;
#pragma unroll
            for (int ks = 0; ks < 4; ks++) {
                int c = (ks * 4 + q) ^ l15;
                bf16x8 bfr = *(const bf16x8*)&wlds[r * 128 + c * 8];
                acc[jt] = __builtin_amdgcn_mfma_f32_16x16x32_bf16(ahi[ks], bfr, acc[jt], 0, 0, 0);
                acc[jt] = __builtin_amdgcn_mfma_f32_16x16x32_bf16(alo[ks], bfr, acc[jt], 0, 0, 0);
            }
        }
#pragma unroll
        for (int jt = 0; jt < 16; jt++) {
            int col = jt * 16 + l15;
            float bv = bias[col];
            _Float16* outp = (jt < 8) ? (stab + (size_t)(rb + q * 4) * 128 + col)
                                      : (rtab + (size_t)(rb + q * 4) * 128 + (col - 128));
#pragma unroll
            for (int i = 0; i < 4; i++)
                outp[(size_t)i * 128] = (_Float16)(acc[jt][i] + bv);
        }
#pragma unroll
        for (int ks = 0; ks < 2; ks++) {
            *(f32x4*)(h2 + (size_t)row * 64 + ks * 32 + q * 8)     = uf[ks * 2] + uf[ks * 2];
            *(f32x4*)(h2 + (size_t)row * 64 + ks * 32 + q * 8 + 4) = uf[ks * 2 + 1] + uf[ks * 2 + 1];
            *(f32x4*)(ph2 + (size_t)row * 64 + ks * 32 + q * 8)     = uf[4 + ks * 2] + uf[4 + ks * 2];
            *(f32x4*)(ph2 + (size_t)row * 64 + ks * 32 + q * 8 + 4) = uf[4 + ks * 2 + 1] + uf[4 + ks * 2 + 1];
        }
    }
}

// ---------------- edge kernel: f16 gathers, path-split, pipelined -----------------
template<int PATH>
__global__ __launch_bounds__(256, 3) void k_edge(
    const int* __restrict__ ssend, const int* __restrict__ srec,
    const float* __restrict__ sdist,
    const _Float16* __restrict__ stab, const _Float16* __restrict__ rtab,
    const float* __restrict__ mW1, const float* __restrict__ mb2,
    const float* __restrict__ pW1g, const float* __restrict__ pb2,
    const unsigned short* __restrict__ W2T, const unsigned short* __restrict__ pW2T,
    int layer,
    float* __restrict__ hout, float* __restrict__ pout)
{
    __shared__ __align__(16) float mbuf[4][16][68];
    const int lane = threadIdx.x & 63;
    const int wv = threadIdx.x >> 6;
    const int l15 = lane & 15, q = lane >> 4;

    const int chunk = (blockIdx.x << 2) + wv;
    if (chunk >= NE / 64) return;

    const _Float16* stb = stab + (PATH ? 64 : 0);
    const _Float16* rtb = rtab + (PATH ? 64 : 0);
    float* outp = PATH ? pout : hout;

    const float* wrow = PATH ? (pW1g + (size_t)layer * 8256 + 8192)
                             : (mW1 + (size_t)layer * 16448 + 16384);
    f32x4 w1c[4];
#pragma unroll
    for (int s = 0; s < 2; s++) {
        w1c[s * 2 + 0] = *(const f32x4*)(wrow + s * 32 + q * 8);
        w1c[s * 2 + 1] = *(const f32x4*)(wrow + s * 32 + q * 8 + 4);
    }
    bf16x8 wb[8];
    {
        const unsigned short* w2 = (PATH ? pW2T : W2T) + layer * 4096;
#pragma unroll
        for (int jt = 0; jt < 4; jt++)
#pragma unroll
            for (int kk = 0; kk < 2; kk++) {
                int off = (jt * 16 + l15) * 64 + kk * 32 + q * 8;
                wb[jt * 2 + kk] = __builtin_bit_cast(bf16x8, *(const us8*)(w2 + off));
            }
    }
    const float* b2p = PATH ? pb2 : mb2;
    float b2v[4];
#pragma unroll
    for (int jt = 0; jt < 4; jt++) b2v[jt] = b2p[layer * 64 + jt * 16 + l15];

    const int ebase = chunk * 64;
    int seA[4], reA[4]; float deA[4];
#pragma unroll
    for (int t = 0; t < 4; t++) {
        seA[t] = ssend[ebase + t * 16 + l15];
        reA[t] = srec[ebase + t * 16 + l15];
        deA[t] = sdist[ebase + t * 16 + l15];
    }

    half8 A[2], B[2];
    {
        const _Float16* sr = stb + (size_t)seA[0] * 128;
        const _Float16* rr = rtb + (size_t)reA[0] * 128;
#pragma unroll
        for (int s = 0; s < 2; s++) {
            A[s] = *(const half8*)(sr + s * 32 + q * 8);
            B[s] = *(const half8*)(rr + s * 32 + q * 8);
        }
    }

    float acc1 = 0.f;
    int cur = -1;

#pragma unroll
    for (int t = 0; t < 4; t++) {
        half8 An[2], Bn[2];
        if (t < 3) {
            const _Float16* sr = stb + (size_t)seA[t + 1] * 128;
            const _Float16* rr = rtb + (size_t)reA[t + 1] * 128;
#pragma unroll
            for (int s = 0; s < 2; s++) {
                An[s] = *(const half8*)(sr + s * 32 + q * 8);
                Bn[s] = *(const half8*)(rr + s * 32 + q * 8);
            }
        }

        const float de = deA[t];
        bf16x8 ah[2];
#pragma unroll
        for (int s = 0; s < 2; s++)
#pragma unroll
            for (int i = 0; i < 4; i++) {
                float v0 = (float)A[s][i]     + (float)B[s][i]     + de * w1c[s * 2][i];
                float v1 = (float)A[s][4 + i] + (float)B[s][4 + i] + de * w1c[s * 2 + 1][i];
                ah[s][i]     = f2bf(PATH ? tanh_f(v0) : silu_f(v0));
                ah[s][4 + i] = f2bf(PATH ? tanh_f(v1) : silu_f(v1));
            }
#pragma unroll
        for (int jt = 0; jt < 4; jt++) {
            f32x4 acc = {0.f, 0.f, 0.f, 0.f};
            acc = __builtin_amdgcn_mfma_f32_16x16x32_bf16(ah[0], wb[jt * 2 + 0], acc, 0, 0, 0);
            acc = __builtin_amdgcn_mfma_f32_16x16x32_bf16(ah[1], wb[jt * 2 + 1], acc, 0, 0, 0);
#pragma unroll
            for (int i = 0; i < 4; i++) {
                float m = acc[i] + b2v[jt];
                mbuf[wv][q * 4 + i][jt * 16 + l15] = PATH ? tanh_f(m) : silu_f(m);
            }
        }

        float vh[16];
#pragma unroll
        for (int e = 0; e < 16; e++) vh[e] = mbuf[wv][e][lane];
#pragma unroll
        for (int e = 0; e < 16; e++) {
            int ree = __shfl(reA[t], e);
            if (ree != cur) {
                if (cur >= 0) atomicAdd(&outp[(size_t)cur * 64 + lane], acc1);
                cur = ree; acc1 = 0.f;
            }
            acc1 += vh[e];
        }

        if (t < 3) {
#pragma unroll
            for (int s = 0; s < 2; s++) { A[s] = An[s]; B[s] = Bn[s]; }
        }
    }
    if (cur >= 0) atomicAdd(&outp[(size_t)cur * 64 + lane], acc1);
}

// ---------------- final node MLP + pooling (MFMA + segmented flush) ----------------
__global__ __launch_bounds__(256) void k_prepool(
    const float* __restrict__ h, const int* __restrict__ batch,
    const unsigned short* __restrict__ preW1T, const float* __restrict__ b1,
    const unsigned short* __restrict__ preW2T, const float* __restrict__ b2,
    float* __restrict__ pooled)
{
    __shared__ __align__(16) float tl[4][16][68];
    const int lane = threadIdx.x & 63;
    const int wv = threadIdx.x >> 6;
    const int l15 = lane & 15, q = lane >> 4;

    bf16x8 wb1[8], wb2[8];
#pragma unroll
    for (int jt = 0; jt < 4; jt++)
#pragma unroll
        for (int kk = 0; kk < 2; kk++) {
            int off = (jt * 16 + l15) * 64 + kk * 32 + q * 8;
            wb1[jt * 2 + kk] = __builtin_bit_cast(bf16x8, *(const us8*)(preW1T + off));
            wb2[jt * 2 + kk] = __builtin_bit_cast(bf16x8, *(const us8*)(preW2T + off));
        }
    float b1v[4], b2v[4];
#pragma unroll
    for (int jt = 0; jt < 4; jt++) {
        b1v[jt] = b1[jt * 16 + l15];
        b2v[jt] = b2[jt * 16 + l15];
    }

    const int NT = NN / 16;
    for (int tile = blockIdx.x * 4 + wv; tile < NT; tile += gridDim.x * 4) {
        const int rb = tile * 16;
        const int row = rb + l15;
        const int gidl = batch[row];               // lane l15 holds row l15's graph id
        const float* hr = h + (size_t)row * 64;
        f32x4 uf[4];
#pragma unroll
        for (int ks = 0; ks < 2; ks++) {
            uf[ks * 2 + 0] = *(const f32x4*)(hr + ks * 32 + q * 8);
            uf[ks * 2 + 1] = *(const f32x4*)(hr + ks * 32 + q * 8 + 4);
        }
        bf16x8 ahi[2], alo[2];
#pragma unroll
        for (int ks = 0; ks < 2; ks++)
#pragma unroll
            for (int i = 0; i < 4; i++) {
                float v0 = uf[ks * 2][i], v1 = uf[ks * 2 + 1][i];
                __bf16 h0 = f2bf(v0), h1 = f2bf(v1);
                ahi[ks][i] = h0; ahi[ks][4 + i] = h1;
                alo[ks][i] = f2bf(v0 - bf2f(h0));
                alo[ks][4 + i] = f2bf(v1 - bf2f(h1));
            }
        // t = silu(h @ W1 + b1), C layout -> LDS
#pragma unroll
        for (int jt = 0; jt < 4; jt++) {
            f32x4 acc = {0.f, 0.f, 0.f, 0.f};
#pragma unroll
            for (int ks = 0; ks < 2; ks++) {
                acc = __builtin_amdgcn_mfma_f32_16x16x32_bf16(ahi[ks], wb1[jt * 2 + ks], acc, 0, 0, 0);
                acc = __builtin_amdgcn_mfma_f32_16x16x32_bf16(alo[ks], wb1[jt * 2 + ks], acc, 0, 0, 0);
            }
#pragma unroll
            for (int i = 0; i < 4; i++)
                tl[wv][q * 4 + i][jt * 16 + l15] = silu_f(acc[i] + b1v[jt]);
        }
        // read back in A layout, hi/lo split
        const float* tr = &tl[wv][l15][0];
        f32x4 u0 = *(const f32x4*)(tr + q * 8);
        f32x4 u1 = *(const f32x4*)(tr + q * 8 + 4);
        f32x4 u2 = *(const f32x4*)(tr + 32 + q * 8);
        f32x4 u3 = *(const f32x4*)(tr + 32 + q * 8 + 4);
        bf16x8 thi[2], tlo[2];
#pragma unroll
        for (int i = 0; i < 4; i++) {
            __bf16 c0 = f2bf(u0[i]), c1 = f2bf(u1[i]), c2 = f2bf(u2[i]), c3 = f2bf(u3[i]);
            thi[0][i] = c0; thi[0][4 + i] = c1; thi[1][i] = c2; thi[1][4 + i] = c3;
            tlo[0][i] = f2bf(u0[i] - bf2f(c0)); tlo[0][4 + i] = f2bf(u1[i] - bf2f(c1));
            tlo[1][i] = f2bf(u2[i] - bf2f(c2)); tlo[1][4 + i] = f2bf(u3[i] - bf2f(c3));
        }
        // out = t @ W2 + b2, C layout -> LDS (reuse buffer)
#pragma unroll
        for (int jt = 0; jt < 4; jt++) {
            f32x4 acc = {0.f, 0.f, 0.f, 0.f};
#pragma unroll
            for (int ks = 0; ks < 2; ks++) {
                acc = __builtin_amdgcn_mfma_f32_16x16x32_bf16(thi[ks], wb2[jt * 2 + ks], acc, 0, 0, 0);
                acc = __builtin_amdgcn_mfma_f32_16x16x32_bf16(tlo[ks], wb2[jt * 2 + ks], acc, 0, 0, 0);
            }
#pragma unroll
            for (int i = 0; i < 4; i++)
                tl[wv][q * 4 + i][jt * 16 + l15] = acc[i] + b2v[jt];
        }
        // segmented flush over sorted batch ids: ~1-2 atomics/lane per tile
        float vh[16];
#pragma unroll
        for (int e = 0; e < 16; e++) vh[e] = tl[wv][e][lane];
        float acc1 = 0.f;
        int cur = -1;
#pragma unroll
        for (int e = 0; e < 16; e++) {
            int ge = __shfl(gidl, e);
            if (ge != cur) {
                if (cur >= 0) atomicAdd(&pooled[(size_t)cur * 64 + lane], acc1);
                cur = ge; acc1 = 0.f;
            }
            acc1 += vh[e];
        }
        if (cur >= 0) atomicAdd(&pooled[(size_t)cur * 64 + lane], acc1);
    }
}

// ---------------- readout ----------------
__global__ __launch_bounds__(256) void k_readout(
    const float* __restrict__ pooled,
    const float* __restrict__ W1, const float* __restrict__ b1,
    const float* __restrict__ W2, const float* __restrict__ b2,
    float* __restrict__ out)
{
    const int lane = threadIdx.x & 63;
    const int wv = threadIdx.x >> 6;
    const int g = (blockIdx.x << 2) + wv;
    if (g >= NG) return;
    const float* pr = pooled + (size_t)g * 64;
    float a0 = 0, a1 = 0, a2 = 0, a3 = 0;
#pragma unroll
    for (int k = 0; k < 64; k += 4) {
        a0 += pr[k] * W1[k * 64 + lane]; a1 += pr[k + 1] * W1[(k + 1) * 64 + lane];
        a2 += pr[k + 2] * W1[(k + 2) * 64 + lane]; a3 += pr[k + 3] * W1[(k + 3) * 64 + lane];
    }
    float v = silu_f(a0 + a1 + a2 + a3 + b1[lane]) * W2[lane];
#pragma unroll
    for (int off = 32; off > 0; off >>= 1) v += __shfl_down(v, off);
    if (lane == 0) out[g] = v + b2[0];
}

extern "C" void kernel_launch(void* const* d_in, const int* in_sizes, int n_in,
                              void* d_out, int out_size, void* d_ws, size_t ws_size,
                              hipStream_t stream)
{
    const float* x = (const float*)d_in[0];
    const float* pos = (const float*)d_in[1];
    const float* pe = (const float*)d_in[2];
    const int* eidx = (const int*)d_in[3];
    const int* batch = (const int*)d_in[4];
    const float* eW = (const float*)d_in[5];
    const float* eb = (const float*)d_in[6];
    const float* epW = (const float*)d_in[7];
    const float* epb = (const float*)d_in[8];
    const float* mW1 = (const float*)d_in[9];
    const float* mb1 = (const float*)d_in[10];
    const float* mW2 = (const float*)d_in[11];
    const float* mb2 = (const float*)d_in[12];
    const float* pW1 = (const float*)d_in[13];
    const float* pb1 = (const float*)d_in[14];
    const float* pW2 = (const float*)d_in[15];
    const float* pb2 = (const float*)d_in[16];
    const float* preW1 = (const float*)d_in[17];
    const float* preb1 = (const float*)d_in[18];
    const float* preW2 = (const float*)d_in[19];
    const float* preb2 = (const float*)d_in[20];
    const float* roW1 = (const float*)d_in[21];
    const float* rob1 = (const float*)d_in[22];
    const float* roW2 = (const float*)d_in[23];
    const float* rob2 = (const float*)d_in[24];

    const int* send = eidx;
    const int* rcv = eidx + NE;

    float* f = (float*)d_ws;
    size_t o = 0;
    float* hA = f + o; o += (size_t)NN * 64;
    float* hB = f + o; o += (size_t)NN * 64;
    float* phA = f + o; o += (size_t)NN * 64;
    float* phB = f + o; o += (size_t)NN * 64;
    _Float16* stab = (_Float16*)(f + o); o += (size_t)NN * 64;
    _Float16* rtab = (_Float16*)(f + o); o += (size_t)NN * 64;
    float* pooled = f + o; o += NG * 64;
    unsigned short* W2T = (unsigned short*)(f + o); o += 8192;
    unsigned short* pW2T = (unsigned short*)(f + o); o += 8192;
    unsigned short* Wswz = (unsigned short*)(f + o); o += 65536;
    unsigned short* WembSwz = (unsigned short*)(f + o); o += 4096;
    unsigned short* preW1T = (unsigned short*)(f + o); o += 2048;
    unsigned short* preW2T = (unsigned short*)(f + o); o += 2048;
    float* biascat = f + o; o += 1024;
    float* biasemb = f + o; o += 128;
    int* hist = (int*)(f + o); o += NN;
    int* cursor = (int*)(f + o); o += NN;
    int* bsum = (int*)(f + o); o += 128;
    int* ssend = (int*)(f + o); o += NE;
    int* srec = (int*)(f + o); o += NE;
    float* sdist = f + o; o += NE;

    hipMemsetAsync(pooled, 0, NG * 64 * sizeof(float), stream);
    hipMemsetAsync(hist, 0, NN * sizeof(int), stream);
    k_wprep<<<512, 256, 0, stream>>>(mW1, mb1, mW2, pW1, pb1, pW2,
                                     eW, eb, epW, epb, preW1, preW2,
                                     W2T, pW2T, Wswz, biascat, WembSwz, biasemb,
                                     preW1T, preW2T);
    k_hist<<<(NE + 255) / 256, 256, 0, stream>>>(rcv, hist);
    k_scan1<<<98, 512, 0, stream>>>(hist, cursor, bsum);
    k_scan2<<<1, 128, 0, stream>>>(bsum);
    k_scatter<<<(NE + 255) / 256, 256, 0, stream>>>(send, rcv, pos, cursor, bsum,
                                                    ssend, srec, sdist);
    k_embed_gemm<<<512, 256, 0, stream>>>(x, pe, WembSwz, biasemb, hA, phA);

    const int EB = (NE / 64 + 3) / 4;
    float* hin = hA; float* pin = phA; float* hout = hB; float* pout = phB;
    for (int l = 0; l < 4; l++) {
        k_node_gemm<<<512, 256, 0, stream>>>(hin, pin, Wswz + (size_t)l * 32768,
                                             biascat + l * 256, stab, rtab, hout, pout);
        k_edge<0><<<EB, 256, 0, stream>>>(ssend, srec, sdist, stab, rtab,
                                          mW1, mb2, pW1, pb2, W2T, pW2T, l, hout, pout);
        k_edge<1><<<EB, 256, 0, stream>>>(ssend, srec, sdist, stab, rtab,
                                          mW1, mb2, pW1, pb2, W2T, pW2T, l, hout, pout);
        float* t;
        t = hin; hin = hout; hout = t;
        t = pin; pin = pout; pout = t;
    }
    k_prepool<<<512, 256, 0, stream>>>(hin, batch, preW1T, preb1, preW2T, preb2, pooled);
    k_readout<<<128, 256, 0, stream>>>(pooled, roW1, rob1, roW2, rob2, (float*)d_out);
}